// Round 1
// baseline (14923.930 us; speedup 1.0000x reference)
//
#include <hip/hip_runtime.h>
#include <math.h>

#define SS 512
#define BB 8
#define NHH 12
#define DD 64
#define HH 768
#define II 2048
#define LL 12
#define SCALE_F 0.07216878364870323f  /* 1/sqrt(3*64) */

// ---------------------------------------------------------------------------
// block reduction helpers (assume blockDim.x == 256)
// ---------------------------------------------------------------------------
__device__ __forceinline__ float2 blockReduceSum2(float a, float b) {
    __shared__ float2 sm[4];
    __shared__ float2 bc;
#pragma unroll
    for (int o = 32; o > 0; o >>= 1) {
        a += __shfl_down(a, o);
        b += __shfl_down(b, o);
    }
    int t = threadIdx.x;
    if ((t & 63) == 0) sm[t >> 6] = make_float2(a, b);
    __syncthreads();
    if (t == 0) {
        float xa = sm[0].x + sm[1].x + sm[2].x + sm[3].x;
        float xb = sm[0].y + sm[1].y + sm[2].y + sm[3].y;
        bc = make_float2(xa, xb);
    }
    __syncthreads();
    return bc;
}

__device__ __forceinline__ float blockMax(float v) {
    __shared__ float sm[4];
    __shared__ float bc;
#pragma unroll
    for (int o = 32; o > 0; o >>= 1) v = fmaxf(v, __shfl_down(v, o));
    int t = threadIdx.x;
    if ((t & 63) == 0) sm[t >> 6] = v;
    __syncthreads();
    if (t == 0) bc = fmaxf(fmaxf(sm[0], sm[1]), fmaxf(sm[2], sm[3]));
    __syncthreads();
    return bc;
}

__device__ __forceinline__ float blockSum(float v) {
    __shared__ float sm[4];
    __shared__ float bc;
#pragma unroll
    for (int o = 32; o > 0; o >>= 1) v += __shfl_down(v, o);
    int t = threadIdx.x;
    if ((t & 63) == 0) sm[t >> 6] = v;
    __syncthreads();
    if (t == 0) bc = sm[0] + sm[1] + sm[2] + sm[3];
    __syncthreads();
    return bc;
}

__device__ __forceinline__ float gelu_erf(float v) {
    return 0.5f * v * (1.0f + erff(v * 0.70710678118654752f));
}
__device__ __forceinline__ float gelu_tanh(float v) {
    const float c = 0.7978845608028654f;
    return 0.5f * v * (1.0f + tanhf(c * (v + 0.044715f * v * v * v)));
}

// ---------------------------------------------------------------------------
// mask decode: handle bool-as-u8 or bool-as-int32 layouts
// ---------------------------------------------------------------------------
__global__ __launch_bounds__(256) void k_decode_mask(const unsigned char* __restrict__ raw,
                                                     int* __restrict__ mask, int n) {
    __shared__ int s_any;
    if (threadIdx.x == 0) s_any = 0;
    __syncthreads();
    int local = 0;
    for (int i = threadIdx.x; i < n; i += blockDim.x)
        if ((i & 3) && raw[i]) local = 1;
    if (local) atomicOr(&s_any, 1);
    __syncthreads();
    bool isU8 = (s_any != 0);
    const int* as_int = (const int*)raw;
    for (int i = threadIdx.x; i < n; i += blockDim.x)
        mask[i] = isU8 ? (raw[i] != 0) : (as_int[i] != 0);
}

// ---------------------------------------------------------------------------
// DeBERTa log-bucketed relative positions -> [0, 62]
// ---------------------------------------------------------------------------
__global__ __launch_bounds__(256) void k_pos_idx(int* __restrict__ out) {
    int i = blockIdx.x * 256 + threadIdx.x;
    if (i >= SS * SS) return;
    int q = i >> 9, k = i & 511;
    int rel = q - k;
    int a = rel < 0 ? -rel : rel;
    int abs_pos = (a < 16) ? 15 : (a < 511 ? a : 511);
    int bucket;
    if (abs_pos <= 16) {
        bucket = rel;
    } else {
        double lp = ceil(log((double)abs_pos / 16.0) / log(511.0 / 16.0) * 15.0);
        int l = (int)lp + 16;
        bucket = (rel > 0) ? l : -l;
    }
    int idx = bucket + 31;
    if (idx < 0) idx = 0;
    if (idx > 62) idx = 62;
    out[i] = idx;
}

// ---------------------------------------------------------------------------
// LayerNorm family (no affine unless noted); EPS = 1e-7, biased variance
// ---------------------------------------------------------------------------
__global__ __launch_bounds__(256) void k_ln(const float* __restrict__ in,
                                            float* __restrict__ out, int width) {
    int row = blockIdx.x, t = threadIdx.x;
    const float* r = in + (size_t)row * width;
    float s = 0.f, ss = 0.f;
    for (int i = t; i < width; i += 256) {
        float v = r[i];
        s += v; ss += v * v;
    }
    float2 r2 = blockReduceSum2(s, ss);
    float inv = 1.0f / (float)width;
    float mean = r2.x * inv;
    float var = r2.y * inv - mean * mean;
    float rs = rsqrtf(var + 1e-7f);
    float* o = out + (size_t)row * width;
    for (int i = t; i < width; i += 256) o[i] = (r[i] - mean) * rs;
}

__global__ __launch_bounds__(256) void k_embed_ln(const int* __restrict__ ids,
                                                  const float* __restrict__ emb,
                                                  float* __restrict__ out) {
    int row = blockIdx.x, t = threadIdx.x;
    const float* r = emb + (size_t)ids[row] * HH;
    float s = 0.f, ss = 0.f;
    for (int i = t; i < HH; i += 256) {
        float v = r[i];
        s += v; ss += v * v;
    }
    float2 r2 = blockReduceSum2(s, ss);
    float mean = r2.x * (1.0f / HH);
    float var = r2.y * (1.0f / HH) - mean * mean;
    float rs = rsqrtf(var + 1e-7f);
    float* o = out + (size_t)row * HH;
    for (int i = t; i < HH; i += 256) o[i] = (r[i] - mean) * rs;
}

__global__ __launch_bounds__(256) void k_rel_ln(const float* __restrict__ rel_emb,
                                                const float* __restrict__ g,
                                                const float* __restrict__ b,
                                                float* __restrict__ out) {
    int row = blockIdx.x, t = threadIdx.x;
    const float* r = rel_emb + (size_t)row * HH;
    float s = 0.f, ss = 0.f;
    for (int i = t; i < HH; i += 256) {
        float v = r[i];
        s += v; ss += v * v;
    }
    float2 r2 = blockReduceSum2(s, ss);
    float mean = r2.x * (1.0f / HH);
    float var = r2.y * (1.0f / HH) - mean * mean;
    float rs = rsqrtf(var + 1e-7f);
    float* o = out + (size_t)row * HH;
    for (int i = t; i < HH; i += 256) o[i] = (r[i] - mean) * rs * g[i] + b[i];
}

// ctx = LN(ctxr * gelu_exact(g)),  g = vg[..., 768:]
__global__ __launch_bounds__(256) void k_gated_ln(const float* __restrict__ ctxr,
                                                  const float* __restrict__ vg,
                                                  float* __restrict__ out) {
    __shared__ float buf[HH];
    int row = blockIdx.x, t = threadIdx.x;
    const float* cr = ctxr + (size_t)row * HH;
    const float* gr = vg + (size_t)row * (2 * HH) + HH;
    float s = 0.f, ss = 0.f;
    for (int i = t; i < HH; i += 256) {
        float v = cr[i] * gelu_erf(gr[i]);
        buf[i] = v;
        s += v; ss += v * v;
    }
    float2 r2 = blockReduceSum2(s, ss);  // syncs cover buf visibility
    float mean = r2.x * (1.0f / HH);
    float var = r2.y * (1.0f / HH) - mean * mean;
    float rs = rsqrtf(var + 1e-7f);
    float* o = out + (size_t)row * HH;
    for (int i = t; i < HH; i += 256) o[i] = (buf[i] - mean) * rs;
}

// h2 = LN(ffh[:, :I] * gelu_tanh(ffh[:, I:]))
__global__ __launch_bounds__(256) void k_ffn_ln(const float* __restrict__ ffh,
                                                float* __restrict__ out) {
    __shared__ float buf[II];
    int row = blockIdx.x, t = threadIdx.x;
    const float* ar = ffh + (size_t)row * (2 * II);
    const float* gr = ar + II;
    float s = 0.f, ss = 0.f;
    for (int i = t; i < II; i += 256) {
        float v = ar[i] * gelu_tanh(gr[i]);
        buf[i] = v;
        s += v; ss += v * v;
    }
    float2 r2 = blockReduceSum2(s, ss);
    float mean = r2.x * (1.0f / II);
    float var = r2.y * (1.0f / II) - mean * mean;
    float rs = rsqrtf(var + 1e-7f);
    float* o = out + (size_t)row * II;
    for (int i = t; i < II; i += 256) o[i] = (buf[i] - mean) * rs;
}

// ---------------------------------------------------------------------------
// Generic fp32 GEMM:  C[M,N] = A[M,K] * W[N,K]^T (+bias[N]) (+res[M,N])
// 64x64 tile, 256 threads, 4x4 microtile, K-tiles of 32, transposed LDS
// ---------------------------------------------------------------------------
__global__ __launch_bounds__(256) void k_gemm_nt(const float* __restrict__ A, int lda,
                                                 const float* __restrict__ W, int ldw,
                                                 float* __restrict__ C, int ldc,
                                                 int M, int N, int K,
                                                 const float* __restrict__ bias,
                                                 const float* __restrict__ res) {
    __shared__ float As[32][68];
    __shared__ float Ws[32][68];
    int bn = blockIdx.x, bm = blockIdx.y;
    int t = threadIdx.x;
    int tx = t & 15, ty = t >> 4;
    float acc[4][4] = {};
    int row0 = bm * 64, col0 = bn * 64;
    for (int kt = 0; kt < K; kt += 32) {
#pragma unroll
        for (int j = 0; j < 2; ++j) {
            int v = t + j * 256;  // 0..511
            int r = v >> 3;       // row in tile
            int c4 = v & 7;       // which float4 of 8
            int gr = row0 + r;
            if (gr > M - 1) gr = M - 1;
            float4 d = *(const float4*)(A + (size_t)gr * lda + kt + c4 * 4);
            As[c4 * 4 + 0][r] = d.x; As[c4 * 4 + 1][r] = d.y;
            As[c4 * 4 + 2][r] = d.z; As[c4 * 4 + 3][r] = d.w;
            float4 e = *(const float4*)(W + (size_t)(col0 + r) * ldw + kt + c4 * 4);
            Ws[c4 * 4 + 0][r] = e.x; Ws[c4 * 4 + 1][r] = e.y;
            Ws[c4 * 4 + 2][r] = e.z; Ws[c4 * 4 + 3][r] = e.w;
        }
        __syncthreads();
#pragma unroll
        for (int kk = 0; kk < 32; ++kk) {
            float4 av = *(const float4*)&As[kk][ty * 4];
            float4 wv = *(const float4*)&Ws[kk][tx * 4];
            float a_[4] = {av.x, av.y, av.z, av.w};
            float w_[4] = {wv.x, wv.y, wv.z, wv.w};
#pragma unroll
            for (int i = 0; i < 4; ++i)
#pragma unroll
                for (int j = 0; j < 4; ++j) acc[i][j] += a_[i] * w_[j];
        }
        __syncthreads();
    }
#pragma unroll
    for (int i = 0; i < 4; ++i) {
        int gr = row0 + ty * 4 + i;
        if (gr >= M) break;
#pragma unroll
        for (int j = 0; j < 4; ++j) {
            int gc = col0 + tx * 4 + j;
            float v = acc[i][j];
            if (bias) v += bias[gc];
            if (res) v += res[(size_t)gr * ldc + gc];
            C[(size_t)gr * ldc + gc] = v;
        }
    }
}

// ---------------------------------------------------------------------------
// content-content scores: scores[b,h,q,k] = sum_d qh[q,b,h,d]*kh[k,b,h,d]  (unscaled)
// ---------------------------------------------------------------------------
__global__ __launch_bounds__(256) void k_attn_cc(const float* __restrict__ qk,
                                                 float* __restrict__ scores) {
    __shared__ float Qs[64][68];
    __shared__ float Ks[64][68];
    int bh = blockIdx.y;
    int b = bh / NHH, h = bh % NHH;
    int tile = blockIdx.x;
    int qt = tile >> 3, kt = tile & 7;
    int t = threadIdx.x;
    int tx = t & 15, ty = t >> 4;
    const float* qbase = qk + h * DD;
    const float* kbase = qk + HH + h * DD;
#pragma unroll
    for (int j = 0; j < 4; ++j) {
        int v = t + j * 256;  // 0..1023
        int r = v >> 4, c4 = v & 15;
        int q = qt * 64 + r;
        float4 d = *(const float4*)(qbase + (size_t)(q * BB + b) * (2 * HH) + c4 * 4);
        Qs[c4 * 4 + 0][r] = d.x; Qs[c4 * 4 + 1][r] = d.y;
        Qs[c4 * 4 + 2][r] = d.z; Qs[c4 * 4 + 3][r] = d.w;
        int k = kt * 64 + r;
        float4 e = *(const float4*)(kbase + (size_t)(k * BB + b) * (2 * HH) + c4 * 4);
        Ks[c4 * 4 + 0][r] = e.x; Ks[c4 * 4 + 1][r] = e.y;
        Ks[c4 * 4 + 2][r] = e.z; Ks[c4 * 4 + 3][r] = e.w;
    }
    __syncthreads();
    float acc[4][4] = {};
#pragma unroll
    for (int kk = 0; kk < 64; ++kk) {
        float4 qv = *(const float4*)&Qs[kk][ty * 4];
        float4 kv = *(const float4*)&Ks[kk][tx * 4];
        float a_[4] = {qv.x, qv.y, qv.z, qv.w};
        float b_[4] = {kv.x, kv.y, kv.z, kv.w};
#pragma unroll
        for (int i = 0; i < 4; ++i)
#pragma unroll
            for (int j = 0; j < 4; ++j) acc[i][j] += a_[i] * b_[j];
    }
    float* out = scores + ((size_t)bh * SS + qt * 64) * SS + kt * 64;
#pragma unroll
    for (int i = 0; i < 4; ++i)
#pragma unroll
        for (int j = 0; j < 4; ++j)
            out[(size_t)(ty * 4 + i) * SS + tx * 4 + j] = acc[i][j];
}

// ---------------------------------------------------------------------------
// cp[q,b,h,r] = qh . kposTab[r,h]  (z=0)   pc[k,b,h,r] = kh . qposTab[r,h]  (z=1)
// ---------------------------------------------------------------------------
__global__ __launch_bounds__(256) void k_cp_pc(const float* __restrict__ qk,
                                               const float* __restrict__ posproj,
                                               float* __restrict__ cp,
                                               float* __restrict__ pc) {
    __shared__ float Tb[63][65];
    __shared__ float Ar[64][68];
    int mt = blockIdx.x, h = blockIdx.y, z = blockIdx.z;
    int t = threadIdx.x;
    int aoff = z ? HH : 0;
    int toff = z ? 0 : HH;
    float* out = z ? pc : cp;
    for (int v = t; v < 1008; v += 256) {
        int r = v >> 4, c4 = v & 15;
        float4 d = *(const float4*)(posproj + (size_t)r * (2 * HH) + toff + h * DD + c4 * 4);
        Tb[r][c4 * 4 + 0] = d.x; Tb[r][c4 * 4 + 1] = d.y;
        Tb[r][c4 * 4 + 2] = d.z; Tb[r][c4 * 4 + 3] = d.w;
    }
#pragma unroll
    for (int j = 0; j < 4; ++j) {
        int v = t + j * 256;
        int m = v >> 4, c4 = v & 15;
        float4 d = *(const float4*)(qk + (size_t)(mt * 64 + m) * (2 * HH) + aoff + h * DD + c4 * 4);
        *(float4*)&Ar[m][c4 * 4] = d;
    }
    __syncthreads();
    for (int i = t; i < 64 * 63; i += 256) {
        int m = i / 63, r = i - m * 63;
        float s = 0.f;
#pragma unroll 16
        for (int d = 0; d < 64; ++d) s += Ar[m][d] * Tb[r][d];
        out[((size_t)(mt * 64 + m) * NHH + h) * 63 + r] = s;
    }
}

// ---------------------------------------------------------------------------
// softmax row: s = mask ? -1e9 : SCALE*(cc + cp[idx] + pc[idx]); p = softmax; mask->0
// ---------------------------------------------------------------------------
__global__ __launch_bounds__(256) void k_softmax(float* __restrict__ scores,
                                                 const float* __restrict__ cp,
                                                 const float* __restrict__ pc,
                                                 const int* __restrict__ pos_idx,
                                                 const int* __restrict__ mask) {
    int q = blockIdx.x & 511;
    int bh = blockIdx.x >> 9;
    int b = bh / NHH, h = bh % NHH;
    __shared__ float cps[63];
    int t = threadIdx.x;
    if (t < 63) cps[t] = cp[(((size_t)q * BB + b) * NHH + h) * 63 + t];
    __syncthreads();
    float* row = scores + ((size_t)bh * SS + q) * SS;
    float s[2];
    int msk[2];
#pragma unroll
    for (int u = 0; u < 2; ++u) {
        int k = t + u * 256;
        int id = pos_idx[q * SS + k];
        float v = row[k] + cps[id] + pc[(((size_t)k * BB + b) * NHH + h) * 63 + id];
        msk[u] = mask[b * SS + k];
        s[u] = msk[u] ? -1e9f : v * SCALE_F;
    }
    float m = blockMax(fmaxf(s[0], s[1]));
    float e[2];
    e[0] = expf(s[0] - m);
    e[1] = expf(s[1] - m);
    float sum = blockSum(e[0] + e[1]);
    float inv = 1.0f / sum;
#pragma unroll
    for (int u = 0; u < 2; ++u) {
        int k = t + u * 256;
        row[k] = msk[u] ? 0.0f : e[u] * inv;
    }
}

// ---------------------------------------------------------------------------
// ctxr[q,b,h,d] = sum_k p[b,h,q,k] * vh[k,b,h,d]
// ---------------------------------------------------------------------------
__global__ __launch_bounds__(256) void k_attn_pv(const float* __restrict__ p,
                                                 const float* __restrict__ vg,
                                                 float* __restrict__ ctxr) {
    __shared__ float Ps[64][68];
    __shared__ float Vs[64][68];
    int bh = blockIdx.y;
    int b = bh / NHH, h = bh % NHH;
    int qt = blockIdx.x;
    int t = threadIdx.x;
    int tx = t & 15, ty = t >> 4;
    float acc[4][4] = {};
    const float* prow = p + ((size_t)bh * SS + qt * 64) * SS;
    const float* vbase = vg + h * DD;
    for (int kt0 = 0; kt0 < SS; kt0 += 64) {
#pragma unroll
        for (int j = 0; j < 4; ++j) {
            int v = t + j * 256;
            int r = v >> 4, c4 = v & 15;
            float4 d = *(const float4*)(prow + (size_t)r * SS + kt0 + c4 * 4);
            Ps[c4 * 4 + 0][r] = d.x; Ps[c4 * 4 + 1][r] = d.y;
            Ps[c4 * 4 + 2][r] = d.z; Ps[c4 * 4 + 3][r] = d.w;
            int k = kt0 + r;
            float4 e = *(const float4*)(vbase + (size_t)(k * BB + b) * (2 * HH) + c4 * 4);
            *(float4*)&Vs[r][c4 * 4] = e;
        }
        __syncthreads();
#pragma unroll
        for (int kk = 0; kk < 64; ++kk) {
            float4 pv = *(const float4*)&Ps[kk][ty * 4];
            float4 vv = *(const float4*)&Vs[kk][tx * 4];
            float a_[4] = {pv.x, pv.y, pv.z, pv.w};
            float b_[4] = {vv.x, vv.y, vv.z, vv.w};
#pragma unroll
            for (int i = 0; i < 4; ++i)
#pragma unroll
                for (int j = 0; j < 4; ++j) acc[i][j] += a_[i] * b_[j];
        }
        __syncthreads();
    }
#pragma unroll
    for (int i = 0; i < 4; ++i) {
        int qg = qt * 64 + ty * 4 + i;
#pragma unroll
        for (int j = 0; j < 4; ++j)
            ctxr[(size_t)(qg * BB + b) * HH + h * DD + tx * 4 + j] = acc[i][j];
    }
}

// ---------------------------------------------------------------------------
// host launcher
// ---------------------------------------------------------------------------
static inline void gemm(const float* A, int lda, const float* W, int ldw,
                        float* C, int ldc, int M, int N, int K,
                        const float* bias, const float* res, hipStream_t st) {
    dim3 g(N / 64, (M + 63) / 64);
    k_gemm_nt<<<g, 256, 0, st>>>(A, lda, W, ldw, C, ldc, M, N, K, bias, res);
}

extern "C" void kernel_launch(void* const* d_in, const int* in_sizes, int n_in,
                              void* d_out, int out_size, void* d_ws, size_t ws_size,
                              hipStream_t stream) {
    const int* ids = (const int*)d_in[0];
    const unsigned char* maskraw = (const unsigned char*)d_in[1];
    const float* word_emb = (const float*)d_in[2];
    const float* rel_emb = (const float*)d_in[3];
    const float* rel_g = (const float*)d_in[4];
    const float* rel_b = (const float*)d_in[5];
    const float* Wqk = (const float*)d_in[6];
    const float* bqk = (const float*)d_in[7];
    const float* Wvg = (const float*)d_in[8];
    const float* bvg = (const float*)d_in[9];
    const float* Wout = (const float*)d_in[10];
    const float* bout = (const float*)d_in[11];
    const float* W1 = (const float*)d_in[12];
    const float* W2 = (const float*)d_in[13];

    const size_t N_X = (size_t)SS * BB * HH;          // 3,145,728
    const size_t N_QK = (size_t)SS * BB * 2 * HH;     // 6,291,456
    const size_t N_SC = (size_t)BB * NHH * SS * SS;   // 25,165,824
    const size_t N_CP = (size_t)SS * BB * NHH * 63;   // 3,096,576
    const size_t N_FFH = (size_t)SS * BB * 2 * II;    // 16,777,216
    const size_t N_REL = (size_t)63 * HH;
    const size_t N_POSP = (size_t)63 * 2 * HH;

    float* ws = (float*)d_ws;
    float* x = ws;
    float* hs = x + N_X;
    float* qk = hs + N_X;
    float* vg = qk + N_QK;
    float* ctxr = vg + N_QK;
    float* ctx = ctxr + N_X;
    float* cp = ctx + N_X;
    float* pc = cp + N_CP;
    float* rel = pc + N_CP;
    float* posproj = rel + N_REL;
    float* region = posproj + N_POSP;  // scores overlaps ffh+h2 (disjoint phases)
    float* scores = region;
    float* ffh = region;
    float* h2 = region + N_FFH;
    int* posidx = (int*)(region + N_SC);
    int* maski = posidx + SS * SS;

    size_t need_bytes = ((size_t)(maski + SS * BB) - (size_t)d_ws);
    if (ws_size < need_bytes) return;  // ~228 MB required

    // ---- setup (per call; deterministic) ----
    k_decode_mask<<<1, 256, 0, stream>>>(maskraw, maski, BB * SS);
    k_pos_idx<<<(SS * SS + 255) / 256, 256, 0, stream>>>(posidx);
    k_embed_ln<<<SS * BB, 256, 0, stream>>>(ids, word_emb, x);
    k_rel_ln<<<63, 256, 0, stream>>>(rel_emb, rel_g, rel_b, rel);

    for (int l = 0; l < LL; ++l) {
        const float* Wqk_l = Wqk + (size_t)l * 2 * HH * HH;
        const float* bqk_l = bqk + (size_t)l * 2 * HH;
        const float* Wvg_l = Wvg + (size_t)l * 2 * HH * HH;
        const float* bvg_l = bvg + (size_t)l * 2 * HH;
        const float* Wout_l = Wout + (size_t)l * HH * HH;
        const float* bout_l = bout + (size_t)l * HH;
        const float* W1_l = W1 + (size_t)l * 2 * II * HH;
        const float* W2_l = W2 + (size_t)l * HH * II;

        // attention
        k_ln<<<SS * BB, 256, 0, stream>>>(x, hs, HH);
        gemm(hs, HH, Wqk_l, HH, qk, 2 * HH, SS * BB, 2 * HH, HH, bqk_l, nullptr, stream);
        gemm(hs, HH, Wvg_l, HH, vg, 2 * HH, SS * BB, 2 * HH, HH, bvg_l, nullptr, stream);
        gemm(rel, HH, Wqk_l, HH, posproj, 2 * HH, 63, 2 * HH, HH, bqk_l, nullptr, stream);
        k_cp_pc<<<dim3(SS * BB / 64, NHH, 2), 256, 0, stream>>>(qk, posproj, cp, pc);
        k_attn_cc<<<dim3(64, BB * NHH), 256, 0, stream>>>(qk, scores);
        k_softmax<<<BB * NHH * SS, 256, 0, stream>>>(scores, cp, pc, posidx, maski);
        k_attn_pv<<<dim3(SS / 64, BB * NHH), 256, 0, stream>>>(scores, vg, ctxr);
        k_gated_ln<<<SS * BB, 256, 0, stream>>>(ctxr, vg, ctx);
        gemm(ctx, HH, Wout_l, HH, x, HH, SS * BB, HH, HH, bout_l, x, stream);

        // GeGLU FFN
        k_ln<<<SS * BB, 256, 0, stream>>>(x, hs, HH);
        gemm(hs, HH, W1_l, HH, ffh, 2 * II, SS * BB, 2 * II, HH, nullptr, nullptr, stream);
        k_ffn_ln<<<SS * BB, 256, 0, stream>>>(ffh, h2);
        gemm(h2, II, W2_l, II, x, HH, SS * BB, HH, II, nullptr, x, stream);
    }

    hipMemcpyAsync(d_out, x, N_X * sizeof(float), hipMemcpyDeviceToDevice, stream);
}

// Round 2
// 6695.052 us; speedup vs baseline: 2.2291x; 2.2291x over previous
//
#include <hip/hip_runtime.h>
#include <math.h>

#define SS 512
#define BB 8
#define NHH 12
#define DD 64
#define HH 768
#define II 2048
#define LL 12
#define SCALE_F 0.07216878364870323f  /* 1/sqrt(3*64) */

typedef __attribute__((ext_vector_type(8))) short bf16x8;
typedef __attribute__((ext_vector_type(4))) float f32x4;

// f32 -> bf16 (RNE, finite values)
__device__ __forceinline__ unsigned short f2b(float f) {
    union { float f; unsigned int u; } x; x.f = f;
    unsigned int r = x.u + 0x7fffu + ((x.u >> 16) & 1u);
    return (unsigned short)(r >> 16);
}

// ---------------------------------------------------------------------------
// block reduction helpers (blockDim.x == 256)
// ---------------------------------------------------------------------------
__device__ __forceinline__ float2 blockReduceSum2(float a, float b) {
    __shared__ float2 sm[4];
    __shared__ float2 bc;
#pragma unroll
    for (int o = 32; o > 0; o >>= 1) {
        a += __shfl_down(a, o);
        b += __shfl_down(b, o);
    }
    int t = threadIdx.x;
    if ((t & 63) == 0) sm[t >> 6] = make_float2(a, b);
    __syncthreads();
    if (t == 0) {
        float xa = sm[0].x + sm[1].x + sm[2].x + sm[3].x;
        float xb = sm[0].y + sm[1].y + sm[2].y + sm[3].y;
        bc = make_float2(xa, xb);
    }
    __syncthreads();
    return bc;
}

__device__ __forceinline__ float blockMax(float v) {
    __shared__ float sm[4];
    __shared__ float bc;
#pragma unroll
    for (int o = 32; o > 0; o >>= 1) v = fmaxf(v, __shfl_down(v, o));
    int t = threadIdx.x;
    if ((t & 63) == 0) sm[t >> 6] = v;
    __syncthreads();
    if (t == 0) bc = fmaxf(fmaxf(sm[0], sm[1]), fmaxf(sm[2], sm[3]));
    __syncthreads();
    return bc;
}

__device__ __forceinline__ float blockSum(float v) {
    __shared__ float sm[4];
    __shared__ float bc;
#pragma unroll
    for (int o = 32; o > 0; o >>= 1) v += __shfl_down(v, o);
    int t = threadIdx.x;
    if ((t & 63) == 0) sm[t >> 6] = v;
    __syncthreads();
    if (t == 0) bc = sm[0] + sm[1] + sm[2] + sm[3];
    __syncthreads();
    return bc;
}

__device__ __forceinline__ float gelu_erf(float v) {
    return 0.5f * v * (1.0f + erff(v * 0.70710678118654752f));
}
__device__ __forceinline__ float gelu_tanh(float v) {
    const float c = 0.7978845608028654f;
    return 0.5f * v * (1.0f + tanhf(c * (v + 0.044715f * v * v * v)));
}

// ---------------------------------------------------------------------------
// mask decode: handle bool-as-u8 or bool-as-int32 layouts
// ---------------------------------------------------------------------------
__global__ __launch_bounds__(256) void k_decode_mask(const unsigned char* __restrict__ raw,
                                                     int* __restrict__ mask, int n) {
    __shared__ int s_any;
    if (threadIdx.x == 0) s_any = 0;
    __syncthreads();
    int local = 0;
    for (int i = threadIdx.x; i < n; i += blockDim.x)
        if ((i & 3) && raw[i]) local = 1;
    if (local) atomicOr(&s_any, 1);
    __syncthreads();
    bool isU8 = (s_any != 0);
    const int* as_int = (const int*)raw;
    for (int i = threadIdx.x; i < n; i += blockDim.x)
        mask[i] = isU8 ? (raw[i] != 0) : (as_int[i] != 0);
}

// ---------------------------------------------------------------------------
// DeBERTa log-bucketed relative positions -> [0, 62]
// ---------------------------------------------------------------------------
__global__ __launch_bounds__(256) void k_pos_idx(int* __restrict__ out) {
    int i = blockIdx.x * 256 + threadIdx.x;
    if (i >= SS * SS) return;
    int q = i >> 9, k = i & 511;
    int rel = q - k;
    int a = rel < 0 ? -rel : rel;
    int abs_pos = (a < 16) ? 15 : (a < 511 ? a : 511);
    int bucket;
    if (abs_pos <= 16) {
        bucket = rel;
    } else {
        double lp = ceil(log((double)abs_pos / 16.0) / log(511.0 / 16.0) * 15.0);
        int l = (int)lp + 16;
        bucket = (rel > 0) ? l : -l;
    }
    int idx = bucket + 31;
    if (idx < 0) idx = 0;
    if (idx > 62) idx = 62;
    out[i] = idx;
}

// ---------------------------------------------------------------------------
// f32 -> bf16 bulk conversion (8 elems/thread)
// ---------------------------------------------------------------------------
__global__ __launch_bounds__(256) void k_f2b(const float* __restrict__ in,
                                             unsigned short* __restrict__ out, int n8) {
    int i = blockIdx.x * 256 + threadIdx.x;
    if (i >= n8) return;
    float4 a = ((const float4*)in)[2 * i];
    float4 b = ((const float4*)in)[2 * i + 1];
    ushort4 lo, hi;
    lo.x = f2b(a.x); lo.y = f2b(a.y); lo.z = f2b(a.z); lo.w = f2b(a.w);
    hi.x = f2b(b.x); hi.y = f2b(b.y); hi.z = f2b(b.z); hi.w = f2b(b.w);
    ((ushort4*)out)[2 * i] = lo;
    ((ushort4*)out)[2 * i + 1] = hi;
}

// ---------------------------------------------------------------------------
// LayerNorm family; EPS = 1e-7, biased variance
// ---------------------------------------------------------------------------
__global__ __launch_bounds__(256) void k_ln_bf(const float* __restrict__ in,
                                               unsigned short* __restrict__ out, int width) {
    int row = blockIdx.x, t = threadIdx.x;
    const float* r = in + (size_t)row * width;
    float s = 0.f, ss = 0.f;
    for (int i = t; i < width; i += 256) {
        float v = r[i];
        s += v; ss += v * v;
    }
    float2 r2 = blockReduceSum2(s, ss);
    float inv = 1.0f / (float)width;
    float mean = r2.x * inv;
    float var = r2.y * inv - mean * mean;
    float rs = rsqrtf(var + 1e-7f);
    unsigned short* o = out + (size_t)row * width;
    for (int i = t; i < width; i += 256) o[i] = f2b((r[i] - mean) * rs);
}

__global__ __launch_bounds__(256) void k_embed_ln(const int* __restrict__ ids,
                                                  const float* __restrict__ emb,
                                                  float* __restrict__ out) {
    int row = blockIdx.x, t = threadIdx.x;
    const float* r = emb + (size_t)ids[row] * HH;
    float s = 0.f, ss = 0.f;
    for (int i = t; i < HH; i += 256) {
        float v = r[i];
        s += v; ss += v * v;
    }
    float2 r2 = blockReduceSum2(s, ss);
    float mean = r2.x * (1.0f / HH);
    float var = r2.y * (1.0f / HH) - mean * mean;
    float rs = rsqrtf(var + 1e-7f);
    float* o = out + (size_t)row * HH;
    for (int i = t; i < HH; i += 256) o[i] = (r[i] - mean) * rs;
}

__global__ __launch_bounds__(256) void k_rel_ln(const float* __restrict__ rel_emb,
                                                const float* __restrict__ g,
                                                const float* __restrict__ b,
                                                float* __restrict__ out) {
    int row = blockIdx.x, t = threadIdx.x;
    const float* r = rel_emb + (size_t)row * HH;
    float s = 0.f, ss = 0.f;
    for (int i = t; i < HH; i += 256) {
        float v = r[i];
        s += v; ss += v * v;
    }
    float2 r2 = blockReduceSum2(s, ss);
    float mean = r2.x * (1.0f / HH);
    float var = r2.y * (1.0f / HH) - mean * mean;
    float rs = rsqrtf(var + 1e-7f);
    float* o = out + (size_t)row * HH;
    for (int i = t; i < HH; i += 256) o[i] = (r[i] - mean) * rs * g[i] + b[i];
}

// ctx_bf = bf16(LN(ctxr * gelu_exact(vg[..., H:])))
__global__ __launch_bounds__(256) void k_gated_ln(const float* __restrict__ ctxr,
                                                  const float* __restrict__ vg,
                                                  unsigned short* __restrict__ out) {
    __shared__ float buf[HH];
    int row = blockIdx.x, t = threadIdx.x;
    const float* cr = ctxr + (size_t)row * HH;
    const float* gr = vg + (size_t)row * (2 * HH) + HH;
    float s = 0.f, ss = 0.f;
    for (int i = t; i < HH; i += 256) {
        float v = cr[i] * gelu_erf(gr[i]);
        buf[i] = v;
        s += v; ss += v * v;
    }
    float2 r2 = blockReduceSum2(s, ss);
    float mean = r2.x * (1.0f / HH);
    float var = r2.y * (1.0f / HH) - mean * mean;
    float rs = rsqrtf(var + 1e-7f);
    unsigned short* o = out + (size_t)row * HH;
    for (int i = t; i < HH; i += 256) o[i] = f2b((buf[i] - mean) * rs);
}

// h2_bf = bf16(LN(ffh[:, :I] * gelu_tanh(ffh[:, I:])))
__global__ __launch_bounds__(256) void k_ffn_ln(const float* __restrict__ ffh,
                                                unsigned short* __restrict__ out) {
    __shared__ float buf[II];
    int row = blockIdx.x, t = threadIdx.x;
    const float* ar = ffh + (size_t)row * (2 * II);
    const float* gr = ar + II;
    float s = 0.f, ss = 0.f;
    for (int i = t; i < II; i += 256) {
        float v = ar[i] * gelu_tanh(gr[i]);
        buf[i] = v;
        s += v; ss += v * v;
    }
    float2 r2 = blockReduceSum2(s, ss);
    float mean = r2.x * (1.0f / II);
    float var = r2.y * (1.0f / II) - mean * mean;
    float rs = rsqrtf(var + 1e-7f);
    unsigned short* o = out + (size_t)row * II;
    for (int i = t; i < II; i += 256) o[i] = f2b((buf[i] - mean) * rs);
}

// ---------------------------------------------------------------------------
// bf16 MFMA GEMM (m97 structure): C[M,N] = A[M,K] * W[N,K]^T (+bias) (+res)
// 128x128 tile, BK=32, 4 waves (2x2), each wave 64x64 via 4x4 frags of
// mfma_f32_16x16x32_bf16. global_load_lds width-16 staging, linear LDS.
// Requires M%128==0, N%128==0, K%32==0, lda/ldw %8==0.
// ---------------------------------------------------------------------------
__global__ __launch_bounds__(256) void k_gemm_bf16(const unsigned short* __restrict__ A, int lda,
                                                   const unsigned short* __restrict__ W, int ldw,
                                                   float* __restrict__ C, int ldc,
                                                   int M, int N, int K,
                                                   const float* __restrict__ bias,
                                                   const float* __restrict__ res) {
    __shared__ unsigned short As[128 * 32];
    __shared__ unsigned short Ws[128 * 32];
    const int t = threadIdx.x;
    const int lane = t & 63, wid = t >> 6;
    const int row0 = blockIdx.y * 128, col0 = blockIdx.x * 128;
    const int wr = (wid >> 1) * 64, wc = (wid & 1) * 64;
    const int rA = lane & 15, kA = (lane >> 4) * 8;

    f32x4 acc[4][4] = {};

    for (int k0 = 0; k0 < K; k0 += 32) {
        // stage A,B tiles: 512 chunks of 16B each; thread t covers chunks t, t+256
#pragma unroll
        for (int j = 0; j < 2; ++j) {
            int c = t + j * 256;                 // chunk id = lds dest order
            int r = c >> 2, ko = (c & 3) * 8;
            const unsigned short* srcA = A + (size_t)(row0 + r) * lda + k0 + ko;
            const unsigned short* srcB = W + (size_t)(col0 + r) * ldw + k0 + ko;
            // wave-uniform LDS base: chunk (j*256 + wid*64), lane adds lane*16
            unsigned short* dstA = As + (size_t)(j * 256 + wid * 64) * 8;
            unsigned short* dstB = Ws + (size_t)(j * 256 + wid * 64) * 8;
            __builtin_amdgcn_global_load_lds(
                (const __attribute__((address_space(1))) void*)srcA,
                (__attribute__((address_space(3))) void*)dstA, 16, 0, 0);
            __builtin_amdgcn_global_load_lds(
                (const __attribute__((address_space(1))) void*)srcB,
                (__attribute__((address_space(3))) void*)dstB, 16, 0, 0);
        }
        __syncthreads();
        bf16x8 af[4], bfr[4];
#pragma unroll
        for (int m = 0; m < 4; ++m)
            af[m] = *(const bf16x8*)&As[(wr + m * 16 + rA) * 32 + kA];
#pragma unroll
        for (int n = 0; n < 4; ++n)
            bfr[n] = *(const bf16x8*)&Ws[(wc + n * 16 + rA) * 32 + kA];
#pragma unroll
        for (int m = 0; m < 4; ++m)
#pragma unroll
            for (int n = 0; n < 4; ++n)
                acc[m][n] = __builtin_amdgcn_mfma_f32_16x16x32_bf16(af[m], bfr[n], acc[m][n], 0, 0, 0);
        __syncthreads();
    }

    // epilogue: C/D layout col=lane&15, row=(lane>>4)*4+i  [m89]
    const int cl = lane & 15, rg = (lane >> 4) * 4;
#pragma unroll
    for (int n = 0; n < 4; ++n) {
        int gc = col0 + wc + n * 16 + cl;
        float bv = bias ? bias[gc] : 0.0f;
#pragma unroll
        for (int m = 0; m < 4; ++m) {
#pragma unroll
            for (int i = 0; i < 4; ++i) {
                int gr = row0 + wr + m * 16 + rg + i;
                float v = acc[m][n][i] + bv;
                if (res) v += res[(size_t)gr * ldc + gc];
                C[(size_t)gr * ldc + gc] = v;
            }
        }
    }
}

// ---------------------------------------------------------------------------
// fp32 fallback GEMM (used only for the 63-row posproj)
// ---------------------------------------------------------------------------
__global__ __launch_bounds__(256) void k_gemm_nt(const float* __restrict__ A, int lda,
                                                 const float* __restrict__ W, int ldw,
                                                 float* __restrict__ C, int ldc,
                                                 int M, int N, int K,
                                                 const float* __restrict__ bias,
                                                 const float* __restrict__ res) {
    __shared__ float Asm[32][68];
    __shared__ float Wsm[32][68];
    int bn = blockIdx.x, bm = blockIdx.y;
    int t = threadIdx.x;
    int tx = t & 15, ty = t >> 4;
    float acc[4][4] = {};
    int row0 = bm * 64, col0 = bn * 64;
    for (int kt = 0; kt < K; kt += 32) {
#pragma unroll
        for (int j = 0; j < 2; ++j) {
            int v = t + j * 256;
            int r = v >> 3;
            int c4 = v & 7;
            int gr = row0 + r;
            if (gr > M - 1) gr = M - 1;
            float4 d = *(const float4*)(A + (size_t)gr * lda + kt + c4 * 4);
            Asm[c4 * 4 + 0][r] = d.x; Asm[c4 * 4 + 1][r] = d.y;
            Asm[c4 * 4 + 2][r] = d.z; Asm[c4 * 4 + 3][r] = d.w;
            float4 e = *(const float4*)(W + (size_t)(col0 + r) * ldw + kt + c4 * 4);
            Wsm[c4 * 4 + 0][r] = e.x; Wsm[c4 * 4 + 1][r] = e.y;
            Wsm[c4 * 4 + 2][r] = e.z; Wsm[c4 * 4 + 3][r] = e.w;
        }
        __syncthreads();
#pragma unroll
        for (int kk = 0; kk < 32; ++kk) {
            float4 av = *(const float4*)&Asm[kk][ty * 4];
            float4 wv = *(const float4*)&Wsm[kk][tx * 4];
            float a_[4] = {av.x, av.y, av.z, av.w};
            float w_[4] = {wv.x, wv.y, wv.z, wv.w};
#pragma unroll
            for (int i = 0; i < 4; ++i)
#pragma unroll
                for (int j = 0; j < 4; ++j) acc[i][j] += a_[i] * w_[j];
        }
        __syncthreads();
    }
#pragma unroll
    for (int i = 0; i < 4; ++i) {
        int gr = row0 + ty * 4 + i;
        if (gr >= M) break;
#pragma unroll
        for (int j = 0; j < 4; ++j) {
            int gc = col0 + tx * 4 + j;
            float v = acc[i][j];
            if (bias) v += bias[gc];
            if (res) v += res[(size_t)gr * ldc + gc];
            C[(size_t)gr * ldc + gc] = v;
        }
    }
}

// ---------------------------------------------------------------------------
// content-content scores (fp32)
// ---------------------------------------------------------------------------
__global__ __launch_bounds__(256) void k_attn_cc(const float* __restrict__ qk,
                                                 float* __restrict__ scores) {
    __shared__ float Qs[64][68];
    __shared__ float Ks[64][68];
    int bh = blockIdx.y;
    int b = bh / NHH, h = bh % NHH;
    int tile = blockIdx.x;
    int qt = tile >> 3, kt = tile & 7;
    int t = threadIdx.x;
    int tx = t & 15, ty = t >> 4;
    const float* qbase = qk + h * DD;
    const float* kbase = qk + HH + h * DD;
#pragma unroll
    for (int j = 0; j < 4; ++j) {
        int v = t + j * 256;
        int r = v >> 4, c4 = v & 15;
        int q = qt * 64 + r;
        float4 d = *(const float4*)(qbase + (size_t)(q * BB + b) * (2 * HH) + c4 * 4);
        Qs[c4 * 4 + 0][r] = d.x; Qs[c4 * 4 + 1][r] = d.y;
        Qs[c4 * 4 + 2][r] = d.z; Qs[c4 * 4 + 3][r] = d.w;
        int k = kt * 64 + r;
        float4 e = *(const float4*)(kbase + (size_t)(k * BB + b) * (2 * HH) + c4 * 4);
        Ks[c4 * 4 + 0][r] = e.x; Ks[c4 * 4 + 1][r] = e.y;
        Ks[c4 * 4 + 2][r] = e.z; Ks[c4 * 4 + 3][r] = e.w;
    }
    __syncthreads();
    float acc[4][4] = {};
#pragma unroll
    for (int kk = 0; kk < 64; ++kk) {
        float4 qv = *(const float4*)&Qs[kk][ty * 4];
        float4 kv = *(const float4*)&Ks[kk][tx * 4];
        float a_[4] = {qv.x, qv.y, qv.z, qv.w};
        float b_[4] = {kv.x, kv.y, kv.z, kv.w};
#pragma unroll
        for (int i = 0; i < 4; ++i)
#pragma unroll
            for (int j = 0; j < 4; ++j) acc[i][j] += a_[i] * b_[j];
    }
    float* out = scores + ((size_t)bh * SS + qt * 64) * SS + kt * 64;
#pragma unroll
    for (int i = 0; i < 4; ++i)
#pragma unroll
        for (int j = 0; j < 4; ++j)
            out[(size_t)(ty * 4 + i) * SS + tx * 4 + j] = acc[i][j];
}

// ---------------------------------------------------------------------------
// cp[q,b,h,r] = qh . kposTab[r,h]  (z=0)   pc[k,b,h,r] = kh . qposTab[r,h]  (z=1)
// ---------------------------------------------------------------------------
__global__ __launch_bounds__(256) void k_cp_pc(const float* __restrict__ qk,
                                               const float* __restrict__ posproj,
                                               float* __restrict__ cp,
                                               float* __restrict__ pc) {
    __shared__ float Tb[63][65];
    __shared__ float Ar[64][68];
    int mt = blockIdx.x, h = blockIdx.y, z = blockIdx.z;
    int t = threadIdx.x;
    int aoff = z ? HH : 0;
    int toff = z ? 0 : HH;
    float* out = z ? pc : cp;
    for (int v = t; v < 1008; v += 256) {
        int r = v >> 4, c4 = v & 15;
        float4 d = *(const float4*)(posproj + (size_t)r * (2 * HH) + toff + h * DD + c4 * 4);
        Tb[r][c4 * 4 + 0] = d.x; Tb[r][c4 * 4 + 1] = d.y;
        Tb[r][c4 * 4 + 2] = d.z; Tb[r][c4 * 4 + 3] = d.w;
    }
#pragma unroll
    for (int j = 0; j < 4; ++j) {
        int v = t + j * 256;
        int m = v >> 4, c4 = v & 15;
        float4 d = *(const float4*)(qk + (size_t)(mt * 64 + m) * (2 * HH) + aoff + h * DD + c4 * 4);
        *(float4*)&Ar[m][c4 * 4] = d;
    }
    __syncthreads();
    for (int i = t; i < 64 * 63; i += 256) {
        int m = i / 63, r = i - m * 63;
        float s = 0.f;
#pragma unroll 16
        for (int d = 0; d < 64; ++d) s += Ar[m][d] * Tb[r][d];
        out[((size_t)(mt * 64 + m) * NHH + h) * 63 + r] = s;
    }
}

// ---------------------------------------------------------------------------
// softmax row
// ---------------------------------------------------------------------------
__global__ __launch_bounds__(256) void k_softmax(float* __restrict__ scores,
                                                 const float* __restrict__ cp,
                                                 const float* __restrict__ pc,
                                                 const int* __restrict__ pos_idx,
                                                 const int* __restrict__ mask) {
    int q = blockIdx.x & 511;
    int bh = blockIdx.x >> 9;
    int b = bh / NHH, h = bh % NHH;
    __shared__ float cps[63];
    int t = threadIdx.x;
    if (t < 63) cps[t] = cp[(((size_t)q * BB + b) * NHH + h) * 63 + t];
    __syncthreads();
    float* row = scores + ((size_t)bh * SS + q) * SS;
    float s[2];
    int msk[2];
#pragma unroll
    for (int u = 0; u < 2; ++u) {
        int k = t + u * 256;
        int id = pos_idx[q * SS + k];
        float v = row[k] + cps[id] + pc[(((size_t)k * BB + b) * NHH + h) * 63 + id];
        msk[u] = mask[b * SS + k];
        s[u] = msk[u] ? -1e9f : v * SCALE_F;
    }
    float m = blockMax(fmaxf(s[0], s[1]));
    float e[2];
    e[0] = expf(s[0] - m);
    e[1] = expf(s[1] - m);
    float sum = blockSum(e[0] + e[1]);
    float inv = 1.0f / sum;
#pragma unroll
    for (int u = 0; u < 2; ++u) {
        int k = t + u * 256;
        row[k] = msk[u] ? 0.0f : e[u] * inv;
    }
}

// ---------------------------------------------------------------------------
// ctxr[q,b,h,d] = sum_k p[b,h,q,k] * vh[k,b,h,d]  (fp32)
// ---------------------------------------------------------------------------
__global__ __launch_bounds__(256) void k_attn_pv(const float* __restrict__ p,
                                                 const float* __restrict__ vg,
                                                 float* __restrict__ ctxr) {
    __shared__ float Ps[64][68];
    __shared__ float Vs[64][68];
    int bh = blockIdx.y;
    int b = bh / NHH, h = bh % NHH;
    int qt = blockIdx.x;
    int t = threadIdx.x;
    int tx = t & 15, ty = t >> 4;
    float acc[4][4] = {};
    const float* prow = p + ((size_t)bh * SS + qt * 64) * SS;
    const float* vbase = vg + h * DD;
    for (int kt0 = 0; kt0 < SS; kt0 += 64) {
#pragma unroll
        for (int j = 0; j < 4; ++j) {
            int v = t + j * 256;
            int r = v >> 4, c4 = v & 15;
            float4 d = *(const float4*)(prow + (size_t)r * SS + kt0 + c4 * 4);
            Ps[c4 * 4 + 0][r] = d.x; Ps[c4 * 4 + 1][r] = d.y;
            Ps[c4 * 4 + 2][r] = d.z; Ps[c4 * 4 + 3][r] = d.w;
            int k = kt0 + r;
            float4 e = *(const float4*)(vbase + (size_t)(k * BB + b) * (2 * HH) + c4 * 4);
            *(float4*)&Vs[r][c4 * 4] = e;
        }
        __syncthreads();
#pragma unroll
        for (int kk = 0; kk < 64; ++kk) {
            float4 pv = *(const float4*)&Ps[kk][ty * 4];
            float4 vv = *(const float4*)&Vs[kk][tx * 4];
            float a_[4] = {pv.x, pv.y, pv.z, pv.w};
            float b_[4] = {vv.x, vv.y, vv.z, vv.w};
#pragma unroll
            for (int i = 0; i < 4; ++i)
#pragma unroll
                for (int j = 0; j < 4; ++j) acc[i][j] += a_[i] * b_[j];
        }
        __syncthreads();
    }
#pragma unroll
    for (int i = 0; i < 4; ++i) {
        int qg = qt * 64 + ty * 4 + i;
#pragma unroll
        for (int j = 0; j < 4; ++j)
            ctxr[(size_t)(qg * BB + b) * HH + h * DD + tx * 4 + j] = acc[i][j];
    }
}

// ---------------------------------------------------------------------------
// host launcher
// ---------------------------------------------------------------------------
static inline void gemm_bf(const unsigned short* A, int lda, const unsigned short* W, int ldw,
                           float* C, int ldc, int M, int N, int K,
                           const float* bias, const float* res, hipStream_t st) {
    dim3 g(N / 128, M / 128);
    k_gemm_bf16<<<g, 256, 0, st>>>(A, lda, W, ldw, C, ldc, M, N, K, bias, res);
}

static inline void f2b_launch(const float* in, unsigned short* out, size_t n, hipStream_t st) {
    int n8 = (int)(n / 8);
    k_f2b<<<(n8 + 255) / 256, 256, 0, st>>>(in, out, n8);
}

extern "C" void kernel_launch(void* const* d_in, const int* in_sizes, int n_in,
                              void* d_out, int out_size, void* d_ws, size_t ws_size,
                              hipStream_t stream) {
    const int* ids = (const int*)d_in[0];
    const unsigned char* maskraw = (const unsigned char*)d_in[1];
    const float* word_emb = (const float*)d_in[2];
    const float* rel_emb = (const float*)d_in[3];
    const float* rel_g = (const float*)d_in[4];
    const float* rel_b = (const float*)d_in[5];
    const float* Wqk = (const float*)d_in[6];
    const float* bqk = (const float*)d_in[7];
    const float* Wvg = (const float*)d_in[8];
    const float* bvg = (const float*)d_in[9];
    const float* Wout = (const float*)d_in[10];
    const float* bout = (const float*)d_in[11];
    const float* W1 = (const float*)d_in[12];
    const float* W2 = (const float*)d_in[13];

    const size_t N_X = (size_t)SS * BB * HH;          // 3,145,728
    const size_t N_QK = (size_t)SS * BB * 2 * HH;     // 6,291,456
    const size_t N_SC = (size_t)BB * NHH * SS * SS;   // 25,165,824
    const size_t N_CP = (size_t)SS * BB * NHH * 63;
    const size_t N_H2 = (size_t)SS * BB * II;         // 8,388,608
    const size_t N_REL = (size_t)63 * HH;
    const size_t N_POSP = (size_t)63 * 2 * HH;
    const size_t N_WQK = (size_t)2 * HH * HH;         // 1,179,648
    const size_t N_WOUT = (size_t)HH * HH;
    const size_t N_W1 = (size_t)2 * II * HH;          // 3,145,728
    const size_t N_W2 = (size_t)HH * II;              // 1,572,864

    float* ws = (float*)d_ws;
    float* x = ws;
    float* qk = x + N_X;
    float* vg = qk + N_QK;
    float* ctxr = vg + N_QK;
    float* cp = ctxr + N_X;
    float* pc = cp + N_CP;
    float* rel = pc + N_CP;
    float* posproj = rel + N_REL;
    float* region = posproj + N_POSP;  // scores / ffh overlap (disjoint phases)
    float* scores = region;
    float* ffh = region;
    unsigned short* bfarea = (unsigned short*)(region + N_SC);
    unsigned short* hs_bf = bfarea;
    unsigned short* ctx_bf = hs_bf + N_X;
    unsigned short* h2_bf = ctx_bf + N_X;
    unsigned short* wqk_bf = h2_bf + N_H2;
    unsigned short* wvg_bf = wqk_bf + N_WQK;
    unsigned short* wout_bf = wvg_bf + N_WQK;
    unsigned short* w1_bf = wout_bf + N_WOUT;
    unsigned short* w2_bf = w1_bf + N_W1;
    int* posidx = (int*)(w2_bf + N_W2);
    int* maski = posidx + SS * SS;

    size_t need_bytes = ((size_t)(maski + BB * SS) - (size_t)d_ws);
    if (ws_size < need_bytes) return;  // ~247 MB required

    // ---- setup ----
    k_decode_mask<<<1, 256, 0, stream>>>(maskraw, maski, BB * SS);
    k_pos_idx<<<(SS * SS + 255) / 256, 256, 0, stream>>>(posidx);
    k_embed_ln<<<SS * BB, 256, 0, stream>>>(ids, word_emb, x);
    k_rel_ln<<<63, 256, 0, stream>>>(rel_emb, rel_g, rel_b, rel);

    for (int l = 0; l < LL; ++l) {
        const float* Wqk_l = Wqk + (size_t)l * N_WQK;
        const float* bqk_l = bqk + (size_t)l * 2 * HH;
        const float* Wvg_l = Wvg + (size_t)l * N_WQK;
        const float* bvg_l = bvg + (size_t)l * 2 * HH;
        const float* Wout_l = Wout + (size_t)l * N_WOUT;
        const float* bout_l = bout + (size_t)l * HH;
        const float* W1_l = W1 + (size_t)l * N_W1;
        const float* W2_l = W2 + (size_t)l * N_W2;

        // weight conversions for this layer
        f2b_launch(Wqk_l, wqk_bf, N_WQK, stream);
        f2b_launch(Wvg_l, wvg_bf, N_WQK, stream);
        f2b_launch(Wout_l, wout_bf, N_WOUT, stream);
        f2b_launch(W1_l, w1_bf, N_W1, stream);
        f2b_launch(W2_l, w2_bf, N_W2, stream);

        // ---- attention ----
        k_ln_bf<<<SS * BB, 256, 0, stream>>>(x, hs_bf, HH);
        gemm_bf(hs_bf, HH, wqk_bf, HH, qk, 2 * HH, SS * BB, 2 * HH, HH, bqk_l, nullptr, stream);
        gemm_bf(hs_bf, HH, wvg_bf, HH, vg, 2 * HH, SS * BB, 2 * HH, HH, bvg_l, nullptr, stream);
        k_gemm_nt<<<dim3((2 * HH) / 64, 1), 256, 0, stream>>>(rel, HH, Wqk_l, HH, posproj, 2 * HH,
                                                              63, 2 * HH, HH, bqk_l, nullptr);
        k_cp_pc<<<dim3(SS * BB / 64, NHH, 2), 256, 0, stream>>>(qk, posproj, cp, pc);
        k_attn_cc<<<dim3(64, BB * NHH), 256, 0, stream>>>(qk, scores);
        k_softmax<<<BB * NHH * SS, 256, 0, stream>>>(scores, cp, pc, posidx, maski);
        k_attn_pv<<<dim3(SS / 64, BB * NHH), 256, 0, stream>>>(scores, vg, ctxr);
        k_gated_ln<<<SS * BB, 256, 0, stream>>>(ctxr, vg, ctx_bf);
        gemm_bf(ctx_bf, HH, wout_bf, HH, x, HH, SS * BB, HH, HH, bout_l, x, stream);

        // ---- GeGLU FFN ----
        k_ln_bf<<<SS * BB, 256, 0, stream>>>(x, hs_bf, HH);
        gemm_bf(hs_bf, HH, w1_bf, HH, ffh, 2 * II, SS * BB, 2 * II, HH, nullptr, nullptr, stream);
        k_ffn_ln<<<SS * BB, 256, 0, stream>>>(ffh, h2_bf);
        gemm_bf(h2_bf, II, w2_bf, II, x, HH, SS * BB, HH, II, nullptr, x, stream);
    }

    hipMemcpyAsync(d_out, x, N_X * sizeof(float), hipMemcpyDeviceToDevice, stream);
}

// Round 3
// 4930.299 us; speedup vs baseline: 3.0270x; 1.3579x over previous
//
#include <hip/hip_runtime.h>
#include <math.h>

#define SS 512
#define BB 8
#define NHH 12
#define DD 64
#define HH 768
#define II 2048
#define LL 12
#define SCALE_F 0.07216878364870323f  /* 1/sqrt(3*64) */

typedef __attribute__((ext_vector_type(8))) short bf16x8;
typedef __attribute__((ext_vector_type(4))) float f32x4;

// f32 -> bf16 (RNE, finite values)
__device__ __forceinline__ unsigned short f2b(float f) {
    union { float f; unsigned int u; } x; x.f = f;
    unsigned int r = x.u + 0x7fffu + ((x.u >> 16) & 1u);
    return (unsigned short)(r >> 16);
}

// ---------------------------------------------------------------------------
// block reduction helpers (blockDim.x == 256)
// ---------------------------------------------------------------------------
__device__ __forceinline__ float2 blockReduceSum2(float a, float b) {
    __shared__ float2 sm[4];
    __shared__ float2 bc;
#pragma unroll
    for (int o = 32; o > 0; o >>= 1) {
        a += __shfl_down(a, o);
        b += __shfl_down(b, o);
    }
    int t = threadIdx.x;
    if ((t & 63) == 0) sm[t >> 6] = make_float2(a, b);
    __syncthreads();
    if (t == 0) {
        float xa = sm[0].x + sm[1].x + sm[2].x + sm[3].x;
        float xb = sm[0].y + sm[1].y + sm[2].y + sm[3].y;
        bc = make_float2(xa, xb);
    }
    __syncthreads();
    return bc;
}

__device__ __forceinline__ float gelu_erf(float v) {
    return 0.5f * v * (1.0f + erff(v * 0.70710678118654752f));
}
__device__ __forceinline__ float gelu_tanh(float v) {
    const float c = 0.7978845608028654f;
    return 0.5f * v * (1.0f + tanhf(c * (v + 0.044715f * v * v * v)));
}

// ---------------------------------------------------------------------------
// mask decode: handle bool-as-u8 or bool-as-int32 layouts
// ---------------------------------------------------------------------------
__global__ __launch_bounds__(256) void k_decode_mask(const unsigned char* __restrict__ raw,
                                                     int* __restrict__ mask, int n) {
    __shared__ int s_any;
    if (threadIdx.x == 0) s_any = 0;
    __syncthreads();
    int local = 0;
    for (int i = threadIdx.x; i < n; i += blockDim.x)
        if ((i & 3) && raw[i]) local = 1;
    if (local) atomicOr(&s_any, 1);
    __syncthreads();
    bool isU8 = (s_any != 0);
    const int* as_int = (const int*)raw;
    for (int i = threadIdx.x; i < n; i += blockDim.x)
        mask[i] = isU8 ? (raw[i] != 0) : (as_int[i] != 0);
}

// ---------------------------------------------------------------------------
// DeBERTa log-bucket table: rel in [-511,511] -> idx in [0,62]
// ---------------------------------------------------------------------------
__global__ __launch_bounds__(256) void k_bucket(int* __restrict__ tab) {
    int i = blockIdx.x * 256 + threadIdx.x;
    if (i >= 1023) return;
    int rel = i - 511;
    int a = rel < 0 ? -rel : rel;
    int abs_pos = (a < 16) ? 15 : (a < 511 ? a : 511);
    int bucket;
    if (abs_pos <= 16) {
        bucket = rel;
    } else {
        double lp = ceil(log((double)abs_pos / 16.0) / log(511.0 / 16.0) * 15.0);
        int l = (int)lp + 16;
        bucket = (rel > 0) ? l : -l;
    }
    int idx = bucket + 31;
    if (idx < 0) idx = 0;
    if (idx > 62) idx = 62;
    tab[i] = idx;
}

// ---------------------------------------------------------------------------
// f32 -> bf16 bulk conversion (8 elems/thread)
// ---------------------------------------------------------------------------
__global__ __launch_bounds__(256) void k_f2b(const float* __restrict__ in,
                                             unsigned short* __restrict__ out, int n8) {
    int i = blockIdx.x * 256 + threadIdx.x;
    if (i >= n8) return;
    float4 a = ((const float4*)in)[2 * i];
    float4 b = ((const float4*)in)[2 * i + 1];
    ushort4 lo, hi;
    lo.x = f2b(a.x); lo.y = f2b(a.y); lo.z = f2b(a.z); lo.w = f2b(a.w);
    hi.x = f2b(b.x); hi.y = f2b(b.y); hi.z = f2b(b.z); hi.w = f2b(b.w);
    ((ushort4*)out)[2 * i] = lo;
    ((ushort4*)out)[2 * i + 1] = hi;
}

// ---------------------------------------------------------------------------
// LayerNorm family; EPS = 1e-7, biased variance
// ---------------------------------------------------------------------------
__global__ __launch_bounds__(256) void k_ln_bf(const float* __restrict__ in,
                                               unsigned short* __restrict__ out, int width) {
    int row = blockIdx.x, t = threadIdx.x;
    const float* r = in + (size_t)row * width;
    float s = 0.f, ss = 0.f;
    for (int i = t; i < width; i += 256) {
        float v = r[i];
        s += v; ss += v * v;
    }
    float2 r2 = blockReduceSum2(s, ss);
    float inv = 1.0f / (float)width;
    float mean = r2.x * inv;
    float var = r2.y * inv - mean * mean;
    float rs = rsqrtf(var + 1e-7f);
    unsigned short* o = out + (size_t)row * width;
    for (int i = t; i < width; i += 256) o[i] = f2b((r[i] - mean) * rs);
}

__global__ __launch_bounds__(256) void k_embed_ln(const int* __restrict__ ids,
                                                  const float* __restrict__ emb,
                                                  float* __restrict__ out) {
    int row = blockIdx.x, t = threadIdx.x;
    const float* r = emb + (size_t)ids[row] * HH;
    float s = 0.f, ss = 0.f;
    for (int i = t; i < HH; i += 256) {
        float v = r[i];
        s += v; ss += v * v;
    }
    float2 r2 = blockReduceSum2(s, ss);
    float mean = r2.x * (1.0f / HH);
    float var = r2.y * (1.0f / HH) - mean * mean;
    float rs = rsqrtf(var + 1e-7f);
    float* o = out + (size_t)row * HH;
    for (int i = t; i < HH; i += 256) o[i] = (r[i] - mean) * rs;
}

__global__ __launch_bounds__(256) void k_rel_ln(const float* __restrict__ rel_emb,
                                                const float* __restrict__ g,
                                                const float* __restrict__ b,
                                                float* __restrict__ out) {
    int row = blockIdx.x, t = threadIdx.x;
    const float* r = rel_emb + (size_t)row * HH;
    float s = 0.f, ss = 0.f;
    for (int i = t; i < HH; i += 256) {
        float v = r[i];
        s += v; ss += v * v;
    }
    float2 r2 = blockReduceSum2(s, ss);
    float mean = r2.x * (1.0f / HH);
    float var = r2.y * (1.0f / HH) - mean * mean;
    float rs = rsqrtf(var + 1e-7f);
    float* o = out + (size_t)row * HH;
    for (int i = t; i < HH; i += 256) o[i] = (r[i] - mean) * rs * g[i] + b[i];
}

// ctx_bf = bf16(LN(ctxr * gelu_exact(vg[..., H:])))
__global__ __launch_bounds__(256) void k_gated_ln(const float* __restrict__ ctxr,
                                                  const float* __restrict__ vg,
                                                  unsigned short* __restrict__ out) {
    __shared__ float buf[HH];
    int row = blockIdx.x, t = threadIdx.x;
    const float* cr = ctxr + (size_t)row * HH;
    const float* gr = vg + (size_t)row * (2 * HH) + HH;
    float s = 0.f, ss = 0.f;
    for (int i = t; i < HH; i += 256) {
        float v = cr[i] * gelu_erf(gr[i]);
        buf[i] = v;
        s += v; ss += v * v;
    }
    float2 r2 = blockReduceSum2(s, ss);
    float mean = r2.x * (1.0f / HH);
    float var = r2.y * (1.0f / HH) - mean * mean;
    float rs = rsqrtf(var + 1e-7f);
    unsigned short* o = out + (size_t)row * HH;
    for (int i = t; i < HH; i += 256) o[i] = f2b((buf[i] - mean) * rs);
}

// h2_bf = bf16(LN(ffh[:, :I] * gelu_tanh(ffh[:, I:])))
__global__ __launch_bounds__(256) void k_ffn_ln(const float* __restrict__ ffh,
                                                unsigned short* __restrict__ out) {
    __shared__ float buf[II];
    int row = blockIdx.x, t = threadIdx.x;
    const float* ar = ffh + (size_t)row * (2 * II);
    const float* gr = ar + II;
    float s = 0.f, ss = 0.f;
    for (int i = t; i < II; i += 256) {
        float v = ar[i] * gelu_tanh(gr[i]);
        buf[i] = v;
        s += v; ss += v * v;
    }
    float2 r2 = blockReduceSum2(s, ss);
    float mean = r2.x * (1.0f / II);
    float var = r2.y * (1.0f / II) - mean * mean;
    float rs = rsqrtf(var + 1e-7f);
    unsigned short* o = out + (size_t)row * II;
    for (int i = t; i < II; i += 256) o[i] = f2b((buf[i] - mean) * rs);
}

// ---------------------------------------------------------------------------
// bf16 MFMA GEMM (m97 structure): C[M,N] = A[M,K] * W[N,K]^T (+bias) (+res)
// ---------------------------------------------------------------------------
__global__ __launch_bounds__(256) void k_gemm_bf16(const unsigned short* __restrict__ A, int lda,
                                                   const unsigned short* __restrict__ W, int ldw,
                                                   float* __restrict__ C, int ldc,
                                                   int M, int N, int K,
                                                   const float* __restrict__ bias,
                                                   const float* __restrict__ res) {
    __shared__ unsigned short As[128 * 32];
    __shared__ unsigned short Ws[128 * 32];
    const int t = threadIdx.x;
    const int lane = t & 63, wid = t >> 6;
    const int row0 = blockIdx.y * 128, col0 = blockIdx.x * 128;
    const int wr = (wid >> 1) * 64, wc = (wid & 1) * 64;
    const int rA = lane & 15, kA = (lane >> 4) * 8;

    f32x4 acc[4][4] = {};

    for (int k0 = 0; k0 < K; k0 += 32) {
#pragma unroll
        for (int j = 0; j < 2; ++j) {
            int c = t + j * 256;
            int r = c >> 2, ko = (c & 3) * 8;
            const unsigned short* srcA = A + (size_t)(row0 + r) * lda + k0 + ko;
            const unsigned short* srcB = W + (size_t)(col0 + r) * ldw + k0 + ko;
            unsigned short* dstA = As + (size_t)(j * 256 + wid * 64) * 8;
            unsigned short* dstB = Ws + (size_t)(j * 256 + wid * 64) * 8;
            __builtin_amdgcn_global_load_lds(
                (const __attribute__((address_space(1))) void*)srcA,
                (__attribute__((address_space(3))) void*)dstA, 16, 0, 0);
            __builtin_amdgcn_global_load_lds(
                (const __attribute__((address_space(1))) void*)srcB,
                (__attribute__((address_space(3))) void*)dstB, 16, 0, 0);
        }
        __syncthreads();
        bf16x8 af[4], bfr[4];
#pragma unroll
        for (int m = 0; m < 4; ++m)
            af[m] = *(const bf16x8*)&As[(wr + m * 16 + rA) * 32 + kA];
#pragma unroll
        for (int n = 0; n < 4; ++n)
            bfr[n] = *(const bf16x8*)&Ws[(wc + n * 16 + rA) * 32 + kA];
#pragma unroll
        for (int m = 0; m < 4; ++m)
#pragma unroll
            for (int n = 0; n < 4; ++n)
                acc[m][n] = __builtin_amdgcn_mfma_f32_16x16x32_bf16(af[m], bfr[n], acc[m][n], 0, 0, 0);
        __syncthreads();
    }

    const int cl = lane & 15, rg = (lane >> 4) * 4;
#pragma unroll
    for (int n = 0; n < 4; ++n) {
        int gc = col0 + wc + n * 16 + cl;
        float bv = bias ? bias[gc] : 0.0f;
#pragma unroll
        for (int m = 0; m < 4; ++m) {
#pragma unroll
            for (int i = 0; i < 4; ++i) {
                int gr = row0 + wr + m * 16 + rg + i;
                float v = acc[m][n][i] + bv;
                if (res) v += res[(size_t)gr * ldc + gc];
                C[(size_t)gr * ldc + gc] = v;
            }
        }
    }
}

// ---------------------------------------------------------------------------
// fp32 fallback GEMM (used only for the 63-row posproj)
// ---------------------------------------------------------------------------
__global__ __launch_bounds__(256) void k_gemm_nt(const float* __restrict__ A, int lda,
                                                 const float* __restrict__ W, int ldw,
                                                 float* __restrict__ C, int ldc,
                                                 int M, int N, int K,
                                                 const float* __restrict__ bias,
                                                 const float* __restrict__ res) {
    __shared__ float Asm[32][68];
    __shared__ float Wsm[32][68];
    int bn = blockIdx.x, bm = blockIdx.y;
    int t = threadIdx.x;
    int tx = t & 15, ty = t >> 4;
    float acc[4][4] = {};
    int row0 = bm * 64, col0 = bn * 64;
    for (int kt = 0; kt < K; kt += 32) {
#pragma unroll
        for (int j = 0; j < 2; ++j) {
            int v = t + j * 256;
            int r = v >> 3;
            int c4 = v & 7;
            int gr = row0 + r;
            if (gr > M - 1) gr = M - 1;
            float4 d = *(const float4*)(A + (size_t)gr * lda + kt + c4 * 4);
            Asm[c4 * 4 + 0][r] = d.x; Asm[c4 * 4 + 1][r] = d.y;
            Asm[c4 * 4 + 2][r] = d.z; Asm[c4 * 4 + 3][r] = d.w;
            float4 e = *(const float4*)(W + (size_t)(col0 + r) * ldw + kt + c4 * 4);
            Wsm[c4 * 4 + 0][r] = e.x; Wsm[c4 * 4 + 1][r] = e.y;
            Wsm[c4 * 4 + 2][r] = e.z; Wsm[c4 * 4 + 3][r] = e.w;
        }
        __syncthreads();
#pragma unroll
        for (int kk = 0; kk < 32; ++kk) {
            float4 av = *(const float4*)&Asm[kk][ty * 4];
            float4 wv = *(const float4*)&Wsm[kk][tx * 4];
            float a_[4] = {av.x, av.y, av.z, av.w};
            float w_[4] = {wv.x, wv.y, wv.z, wv.w};
#pragma unroll
            for (int i = 0; i < 4; ++i)
#pragma unroll
                for (int j = 0; j < 4; ++j) acc[i][j] += a_[i] * w_[j];
        }
        __syncthreads();
    }
#pragma unroll
    for (int i = 0; i < 4; ++i) {
        int gr = row0 + ty * 4 + i;
        if (gr >= M) break;
#pragma unroll
        for (int j = 0; j < 4; ++j) {
            int gc = col0 + tx * 4 + j;
            float v = acc[i][j];
            if (bias) v += bias[gc];
            if (res) v += res[(size_t)gr * ldc + gc];
            C[(size_t)gr * ldc + gc] = v;
        }
    }
}

// ---------------------------------------------------------------------------
// repack: qk f32 [s*B, 2H] -> qT,kT bf16 [b,h,s,d]
// ---------------------------------------------------------------------------
__global__ __launch_bounds__(256) void k_repack_qk(const float* __restrict__ qk,
                                                   unsigned short* __restrict__ qT,
                                                   unsigned short* __restrict__ kT) {
    int bh = blockIdx.y;
    int b = bh / NHH, h = bh % NHH;
    int s0 = blockIdx.x * 64;
    int t = threadIdx.x;
#pragma unroll
    for (int j = 0; j < 2; ++j) {
        int idx = t + j * 256;          // 0..511
        int r = idx >> 3, dc = idx & 7; // row in s-tile, d-chunk of 8
        const float* src = qk + ((size_t)(s0 + r) * BB + b) * (2 * HH) + h * DD + dc * 8;
        float4 a = *(const float4*)src;
        float4 c = *(const float4*)(src + 4);
        ushort4 lo, hi;
        lo.x = f2b(a.x); lo.y = f2b(a.y); lo.z = f2b(a.z); lo.w = f2b(a.w);
        hi.x = f2b(c.x); hi.y = f2b(c.y); hi.z = f2b(c.z); hi.w = f2b(c.w);
        unsigned short* dq = qT + ((size_t)bh * SS + s0 + r) * DD + dc * 8;
        *(ushort4*)dq = lo; *(ushort4*)(dq + 4) = hi;
        const float* srck = src + HH;
        float4 a2 = *(const float4*)srck;
        float4 c2 = *(const float4*)(srck + 4);
        ushort4 lo2, hi2;
        lo2.x = f2b(a2.x); lo2.y = f2b(a2.y); lo2.z = f2b(a2.z); lo2.w = f2b(a2.w);
        hi2.x = f2b(c2.x); hi2.y = f2b(c2.y); hi2.z = f2b(c2.z); hi2.w = f2b(c2.w);
        unsigned short* dk = kT + ((size_t)bh * SS + s0 + r) * DD + dc * 8;
        *(ushort4*)dk = lo2; *(ushort4*)(dk + 4) = hi2;
    }
}

// ---------------------------------------------------------------------------
// repack: vg f32 [s*B, 2H] (v half) -> vT bf16 [b,h,d,s] (transposed)
// ---------------------------------------------------------------------------
__global__ __launch_bounds__(256) void k_repack_vT(const float* __restrict__ vg,
                                                   unsigned short* __restrict__ vT) {
    __shared__ unsigned short tile[64][72];
    int bh = blockIdx.y;
    int b = bh / NHH, h = bh % NHH;
    int s0 = blockIdx.x * 64;
    int t = threadIdx.x;
#pragma unroll
    for (int j = 0; j < 4; ++j) {
        int idx = t + j * 256;          // 0..1023
        int r = idx >> 4, c4 = idx & 15;
        float4 d = *(const float4*)(vg + ((size_t)(s0 + r) * BB + b) * (2 * HH) + h * DD + c4 * 4);
        ushort4 u;
        u.x = f2b(d.x); u.y = f2b(d.y); u.z = f2b(d.z); u.w = f2b(d.w);
        *(ushort4*)&tile[r][c4 * 4] = u;
    }
    __syncthreads();
#pragma unroll
    for (int j = 0; j < 2; ++j) {
        int idx = t + j * 256;          // 0..511
        int d = idx >> 3, s8 = idx & 7;
        ushort4 a, c;
        a.x = tile[s8 * 8 + 0][d]; a.y = tile[s8 * 8 + 1][d];
        a.z = tile[s8 * 8 + 2][d]; a.w = tile[s8 * 8 + 3][d];
        c.x = tile[s8 * 8 + 4][d]; c.y = tile[s8 * 8 + 5][d];
        c.z = tile[s8 * 8 + 6][d]; c.w = tile[s8 * 8 + 7][d];
        unsigned short* dst = vT + ((size_t)bh * DD + d) * SS + s0 + s8 * 8;
        *(ushort4*)dst = a; *(ushort4*)(dst + 4) = c;
    }
}

// ---------------------------------------------------------------------------
// cp[b,h,q,r] = qh . kposTab[r,h]  (z=0)   pc[b,h,k,r] = kh . qposTab[r,h]  (z=1)
// ---------------------------------------------------------------------------
__global__ __launch_bounds__(256) void k_cp_pc(const float* __restrict__ qk,
                                               const float* __restrict__ posproj,
                                               float* __restrict__ cp,
                                               float* __restrict__ pc) {
    __shared__ float Tb[63][65];
    __shared__ float Ar[64][68];
    int mt = blockIdx.x, h = blockIdx.y, z = blockIdx.z;
    int t = threadIdx.x;
    int aoff = z ? HH : 0;
    int toff = z ? 0 : HH;
    float* out = z ? pc : cp;
    for (int v = t; v < 1008; v += 256) {
        int r = v >> 4, c4 = v & 15;
        float4 d = *(const float4*)(posproj + (size_t)r * (2 * HH) + toff + h * DD + c4 * 4);
        Tb[r][c4 * 4 + 0] = d.x; Tb[r][c4 * 4 + 1] = d.y;
        Tb[r][c4 * 4 + 2] = d.z; Tb[r][c4 * 4 + 3] = d.w;
    }
#pragma unroll
    for (int j = 0; j < 4; ++j) {
        int v = t + j * 256;
        int m = v >> 4, c4 = v & 15;
        float4 d = *(const float4*)(qk + (size_t)(mt * 64 + m) * (2 * HH) + aoff + h * DD + c4 * 4);
        *(float4*)&Ar[m][c4 * 4] = d;
    }
    __syncthreads();
    for (int i = t; i < 64 * 63; i += 256) {
        int m = i / 63, r = i - m * 63;
        float s = 0.f;
#pragma unroll 16
        for (int d = 0; d < 64; ++d) s += Ar[m][d] * Tb[r][d];
        int row = mt * 64 + m;          // row = s*B + b
        int sIdx = row >> 3, bIdx = row & 7;
        out[(((size_t)(bIdx * NHH + h)) * SS + sIdx) * 63 + r] = s;
    }
}

// ---------------------------------------------------------------------------
// fused disentangled flash attention:
//   per (bh, qtile of 128): 4 waves x 32 q-rows, KBLK=64, online softmax.
//   S = Q.K^T (MFMA) + cp[q,id] + pc[k,id], id = bucket[q-k+511]; mask -> -1e9
//   P -> bf16 via LDS transpose; O += P.V (MFMA, V^T from global)
// ---------------------------------------------------------------------------
__global__ __launch_bounds__(256) void k_attn_fused(
    const unsigned short* __restrict__ qT, const unsigned short* __restrict__ kT,
    const unsigned short* __restrict__ vT, const float* __restrict__ cp,
    const float* __restrict__ pc, const int* __restrict__ bucket,
    const int* __restrict__ mask, float* __restrict__ ctxr) {
    __shared__ unsigned short pb_all[4][32 * 72];
    __shared__ int btab[1023];
    int t = threadIdx.x;
    for (int i = t; i < 1023; i += 256) btab[i] = bucket[i];
    __syncthreads();
    int lane = t & 63, wid = t >> 6;
    int bh = blockIdx.y;
    int b = bh / NHH, h = bh % NHH;
    int q0 = blockIdx.x * 128 + wid * 32;
    int rA = lane & 15, g = lane >> 4, kA = g * 8;
    unsigned short* pb = pb_all[wid];
    const unsigned short* qTb = qT + (size_t)bh * SS * DD;
    const unsigned short* kTb = kT + (size_t)bh * SS * DD;
    const unsigned short* vTb = vT + (size_t)bh * DD * SS;
    const float* cpb = cp + (size_t)bh * SS * 63;
    const float* pcb = pc + (size_t)bh * SS * 63;
    const int* mkb = mask + b * SS;

    bf16x8 aq[2][2];
#pragma unroll
    for (int m = 0; m < 2; ++m)
#pragma unroll
        for (int dc = 0; dc < 2; ++dc)
            aq[m][dc] = *(const bf16x8*)&qTb[(size_t)(q0 + m * 16 + rA) * DD + dc * 32 + kA];

    f32x4 o[2][4] = {};
    float mrow[2][4], lrow[2][4];
#pragma unroll
    for (int m = 0; m < 2; ++m)
#pragma unroll
        for (int i = 0; i < 4; ++i) { mrow[m][i] = -INFINITY; lrow[m][i] = 0.f; }

    for (int kt = 0; kt < 8; ++kt) {
        int k0 = kt * 64;
        // ---- S = Q.K^T ----
        f32x4 sa[2][4] = {};
#pragma unroll
        for (int n = 0; n < 4; ++n) {
            bf16x8 bk0 = *(const bf16x8*)&kTb[(size_t)(k0 + n * 16 + rA) * DD + kA];
            bf16x8 bk1 = *(const bf16x8*)&kTb[(size_t)(k0 + n * 16 + rA) * DD + 32 + kA];
#pragma unroll
            for (int m = 0; m < 2; ++m) {
                sa[m][n] = __builtin_amdgcn_mfma_f32_16x16x32_bf16(aq[m][0], bk0, sa[m][n], 0, 0, 0);
                sa[m][n] = __builtin_amdgcn_mfma_f32_16x16x32_bf16(aq[m][1], bk1, sa[m][n], 0, 0, 0);
            }
        }
        int mk[4];
#pragma unroll
        for (int n = 0; n < 4; ++n) mk[n] = mkb[k0 + n * 16 + rA];

        // ---- bias + mask + online softmax ----
        float pv[2][4][4];
#pragma unroll
        for (int m = 0; m < 2; ++m) {
#pragma unroll
            for (int i = 0; i < 4; ++i) {
                int q = q0 + m * 16 + g * 4 + i;
                float sv[4];
                float tmax = -INFINITY;
#pragma unroll
                for (int n = 0; n < 4; ++n) {
                    int k = k0 + n * 16 + rA;
                    int id = btab[q - k + 511];
                    float v = (sa[m][n][i] + cpb[q * 63 + id] + pcb[k * 63 + id]) * SCALE_F;
                    v = mk[n] ? -1e9f : v;
                    sv[n] = v;
                    tmax = fmaxf(tmax, v);
                }
                tmax = fmaxf(tmax, __shfl_xor(tmax, 1, 16));
                tmax = fmaxf(tmax, __shfl_xor(tmax, 2, 16));
                tmax = fmaxf(tmax, __shfl_xor(tmax, 4, 16));
                tmax = fmaxf(tmax, __shfl_xor(tmax, 8, 16));
                float mold = mrow[m][i];
                float mnew = fmaxf(mold, tmax);
                float alpha = __expf(mold - mnew);
                float ls = 0.f;
#pragma unroll
                for (int n = 0; n < 4; ++n) {
                    float p = __expf(sv[n] - mnew);
                    pv[m][n][i] = p;
                    ls += p;
                }
                ls += __shfl_xor(ls, 1, 16);
                ls += __shfl_xor(ls, 2, 16);
                ls += __shfl_xor(ls, 4, 16);
                ls += __shfl_xor(ls, 8, 16);
                lrow[m][i] = lrow[m][i] * alpha + ls;
                mrow[m][i] = mnew;
#pragma unroll
                for (int n = 0; n < 4; ++n) o[m][n][i] *= alpha;
            }
        }
        // ---- P -> bf16 via LDS (C-layout -> A-layout transpose) ----
#pragma unroll
        for (int m = 0; m < 2; ++m)
#pragma unroll
            for (int n = 0; n < 4; ++n)
#pragma unroll
                for (int i = 0; i < 4; ++i)
                    pb[(m * 16 + g * 4 + i) * 72 + n * 16 + rA] = f2b(pv[m][n][i]);
        // ---- O += P.V ----
        bf16x8 ap[2][2];
#pragma unroll
        for (int m = 0; m < 2; ++m)
#pragma unroll
            for (int kc = 0; kc < 2; ++kc)
                ap[m][kc] = *(const bf16x8*)&pb[(m * 16 + rA) * 72 + kc * 32 + kA];
#pragma unroll
        for (int n = 0; n < 4; ++n) {
            bf16x8 bv0 = *(const bf16x8*)&vTb[(size_t)(n * 16 + rA) * SS + k0 + kA];
            bf16x8 bv1 = *(const bf16x8*)&vTb[(size_t)(n * 16 + rA) * SS + k0 + 32 + kA];
#pragma unroll
            for (int m = 0; m < 2; ++m) {
                o[m][n] = __builtin_amdgcn_mfma_f32_16x16x32_bf16(ap[m][0], bv0, o[m][n], 0, 0, 0);
                o[m][n] = __builtin_amdgcn_mfma_f32_16x16x32_bf16(ap[m][1], bv1, o[m][n], 0, 0, 0);
            }
        }
    }
    // ---- epilogue: ctxr[q,b,h,d] = O / l ----
#pragma unroll
    for (int m = 0; m < 2; ++m)
#pragma unroll
        for (int i = 0; i < 4; ++i) {
            int q = q0 + m * 16 + g * 4 + i;
            float inv = 1.0f / lrow[m][i];
#pragma unroll
            for (int n = 0; n < 4; ++n)
                ctxr[((size_t)q * BB + b) * HH + h * DD + n * 16 + rA] = o[m][n][i] * inv;
        }
}

// ---------------------------------------------------------------------------
// host launcher
// ---------------------------------------------------------------------------
static inline void gemm_bf(const unsigned short* A, int lda, const unsigned short* W, int ldw,
                           float* C, int ldc, int M, int N, int K,
                           const float* bias, const float* res, hipStream_t st) {
    dim3 g(N / 128, M / 128);
    k_gemm_bf16<<<g, 256, 0, st>>>(A, lda, W, ldw, C, ldc, M, N, K, bias, res);
}

static inline void f2b_launch(const float* in, unsigned short* out, size_t n, hipStream_t st) {
    int n8 = (int)(n / 8);
    k_f2b<<<(n8 + 255) / 256, 256, 0, st>>>(in, out, n8);
}

extern "C" void kernel_launch(void* const* d_in, const int* in_sizes, int n_in,
                              void* d_out, int out_size, void* d_ws, size_t ws_size,
                              hipStream_t stream) {
    const int* ids = (const int*)d_in[0];
    const unsigned char* maskraw = (const unsigned char*)d_in[1];
    const float* word_emb = (const float*)d_in[2];
    const float* rel_emb = (const float*)d_in[3];
    const float* rel_g = (const float*)d_in[4];
    const float* rel_b = (const float*)d_in[5];
    const float* Wqk = (const float*)d_in[6];
    const float* bqk = (const float*)d_in[7];
    const float* Wvg = (const float*)d_in[8];
    const float* bvg = (const float*)d_in[9];
    const float* Wout = (const float*)d_in[10];
    const float* bout = (const float*)d_in[11];
    const float* W1 = (const float*)d_in[12];
    const float* W2 = (const float*)d_in[13];

    const size_t N_X = (size_t)SS * BB * HH;
    const size_t N_QK = (size_t)SS * BB * 2 * HH;
    const size_t N_CP = (size_t)SS * BB * NHH * 63;
    const size_t N_FFH = (size_t)SS * BB * 2 * II;
    const size_t N_H2 = (size_t)SS * BB * II;
    const size_t N_REL = (size_t)63 * HH;
    const size_t N_POSP = (size_t)63 * 2 * HH;
    const size_t N_WQK = (size_t)2 * HH * HH;
    const size_t N_WOUT = (size_t)HH * HH;
    const size_t N_W1 = (size_t)2 * II * HH;
    const size_t N_W2 = (size_t)HH * II;
    const size_t N_HD = (size_t)BB * NHH * SS * DD;   // 3,145,728

    float* ws = (float*)d_ws;
    float* x = ws;
    float* qk = x + N_X;
    float* vg = qk + N_QK;
    float* ctxr = vg + N_QK;
    float* cp = ctxr + N_X;
    float* pc = cp + N_CP;
    float* rel = pc + N_CP;
    float* posproj = rel + N_REL;
    float* ffh = posproj + N_POSP;
    unsigned short* bfarea = (unsigned short*)(ffh + N_FFH);
    unsigned short* hs_bf = bfarea;
    unsigned short* ctx_bf = hs_bf + N_X;
    unsigned short* h2_bf = ctx_bf + N_X;
    unsigned short* wqk_bf = h2_bf + N_H2;
    unsigned short* wvg_bf = wqk_bf + N_WQK;
    unsigned short* wout_bf = wvg_bf + N_WQK;
    unsigned short* w1_bf = wout_bf + N_WOUT;
    unsigned short* w2_bf = w1_bf + N_W1;
    unsigned short* qT = w2_bf + N_W2;
    unsigned short* kT = qT + N_HD;
    unsigned short* vT = kT + N_HD;
    int* bucket = (int*)(vT + N_HD);
    int* maski = bucket + 1024;

    size_t need_bytes = ((size_t)(maski + BB * SS) - (size_t)d_ws);
    if (ws_size < need_bytes) return;  // ~232 MB required

    // ---- setup ----
    k_decode_mask<<<1, 256, 0, stream>>>(maskraw, maski, BB * SS);
    k_bucket<<<4, 256, 0, stream>>>(bucket);
    k_embed_ln<<<SS * BB, 256, 0, stream>>>(ids, word_emb, x);
    k_rel_ln<<<63, 256, 0, stream>>>(rel_emb, rel_g, rel_b, rel);

    for (int l = 0; l < LL; ++l) {
        const float* Wqk_l = Wqk + (size_t)l * N_WQK;
        const float* bqk_l = bqk + (size_t)l * 2 * HH;
        const float* Wvg_l = Wvg + (size_t)l * N_WQK;
        const float* bvg_l = bvg + (size_t)l * 2 * HH;
        const float* Wout_l = Wout + (size_t)l * N_WOUT;
        const float* bout_l = bout + (size_t)l * HH;
        const float* W1_l = W1 + (size_t)l * N_W1;
        const float* W2_l = W2 + (size_t)l * N_W2;

        f2b_launch(Wqk_l, wqk_bf, N_WQK, stream);
        f2b_launch(Wvg_l, wvg_bf, N_WQK, stream);
        f2b_launch(Wout_l, wout_bf, N_WOUT, stream);
        f2b_launch(W1_l, w1_bf, N_W1, stream);
        f2b_launch(W2_l, w2_bf, N_W2, stream);

        // ---- attention ----
        k_ln_bf<<<SS * BB, 256, 0, stream>>>(x, hs_bf, HH);
        gemm_bf(hs_bf, HH, wqk_bf, HH, qk, 2 * HH, SS * BB, 2 * HH, HH, bqk_l, nullptr, stream);
        gemm_bf(hs_bf, HH, wvg_bf, HH, vg, 2 * HH, SS * BB, 2 * HH, HH, bvg_l, nullptr, stream);
        k_gemm_nt<<<dim3((2 * HH) / 64, 1), 256, 0, stream>>>(rel, HH, Wqk_l, HH, posproj, 2 * HH,
                                                              63, 2 * HH, HH, bqk_l, nullptr);
        k_repack_qk<<<dim3(SS / 64, BB * NHH), 256, 0, stream>>>(qk, qT, kT);
        k_repack_vT<<<dim3(SS / 64, BB * NHH), 256, 0, stream>>>(vg, vT);
        k_cp_pc<<<dim3(SS * BB / 64, NHH, 2), 256, 0, stream>>>(qk, posproj, cp, pc);
        k_attn_fused<<<dim3(SS / 128, BB * NHH), 256, 0, stream>>>(qT, kT, vT, cp, pc,
                                                                   bucket, maski, ctxr);
        k_gated_ln<<<SS * BB, 256, 0, stream>>>(ctxr, vg, ctx_bf);
        gemm_bf(ctx_bf, HH, wout_bf, HH, x, HH, SS * BB, HH, HH, bout_l, x, stream);

        // ---- GeGLU FFN ----
        k_ln_bf<<<SS * BB, 256, 0, stream>>>(x, hs_bf, HH);
        gemm_bf(hs_bf, HH, w1_bf, HH, ffh, 2 * II, SS * BB, 2 * II, HH, nullptr, nullptr, stream);
        k_ffn_ln<<<SS * BB, 256, 0, stream>>>(ffh, h2_bf);
        gemm_bf(h2_bf, II, w2_bf, II, x, HH, SS * BB, HH, II, nullptr, x, stream);
    }

    hipMemcpyAsync(d_out, x, N_X * sizeof(float), hipMemcpyDeviceToDevice, stream);
}

// Round 4
// 4291.059 us; speedup vs baseline: 3.4779x; 1.1490x over previous
//
#include <hip/hip_runtime.h>
#include <math.h>

#define SS 512
#define BB 8
#define NHH 12
#define DD 64
#define HH 768
#define II 2048
#define LL 12
#define SCALE_F 0.07216878364870323f  /* 1/sqrt(3*64) */

typedef __attribute__((ext_vector_type(8))) short bf16x8;
typedef __attribute__((ext_vector_type(4))) float f32x4;

// f32 -> bf16 (RNE, finite values)
__device__ __forceinline__ unsigned short f2b(float f) {
    union { float f; unsigned int u; } x; x.f = f;
    unsigned int r = x.u + 0x7fffu + ((x.u >> 16) & 1u);
    return (unsigned short)(r >> 16);
}
__device__ __forceinline__ float b2f(unsigned short u) {
    union { unsigned int u; float f; } x; x.u = ((unsigned int)u) << 16;
    return x.f;
}

// ---------------------------------------------------------------------------
// block reduction helpers (blockDim.x == 256)
// ---------------------------------------------------------------------------
__device__ __forceinline__ float2 blockReduceSum2(float a, float b) {
    __shared__ float2 sm[4];
    __shared__ float2 bc;
#pragma unroll
    for (int o = 32; o > 0; o >>= 1) {
        a += __shfl_down(a, o);
        b += __shfl_down(b, o);
    }
    int t = threadIdx.x;
    if ((t & 63) == 0) sm[t >> 6] = make_float2(a, b);
    __syncthreads();
    if (t == 0) {
        float xa = sm[0].x + sm[1].x + sm[2].x + sm[3].x;
        float xb = sm[0].y + sm[1].y + sm[2].y + sm[3].y;
        bc = make_float2(xa, xb);
    }
    __syncthreads();
    return bc;
}

__device__ __forceinline__ float gelu_erf(float v) {
    return 0.5f * v * (1.0f + erff(v * 0.70710678118654752f));
}
__device__ __forceinline__ float gelu_tanh(float v) {
    const float c = 0.7978845608028654f;
    return 0.5f * v * (1.0f + tanhf(c * (v + 0.044715f * v * v * v)));
}

// ---------------------------------------------------------------------------
// mask decode: handle bool-as-u8 or bool-as-int32 layouts
// ---------------------------------------------------------------------------
__global__ __launch_bounds__(256) void k_decode_mask(const unsigned char* __restrict__ raw,
                                                     int* __restrict__ mask, int n) {
    __shared__ int s_any;
    if (threadIdx.x == 0) s_any = 0;
    __syncthreads();
    int local = 0;
    for (int i = threadIdx.x; i < n; i += blockDim.x)
        if ((i & 3) && raw[i]) local = 1;
    if (local) atomicOr(&s_any, 1);
    __syncthreads();
    bool isU8 = (s_any != 0);
    const int* as_int = (const int*)raw;
    for (int i = threadIdx.x; i < n; i += blockDim.x)
        mask[i] = isU8 ? (raw[i] != 0) : (as_int[i] != 0);
}

// ---------------------------------------------------------------------------
// DeBERTa log-bucket table: rel in [-511,511] -> idx in [0,62]
// ---------------------------------------------------------------------------
__global__ __launch_bounds__(256) void k_bucket(int* __restrict__ tab) {
    int i = blockIdx.x * 256 + threadIdx.x;
    if (i >= 1023) return;
    int rel = i - 511;
    int a = rel < 0 ? -rel : rel;
    int abs_pos = (a < 16) ? 15 : (a < 511 ? a : 511);
    int bucket;
    if (abs_pos <= 16) {
        bucket = rel;
    } else {
        double lp = ceil(log((double)abs_pos / 16.0) / log(511.0 / 16.0) * 15.0);
        int l = (int)lp + 16;
        bucket = (rel > 0) ? l : -l;
    }
    int idx = bucket + 31;
    if (idx < 0) idx = 0;
    if (idx > 62) idx = 62;
    tab[i] = idx;
}

// ---------------------------------------------------------------------------
// f32 -> bf16 bulk conversion (8 elems/thread)
// ---------------------------------------------------------------------------
__global__ __launch_bounds__(256) void k_f2b(const float* __restrict__ in,
                                             unsigned short* __restrict__ out, int n8) {
    int i = blockIdx.x * 256 + threadIdx.x;
    if (i >= n8) return;
    float4 a = ((const float4*)in)[2 * i];
    float4 b = ((const float4*)in)[2 * i + 1];
    ushort4 lo, hi;
    lo.x = f2b(a.x); lo.y = f2b(a.y); lo.z = f2b(a.z); lo.w = f2b(a.w);
    hi.x = f2b(b.x); hi.y = f2b(b.y); hi.z = f2b(b.z); hi.w = f2b(b.w);
    ((ushort4*)out)[2 * i] = lo;
    ((ushort4*)out)[2 * i + 1] = hi;
}

// ---------------------------------------------------------------------------
// LayerNorm family; EPS = 1e-7, biased variance
// ---------------------------------------------------------------------------
__global__ __launch_bounds__(256) void k_ln_bf(const float* __restrict__ in,
                                               unsigned short* __restrict__ out) {
    int row = blockIdx.x, t = threadIdx.x;
    const float* r = in + (size_t)row * HH;
    float v0 = r[t], v1 = r[t + 256], v2 = r[t + 512];
    float s = v0 + v1 + v2;
    float ss = v0 * v0 + v1 * v1 + v2 * v2;
    float2 r2 = blockReduceSum2(s, ss);
    float mean = r2.x * (1.0f / HH);
    float var = r2.y * (1.0f / HH) - mean * mean;
    float rs = rsqrtf(var + 1e-7f);
    unsigned short* o = out + (size_t)row * HH;
    o[t] = f2b((v0 - mean) * rs);
    o[t + 256] = f2b((v1 - mean) * rs);
    o[t + 512] = f2b((v2 - mean) * rs);
}

__global__ __launch_bounds__(256) void k_embed_ln(const int* __restrict__ ids,
                                                  const float* __restrict__ emb,
                                                  float* __restrict__ out) {
    int row = blockIdx.x, t = threadIdx.x;
    const float* r = emb + (size_t)ids[row] * HH;
    float v0 = r[t], v1 = r[t + 256], v2 = r[t + 512];
    float s = v0 + v1 + v2;
    float ss = v0 * v0 + v1 * v1 + v2 * v2;
    float2 r2 = blockReduceSum2(s, ss);
    float mean = r2.x * (1.0f / HH);
    float var = r2.y * (1.0f / HH) - mean * mean;
    float rs = rsqrtf(var + 1e-7f);
    float* o = out + (size_t)row * HH;
    o[t] = (v0 - mean) * rs;
    o[t + 256] = (v1 - mean) * rs;
    o[t + 512] = (v2 - mean) * rs;
}

// rel LN -> bf16, padded to 128 rows (rows 63..127 zero)
__global__ __launch_bounds__(256) void k_rel_ln_bf(const float* __restrict__ rel_emb,
                                                   const float* __restrict__ g,
                                                   const float* __restrict__ b,
                                                   unsigned short* __restrict__ out) {
    int row = blockIdx.x, t = threadIdx.x;
    unsigned short* o = out + (size_t)row * HH;
    if (row >= 63) {
        o[t] = 0; o[t + 256] = 0; o[t + 512] = 0;
        return;
    }
    const float* r = rel_emb + (size_t)row * HH;
    float v0 = r[t], v1 = r[t + 256], v2 = r[t + 512];
    float s = v0 + v1 + v2;
    float ss = v0 * v0 + v1 * v1 + v2 * v2;
    float2 r2 = blockReduceSum2(s, ss);
    float mean = r2.x * (1.0f / HH);
    float var = r2.y * (1.0f / HH) - mean * mean;
    float rs = rsqrtf(var + 1e-7f);
    o[t] = f2b((v0 - mean) * rs * g[t] + b[t]);
    o[t + 256] = f2b((v1 - mean) * rs * g[t + 256] + b[t + 256]);
    o[t + 512] = f2b((v2 - mean) * rs * g[t + 512] + b[t + 512]);
}

// ctx_bf = bf16(LN(ctxr * gelu_exact(g))), g = qkvg[..., 2304:3072] (bf16)
__global__ __launch_bounds__(256) void k_gated_ln(const float* __restrict__ ctxr,
                                                  const unsigned short* __restrict__ qkvg,
                                                  unsigned short* __restrict__ out) {
    int row = blockIdx.x, t = threadIdx.x;
    const float* cr = ctxr + (size_t)row * HH;
    const unsigned short* gr = qkvg + (size_t)row * 3072 + 2304;
    float v[3];
    float s = 0.f, ss = 0.f;
#pragma unroll
    for (int e = 0; e < 3; ++e) {
        int i = t + e * 256;
        float x = cr[i] * gelu_erf(b2f(gr[i]));
        v[e] = x;
        s += x; ss += x * x;
    }
    float2 r2 = blockReduceSum2(s, ss);
    float mean = r2.x * (1.0f / HH);
    float var = r2.y * (1.0f / HH) - mean * mean;
    float rs = rsqrtf(var + 1e-7f);
    unsigned short* o = out + (size_t)row * HH;
#pragma unroll
    for (int e = 0; e < 3; ++e) o[t + e * 256] = f2b((v[e] - mean) * rs);
}

// h2_bf = bf16(LN(ffh[:, :I] * gelu_tanh(ffh[:, I:])))  (ffh bf16 [row][4096])
__global__ __launch_bounds__(256) void k_ffn_ln(const unsigned short* __restrict__ ffh,
                                                unsigned short* __restrict__ out) {
    int row = blockIdx.x, t = threadIdx.x;
    const unsigned short* ar = ffh + (size_t)row * 4096 + t * 8;
    const unsigned short* gr = ar + II;
    ushort4 a0 = *(const ushort4*)ar;
    ushort4 a1 = *(const ushort4*)(ar + 4);
    ushort4 g0 = *(const ushort4*)gr;
    ushort4 g1 = *(const ushort4*)(gr + 4);
    float av[8] = {b2f(a0.x), b2f(a0.y), b2f(a0.z), b2f(a0.w),
                   b2f(a1.x), b2f(a1.y), b2f(a1.z), b2f(a1.w)};
    float gv[8] = {b2f(g0.x), b2f(g0.y), b2f(g0.z), b2f(g0.w),
                   b2f(g1.x), b2f(g1.y), b2f(g1.z), b2f(g1.w)};
    float v[8];
    float s = 0.f, ss = 0.f;
#pragma unroll
    for (int e = 0; e < 8; ++e) {
        float x = av[e] * gelu_tanh(gv[e]);
        v[e] = x;
        s += x; ss += x * x;
    }
    float2 r2 = blockReduceSum2(s, ss);
    float mean = r2.x * (1.0f / II);
    float var = r2.y * (1.0f / II) - mean * mean;
    float rs = rsqrtf(var + 1e-7f);
    ushort4 o0, o1;
    o0.x = f2b((v[0] - mean) * rs); o0.y = f2b((v[1] - mean) * rs);
    o0.z = f2b((v[2] - mean) * rs); o0.w = f2b((v[3] - mean) * rs);
    o1.x = f2b((v[4] - mean) * rs); o1.y = f2b((v[5] - mean) * rs);
    o1.z = f2b((v[6] - mean) * rs); o1.w = f2b((v[7] - mean) * rs);
    unsigned short* o = out + (size_t)row * II + t * 8;
    *(ushort4*)o = o0;
    *(ushort4*)(o + 4) = o1;
}

// ---------------------------------------------------------------------------
// bf16 MFMA GEMM (m97 structure + bijective XCD swizzle):
//   C[M,N] = A[M,K] * W[N,K]^T (+bias[/bias2 at col>=1536]) (+res)
//   OBF=1 -> bf16 output, OBF=0 -> f32 output
// Requires M%128==0, N%128==0, K%32==0.
// ---------------------------------------------------------------------------
template <int OBF>
__global__ __launch_bounds__(256) void k_gemm_bf16(const unsigned short* __restrict__ A, int lda,
                                                   const unsigned short* __restrict__ W, int ldw,
                                                   void* __restrict__ Cv, int ldc,
                                                   int M, int N, int K,
                                                   const float* __restrict__ bias,
                                                   const float* __restrict__ bias2,
                                                   const float* __restrict__ res) {
    __shared__ unsigned short As[128 * 32];
    __shared__ unsigned short Ws[128 * 32];
    // bijective XCD swizzle (T1, m204 variant)
    int nwg = gridDim.x * gridDim.y;
    int orig = blockIdx.y * gridDim.x + blockIdx.x;
    int qq = nwg >> 3, rr = nwg & 7;
    int xcd = orig & 7, idx = orig >> 3;
    int wg = (xcd < rr ? xcd * (qq + 1) : rr * (qq + 1) + (xcd - rr) * qq) + idx;
    int bx = wg % gridDim.x, by = wg / gridDim.x;

    const int t = threadIdx.x;
    const int lane = t & 63, wid = t >> 6;
    const int row0 = by * 128, col0 = bx * 128;
    const int wr = (wid >> 1) * 64, wc = (wid & 1) * 64;
    const int rA = lane & 15, kA = (lane >> 4) * 8;

    f32x4 acc[4][4] = {};

    for (int k0 = 0; k0 < K; k0 += 32) {
#pragma unroll
        for (int j = 0; j < 2; ++j) {
            int c = t + j * 256;
            int r = c >> 2, ko = (c & 3) * 8;
            const unsigned short* srcA = A + (size_t)(row0 + r) * lda + k0 + ko;
            const unsigned short* srcB = W + (size_t)(col0 + r) * ldw + k0 + ko;
            unsigned short* dstA = As + (size_t)(j * 256 + wid * 64) * 8;
            unsigned short* dstB = Ws + (size_t)(j * 256 + wid * 64) * 8;
            __builtin_amdgcn_global_load_lds(
                (const __attribute__((address_space(1))) void*)srcA,
                (__attribute__((address_space(3))) void*)dstA, 16, 0, 0);
            __builtin_amdgcn_global_load_lds(
                (const __attribute__((address_space(1))) void*)srcB,
                (__attribute__((address_space(3))) void*)dstB, 16, 0, 0);
        }
        __syncthreads();
        bf16x8 af[4], bfr[4];
#pragma unroll
        for (int m = 0; m < 4; ++m)
            af[m] = *(const bf16x8*)&As[(wr + m * 16 + rA) * 32 + kA];
#pragma unroll
        for (int n = 0; n < 4; ++n)
            bfr[n] = *(const bf16x8*)&Ws[(wc + n * 16 + rA) * 32 + kA];
#pragma unroll
        for (int m = 0; m < 4; ++m)
#pragma unroll
            for (int n = 0; n < 4; ++n)
                acc[m][n] = __builtin_amdgcn_mfma_f32_16x16x32_bf16(af[m], bfr[n], acc[m][n], 0, 0, 0);
        __syncthreads();
    }

    float* Cf = (float*)Cv;
    unsigned short* Cb = (unsigned short*)Cv;
    const int cl = lane & 15, rg = (lane >> 4) * 4;
#pragma unroll
    for (int n = 0; n < 4; ++n) {
        int gc = col0 + wc + n * 16 + cl;
        float bv = 0.0f;
        if (bias) bv = (bias2 && gc >= 1536) ? bias2[gc - 1536] : bias[gc];
#pragma unroll
        for (int m = 0; m < 4; ++m) {
#pragma unroll
            for (int i = 0; i < 4; ++i) {
                int gr = row0 + wr + m * 16 + rg + i;
                float v = acc[m][n][i] + bv;
                if (OBF) {
                    Cb[(size_t)gr * ldc + gc] = f2b(v);
                } else {
                    if (res) v += res[(size_t)gr * ldc + gc];
                    Cf[(size_t)gr * ldc + gc] = v;
                }
            }
        }
    }
}

// ---------------------------------------------------------------------------
// repack: qkvg bf16 [s*B, 3072] -> qT,kT bf16 [b,h,s,d]
// ---------------------------------------------------------------------------
__global__ __launch_bounds__(256) void k_repack_qk(const unsigned short* __restrict__ qkvg,
                                                   unsigned short* __restrict__ qT,
                                                   unsigned short* __restrict__ kT) {
    int bh = blockIdx.y;
    int b = bh / NHH, h = bh % NHH;
    int s0 = blockIdx.x * 64;
    int t = threadIdx.x;
#pragma unroll
    for (int j = 0; j < 2; ++j) {
        int idx = t + j * 256;          // 0..511
        int r = idx >> 3, dc = idx & 7; // row in s-tile, d-chunk of 8
        const unsigned short* src = qkvg + ((size_t)(s0 + r) * BB + b) * 3072 + h * DD + dc * 8;
        ushort4 a = *(const ushort4*)src;
        ushort4 c = *(const ushort4*)(src + 4);
        unsigned short* dq = qT + ((size_t)bh * SS + s0 + r) * DD + dc * 8;
        *(ushort4*)dq = a; *(ushort4*)(dq + 4) = c;
        const unsigned short* srck = src + HH;
        ushort4 a2 = *(const ushort4*)srck;
        ushort4 c2 = *(const ushort4*)(srck + 4);
        unsigned short* dk = kT + ((size_t)bh * SS + s0 + r) * DD + dc * 8;
        *(ushort4*)dk = a2; *(ushort4*)(dk + 4) = c2;
    }
}

// ---------------------------------------------------------------------------
// repack: qkvg bf16 (v at cols 1536..2303) -> vT bf16 [b,h,d,s]
// ---------------------------------------------------------------------------
__global__ __launch_bounds__(256) void k_repack_vT(const unsigned short* __restrict__ qkvg,
                                                   unsigned short* __restrict__ vT) {
    __shared__ unsigned short tile[64][72];
    int bh = blockIdx.y;
    int b = bh / NHH, h = bh % NHH;
    int s0 = blockIdx.x * 64;
    int t = threadIdx.x;
#pragma unroll
    for (int j = 0; j < 4; ++j) {
        int idx = t + j * 256;          // 0..1023
        int r = idx >> 4, c4 = idx & 15;
        ushort4 u = *(const ushort4*)(qkvg + ((size_t)(s0 + r) * BB + b) * 3072 + 1536 + h * DD + c4 * 4);
        *(ushort4*)&tile[r][c4 * 4] = u;
    }
    __syncthreads();
#pragma unroll
    for (int j = 0; j < 2; ++j) {
        int idx = t + j * 256;          // 0..511
        int d = idx >> 3, s8 = idx & 7;
        ushort4 a, c;
        a.x = tile[s8 * 8 + 0][d]; a.y = tile[s8 * 8 + 1][d];
        a.z = tile[s8 * 8 + 2][d]; a.w = tile[s8 * 8 + 3][d];
        c.x = tile[s8 * 8 + 4][d]; c.y = tile[s8 * 8 + 5][d];
        c.z = tile[s8 * 8 + 6][d]; c.w = tile[s8 * 8 + 7][d];
        unsigned short* dst = vT + ((size_t)bh * DD + d) * SS + s0 + s8 * 8;
        *(ushort4*)dst = a; *(ushort4*)(dst + 4) = c;
    }
}

// ---------------------------------------------------------------------------
// cp[b,h,q,r] = qh . kposTab[r,h]  (z=0)   pc[b,h,k,r] = kh . qposTab[r,h]  (z=1)
// qkvg bf16 [row,3072]: q at col 0, k at col 768.  posproj f32 [128,1536].
// ---------------------------------------------------------------------------
__global__ __launch_bounds__(256) void k_cp_pc(const unsigned short* __restrict__ qkvg,
                                               const float* __restrict__ posproj,
                                               float* __restrict__ cp,
                                               float* __restrict__ pc) {
    __shared__ float Tb[63][65];
    __shared__ float Ar[64][68];
    int mt = blockIdx.x, h = blockIdx.y, z = blockIdx.z;
    int t = threadIdx.x;
    int aoff = z ? HH : 0;          // q (cp) / k (pc) column base in qkvg
    int toff = z ? 0 : HH;          // qpos (pc) / kpos (cp) column base in posproj
    float* out = z ? pc : cp;
    for (int v = t; v < 1008; v += 256) {
        int r = v >> 4, c4 = v & 15;
        float4 d = *(const float4*)(posproj + (size_t)r * 1536 + toff + h * DD + c4 * 4);
        Tb[r][c4 * 4 + 0] = d.x; Tb[r][c4 * 4 + 1] = d.y;
        Tb[r][c4 * 4 + 2] = d.z; Tb[r][c4 * 4 + 3] = d.w;
    }
#pragma unroll
    for (int j = 0; j < 2; ++j) {
        int idx = t + j * 256;      // 0..511
        int m = idx >> 3, dc = idx & 7;
        const unsigned short* src = qkvg + (size_t)(mt * 64 + m) * 3072 + aoff + h * DD + dc * 8;
        ushort4 a = *(const ushort4*)src;
        ushort4 c = *(const ushort4*)(src + 4);
        float* dst = &Ar[m][dc * 8];
        dst[0] = b2f(a.x); dst[1] = b2f(a.y); dst[2] = b2f(a.z); dst[3] = b2f(a.w);
        dst[4] = b2f(c.x); dst[5] = b2f(c.y); dst[6] = b2f(c.z); dst[7] = b2f(c.w);
    }
    __syncthreads();
    for (int i = t; i < 64 * 63; i += 256) {
        int m = i / 63, r = i - m * 63;
        float s = 0.f;
#pragma unroll 16
        for (int d = 0; d < 64; ++d) s += Ar[m][d] * Tb[r][d];
        int row = mt * 64 + m;      // row = s*B + b
        int sIdx = row >> 3, bIdx = row & 7;
        out[(((size_t)(bIdx * NHH + h)) * SS + sIdx) * 63 + r] = s;
    }
}

// ---------------------------------------------------------------------------
// fused disentangled flash attention (unchanged structure from round 3)
// ---------------------------------------------------------------------------
__global__ __launch_bounds__(256) void k_attn_fused(
    const unsigned short* __restrict__ qT, const unsigned short* __restrict__ kT,
    const unsigned short* __restrict__ vT, const float* __restrict__ cp,
    const float* __restrict__ pc, const int* __restrict__ bucket,
    const int* __restrict__ mask, float* __restrict__ ctxr) {
    __shared__ unsigned short pb_all[4][32 * 72];
    __shared__ int btab[1023];
    int t = threadIdx.x;
    for (int i = t; i < 1023; i += 256) btab[i] = bucket[i];
    __syncthreads();
    int lane = t & 63, wid = t >> 6;
    int bh = blockIdx.y;
    int b = bh / NHH, h = bh % NHH;
    int q0 = blockIdx.x * 128 + wid * 32;
    int rA = lane & 15, g = lane >> 4, kA = g * 8;
    unsigned short* pb = pb_all[wid];
    const unsigned short* qTb = qT + (size_t)bh * SS * DD;
    const unsigned short* kTb = kT + (size_t)bh * SS * DD;
    const unsigned short* vTb = vT + (size_t)bh * DD * SS;
    const float* cpb = cp + (size_t)bh * SS * 63;
    const float* pcb = pc + (size_t)bh * SS * 63;
    const int* mkb = mask + b * SS;

    bf16x8 aq[2][2];
#pragma unroll
    for (int m = 0; m < 2; ++m)
#pragma unroll
        for (int dc = 0; dc < 2; ++dc)
            aq[m][dc] = *(const bf16x8*)&qTb[(size_t)(q0 + m * 16 + rA) * DD + dc * 32 + kA];

    f32x4 o[2][4] = {};
    float mrow[2][4], lrow[2][4];
#pragma unroll
    for (int m = 0; m < 2; ++m)
#pragma unroll
        for (int i = 0; i < 4; ++i) { mrow[m][i] = -INFINITY; lrow[m][i] = 0.f; }

    for (int kt = 0; kt < 8; ++kt) {
        int k0 = kt * 64;
        // ---- S = Q.K^T ----
        f32x4 sa[2][4] = {};
#pragma unroll
        for (int n = 0; n < 4; ++n) {
            bf16x8 bk0 = *(const bf16x8*)&kTb[(size_t)(k0 + n * 16 + rA) * DD + kA];
            bf16x8 bk1 = *(const bf16x8*)&kTb[(size_t)(k0 + n * 16 + rA) * DD + 32 + kA];
#pragma unroll
            for (int m = 0; m < 2; ++m) {
                sa[m][n] = __builtin_amdgcn_mfma_f32_16x16x32_bf16(aq[m][0], bk0, sa[m][n], 0, 0, 0);
                sa[m][n] = __builtin_amdgcn_mfma_f32_16x16x32_bf16(aq[m][1], bk1, sa[m][n], 0, 0, 0);
            }
        }
        int mk[4];
#pragma unroll
        for (int n = 0; n < 4; ++n) mk[n] = mkb[k0 + n * 16 + rA];

        // ---- bias + mask + online softmax ----
        float pv[2][4][4];
#pragma unroll
        for (int m = 0; m < 2; ++m) {
#pragma unroll
            for (int i = 0; i < 4; ++i) {
                int q = q0 + m * 16 + g * 4 + i;
                float sv[4];
                float tmax = -INFINITY;
#pragma unroll
                for (int n = 0; n < 4; ++n) {
                    int k = k0 + n * 16 + rA;
                    int id = btab[q - k + 511];
                    float v = (sa[m][n][i] + cpb[q * 63 + id] + pcb[k * 63 + id]) * SCALE_F;
                    v = mk[n] ? -1e9f : v;
                    sv[n] = v;
                    tmax = fmaxf(tmax, v);
                }
                tmax = fmaxf(tmax, __shfl_xor(tmax, 1, 16));
                tmax = fmaxf(tmax, __shfl_xor(tmax, 2, 16));
                tmax = fmaxf(tmax, __shfl_xor(tmax, 4, 16));
                tmax = fmaxf(tmax, __shfl_xor(tmax, 8, 16));
                float mold = mrow[m][i];
                float mnew = fmaxf(mold, tmax);
                float alpha = __expf(mold - mnew);
                float ls = 0.f;
#pragma unroll
                for (int n = 0; n < 4; ++n) {
                    float p = __expf(sv[n] - mnew);
                    pv[m][n][i] = p;
                    ls += p;
                }
                ls += __shfl_xor(ls, 1, 16);
                ls += __shfl_xor(ls, 2, 16);
                ls += __shfl_xor(ls, 4, 16);
                ls += __shfl_xor(ls, 8, 16);
                lrow[m][i] = lrow[m][i] * alpha + ls;
                mrow[m][i] = mnew;
#pragma unroll
                for (int n = 0; n < 4; ++n) o[m][n][i] *= alpha;
            }
        }
        // ---- P -> bf16 via LDS (C-layout -> A-layout transpose) ----
#pragma unroll
        for (int m = 0; m < 2; ++m)
#pragma unroll
            for (int n = 0; n < 4; ++n)
#pragma unroll
                for (int i = 0; i < 4; ++i)
                    pb[(m * 16 + g * 4 + i) * 72 + n * 16 + rA] = f2b(pv[m][n][i]);
        // ---- O += P.V ----
        bf16x8 ap[2][2];
#pragma unroll
        for (int m = 0; m < 2; ++m)
#pragma unroll
            for (int kc = 0; kc < 2; ++kc)
                ap[m][kc] = *(const bf16x8*)&pb[(m * 16 + rA) * 72 + kc * 32 + kA];
#pragma unroll
        for (int n = 0; n < 4; ++n) {
            bf16x8 bv0 = *(const bf16x8*)&vTb[(size_t)(n * 16 + rA) * SS + k0 + kA];
            bf16x8 bv1 = *(const bf16x8*)&vTb[(size_t)(n * 16 + rA) * SS + k0 + 32 + kA];
#pragma unroll
            for (int m = 0; m < 2; ++m) {
                o[m][n] = __builtin_amdgcn_mfma_f32_16x16x32_bf16(ap[m][0], bv0, o[m][n], 0, 0, 0);
                o[m][n] = __builtin_amdgcn_mfma_f32_16x16x32_bf16(ap[m][1], bv1, o[m][n], 0, 0, 0);
            }
        }
    }
    // ---- epilogue: ctxr[q,b,h,d] = O / l ----
#pragma unroll
    for (int m = 0; m < 2; ++m)
#pragma unroll
        for (int i = 0; i < 4; ++i) {
            int q = q0 + m * 16 + g * 4 + i;
            float inv = 1.0f / lrow[m][i];
#pragma unroll
            for (int n = 0; n < 4; ++n)
                ctxr[((size_t)q * BB + b) * HH + h * DD + n * 16 + rA] = o[m][n][i] * inv;
        }
}

// ---------------------------------------------------------------------------
// host launcher
// ---------------------------------------------------------------------------
static inline void gemm_bf(const unsigned short* A, int lda, const unsigned short* W, int ldw,
                           void* C, int ldc, int M, int N, int K,
                           const float* bias, const float* bias2, const float* res,
                           int obf, hipStream_t st) {
    dim3 g(N / 128, M / 128);
    if (obf)
        k_gemm_bf16<1><<<g, 256, 0, st>>>(A, lda, W, ldw, C, ldc, M, N, K, bias, bias2, res);
    else
        k_gemm_bf16<0><<<g, 256, 0, st>>>(A, lda, W, ldw, C, ldc, M, N, K, bias, bias2, res);
}

static inline void f2b_launch(const float* in, unsigned short* out, size_t n, hipStream_t st) {
    int n8 = (int)(n / 8);
    k_f2b<<<(n8 + 255) / 256, 256, 0, st>>>(in, out, n8);
}

extern "C" void kernel_launch(void* const* d_in, const int* in_sizes, int n_in,
                              void* d_out, int out_size, void* d_ws, size_t ws_size,
                              hipStream_t stream) {
    const int* ids = (const int*)d_in[0];
    const unsigned char* maskraw = (const unsigned char*)d_in[1];
    const float* word_emb = (const float*)d_in[2];
    const float* rel_emb = (const float*)d_in[3];
    const float* rel_g = (const float*)d_in[4];
    const float* rel_b = (const float*)d_in[5];
    const float* Wqk = (const float*)d_in[6];
    const float* bqk = (const float*)d_in[7];
    const float* Wvg = (const float*)d_in[8];
    const float* bvg = (const float*)d_in[9];
    const float* Wout = (const float*)d_in[10];
    const float* bout = (const float*)d_in[11];
    const float* W1 = (const float*)d_in[12];
    const float* W2 = (const float*)d_in[13];

    const size_t N_X = (size_t)SS * BB * HH;          // 3,145,728
    const size_t N_CP = (size_t)SS * BB * NHH * 63;   // 3,096,576
    const size_t N_H2 = (size_t)SS * BB * II;         // 8,388,608
    const size_t N_WQK = (size_t)2 * HH * HH;         // 1,179,648
    const size_t N_WOUT = (size_t)HH * HH;
    const size_t N_W1 = (size_t)2 * II * HH;          // 3,145,728
    const size_t N_W2 = (size_t)HH * II;              // 1,572,864
    const size_t N_HD = (size_t)BB * NHH * SS * DD;   // 3,145,728
    const size_t N_QKVG = (size_t)SS * BB * 3072;     // 12,582,912
    const size_t N_FFH = (size_t)SS * BB * 4096;      // 16,777,216

    float* ws = (float*)d_ws;
    float* x = ws;
    float* ctxr = x + N_X;
    float* cp = ctxr + N_X;
    float* pc = cp + N_CP;
    float* posproj = pc + N_CP;                       // 128*1536
    unsigned short* us = (unsigned short*)(posproj + 128 * 1536);
    unsigned short* qkvg = us;
    unsigned short* hs_bf = qkvg + N_QKVG;
    unsigned short* ctx_bf = hs_bf + N_X;
    unsigned short* h2_bf = ctx_bf + N_X;
    unsigned short* ffh = h2_bf + N_H2;
    unsigned short* wqkvg_bf = ffh + N_FFH;           // packed [Wqk; Wvg] rows
    unsigned short* wout_bf = wqkvg_bf + 2 * N_WQK;
    unsigned short* w1_bf = wout_bf + N_WOUT;
    unsigned short* w2_bf = w1_bf + N_W1;
    unsigned short* rel_bf = w2_bf + N_W2;            // 128*768 (padded)
    unsigned short* qT = rel_bf + 128 * HH;
    unsigned short* kT = qT + N_HD;
    unsigned short* vT = kT + N_HD;
    int* bucket = (int*)(vT + N_HD);
    int* maski = bucket + 1024;

    size_t need_bytes = ((size_t)(maski + BB * SS) - (size_t)d_ws);
    if (ws_size < need_bytes) return;  // ~175 MB required

    // ---- setup ----
    k_decode_mask<<<1, 256, 0, stream>>>(maskraw, maski, BB * SS);
    k_bucket<<<4, 256, 0, stream>>>(bucket);
    k_embed_ln<<<SS * BB, 256, 0, stream>>>(ids, word_emb, x);
    k_rel_ln_bf<<<128, 256, 0, stream>>>(rel_emb, rel_g, rel_b, rel_bf);

    for (int l = 0; l < LL; ++l) {
        const float* Wqk_l = Wqk + (size_t)l * N_WQK;
        const float* bqk_l = bqk + (size_t)l * 2 * HH;
        const float* Wvg_l = Wvg + (size_t)l * N_WQK;
        const float* bvg_l = bvg + (size_t)l * 2 * HH;
        const float* Wout_l = Wout + (size_t)l * N_WOUT;
        const float* bout_l = bout + (size_t)l * HH;
        const float* W1_l = W1 + (size_t)l * N_W1;
        const float* W2_l = W2 + (size_t)l * N_W2;

        // weight conversions (qk+vg packed row-wise into one [3072,768] matrix)
        f2b_launch(Wqk_l, wqkvg_bf, N_WQK, stream);
        f2b_launch(Wvg_l, wqkvg_bf + N_WQK, N_WQK, stream);
        f2b_launch(Wout_l, wout_bf, N_WOUT, stream);
        f2b_launch(W1_l, w1_bf, N_W1, stream);
        f2b_launch(W2_l, w2_bf, N_W2, stream);

        // ---- attention ----
        k_ln_bf<<<SS * BB, 256, 0, stream>>>(x, hs_bf);
        // fused q,k,v,g projection -> bf16 [4096, 3072]
        gemm_bf(hs_bf, HH, wqkvg_bf, HH, qkvg, 3072, SS * BB, 3072, HH,
                bqk_l, bvg_l, nullptr, 1, stream);
        // posproj = rel * Wqk^T + bqk  (padded M=128, f32 out [128,1536])
        gemm_bf(rel_bf, HH, wqkvg_bf, HH, posproj, 1536, 128, 1536, HH,
                bqk_l, nullptr, nullptr, 0, stream);
        k_repack_qk<<<dim3(SS / 64, BB * NHH), 256, 0, stream>>>(qkvg, qT, kT);
        k_repack_vT<<<dim3(SS / 64, BB * NHH), 256, 0, stream>>>(qkvg, vT);
        k_cp_pc<<<dim3(SS * BB / 64, NHH, 2), 256, 0, stream>>>(qkvg, posproj, cp, pc);
        k_attn_fused<<<dim3(SS / 128, BB * NHH), 256, 0, stream>>>(qT, kT, vT, cp, pc,
                                                                   bucket, maski, ctxr);
        k_gated_ln<<<SS * BB, 256, 0, stream>>>(ctxr, qkvg, ctx_bf);
        gemm_bf(ctx_bf, HH, wout_bf, HH, x, HH, SS * BB, HH, HH,
                bout_l, nullptr, x, 0, stream);

        // ---- GeGLU FFN ----
        k_ln_bf<<<SS * BB, 256, 0, stream>>>(x, hs_bf);
        gemm_bf(hs_bf, HH, w1_bf, HH, ffh, 4096, SS * BB, 4096, HH,
                nullptr, nullptr, nullptr, 1, stream);
        k_ffn_ln<<<SS * BB, 256, 0, stream>>>(ffh, h2_bf);
        gemm_bf(h2_bf, II, w2_bf, II, x, HH, SS * BB, HH, II,
                nullptr, nullptr, x, 0, stream);
    }

    hipMemcpyAsync(d_out, x, N_X * sizeof(float), hipMemcpyDeviceToDevice, stream);
}

// Round 5
// 4079.797 us; speedup vs baseline: 3.6580x; 1.0518x over previous
//
#include <hip/hip_runtime.h>
#include <math.h>

#define SS 512
#define BB 8
#define NHH 12
#define DD 64
#define HH 768
#define II 2048
#define LL 12
#define SCALE_F 0.07216878364870323f  /* 1/sqrt(3*64) */

typedef __attribute__((ext_vector_type(8))) short bf16x8;
typedef __attribute__((ext_vector_type(4))) float f32x4;

// f32 -> bf16 (RNE, finite values)
__device__ __forceinline__ unsigned short f2b(float f) {
    union { float f; unsigned int u; } x; x.f = f;
    unsigned int r = x.u + 0x7fffu + ((x.u >> 16) & 1u);
    return (unsigned short)(r >> 16);
}
__device__ __forceinline__ float b2f(unsigned short u) {
    union { unsigned int u; float f; } x; x.u = ((unsigned int)u) << 16;
    return x.f;
}

// ---------------------------------------------------------------------------
// block reduction helpers (blockDim.x == 256)
// ---------------------------------------------------------------------------
__device__ __forceinline__ float2 blockReduceSum2(float a, float b) {
    __shared__ float2 sm[4];
    __shared__ float2 bc;
#pragma unroll
    for (int o = 32; o > 0; o >>= 1) {
        a += __shfl_down(a, o);
        b += __shfl_down(b, o);
    }
    int t = threadIdx.x;
    if ((t & 63) == 0) sm[t >> 6] = make_float2(a, b);
    __syncthreads();
    if (t == 0) {
        float xa = sm[0].x + sm[1].x + sm[2].x + sm[3].x;
        float xb = sm[0].y + sm[1].y + sm[2].y + sm[3].y;
        bc = make_float2(xa, xb);
    }
    __syncthreads();
    return bc;
}

__device__ __forceinline__ float gelu_erf(float v) {
    return 0.5f * v * (1.0f + erff(v * 0.70710678118654752f));
}
__device__ __forceinline__ float gelu_tanh(float v) {
    const float c = 0.7978845608028654f;
    return 0.5f * v * (1.0f + tanhf(c * (v + 0.044715f * v * v * v)));
}

// ---------------------------------------------------------------------------
// mask decode: handle bool-as-u8 or bool-as-int32 layouts
// ---------------------------------------------------------------------------
__global__ __launch_bounds__(256) void k_decode_mask(const unsigned char* __restrict__ raw,
                                                     int* __restrict__ mask, int n) {
    __shared__ int s_any;
    if (threadIdx.x == 0) s_any = 0;
    __syncthreads();
    int local = 0;
    for (int i = threadIdx.x; i < n; i += blockDim.x)
        if ((i & 3) && raw[i]) local = 1;
    if (local) atomicOr(&s_any, 1);
    __syncthreads();
    bool isU8 = (s_any != 0);
    const int* as_int = (const int*)raw;
    for (int i = threadIdx.x; i < n; i += blockDim.x)
        mask[i] = isU8 ? (raw[i] != 0) : (as_int[i] != 0);
}

// ---------------------------------------------------------------------------
// DeBERTa log-bucket table: rel in [-511,511] -> idx in [0,62]
// ---------------------------------------------------------------------------
__global__ __launch_bounds__(256) void k_bucket(int* __restrict__ tab) {
    int i = blockIdx.x * 256 + threadIdx.x;
    if (i >= 1023) return;
    int rel = i - 511;
    int a = rel < 0 ? -rel : rel;
    int abs_pos = (a < 16) ? 15 : (a < 511 ? a : 511);
    int bucket;
    if (abs_pos <= 16) {
        bucket = rel;
    } else {
        double lp = ceil(log((double)abs_pos / 16.0) / log(511.0 / 16.0) * 15.0);
        int l = (int)lp + 16;
        bucket = (rel > 0) ? l : -l;
    }
    int idx = bucket + 31;
    if (idx < 0) idx = 0;
    if (idx > 62) idx = 62;
    tab[i] = idx;
}

// ---------------------------------------------------------------------------
// fused per-layer weight conversion: all 5 weight blocks -> contiguous bf16
// segment boundaries in 8-elem chunks (sizes are compile-time constants)
// ---------------------------------------------------------------------------
__global__ __launch_bounds__(256) void k_f2b_all(const float* __restrict__ wqk,
                                                 const float* __restrict__ wvg,
                                                 const float* __restrict__ wout,
                                                 const float* __restrict__ w1,
                                                 const float* __restrict__ w2,
                                                 unsigned short* __restrict__ out) {
    int i = blockIdx.x * 256 + threadIdx.x;
    if (i >= 958464) return;
    const float* src;
    int off;
    if (i < 294912) {
        if (i < 147456) { src = wqk; off = i; }
        else            { src = wvg; off = i - 147456; }
    } else if (i < 368640) { src = wout; off = i - 294912; }
    else if (i < 761856)   { src = w1;   off = i - 368640; }
    else                   { src = w2;   off = i - 761856; }
    float4 a = ((const float4*)src)[2 * (size_t)off];
    float4 b = ((const float4*)src)[2 * (size_t)off + 1];
    ushort4 lo, hi;
    lo.x = f2b(a.x); lo.y = f2b(a.y); lo.z = f2b(a.z); lo.w = f2b(a.w);
    hi.x = f2b(b.x); hi.y = f2b(b.y); hi.z = f2b(b.z); hi.w = f2b(b.w);
    ((ushort4*)out)[2 * (size_t)i] = lo;
    ((ushort4*)out)[2 * (size_t)i + 1] = hi;
}

// ---------------------------------------------------------------------------
// LayerNorm family; EPS = 1e-7, biased variance
// ---------------------------------------------------------------------------
__global__ __launch_bounds__(256) void k_ln_bf(const float* __restrict__ in,
                                               unsigned short* __restrict__ out) {
    int row = blockIdx.x, t = threadIdx.x;
    const float* r = in + (size_t)row * HH;
    float v0 = r[t], v1 = r[t + 256], v2 = r[t + 512];
    float s = v0 + v1 + v2;
    float ss = v0 * v0 + v1 * v1 + v2 * v2;
    float2 r2 = blockReduceSum2(s, ss);
    float mean = r2.x * (1.0f / HH);
    float var = r2.y * (1.0f / HH) - mean * mean;
    float rs = rsqrtf(var + 1e-7f);
    unsigned short* o = out + (size_t)row * HH;
    o[t] = f2b((v0 - mean) * rs);
    o[t + 256] = f2b((v1 - mean) * rs);
    o[t + 512] = f2b((v2 - mean) * rs);
}

__global__ __launch_bounds__(256) void k_embed_ln(const int* __restrict__ ids,
                                                  const float* __restrict__ emb,
                                                  float* __restrict__ out) {
    int row = blockIdx.x, t = threadIdx.x;
    const float* r = emb + (size_t)ids[row] * HH;
    float v0 = r[t], v1 = r[t + 256], v2 = r[t + 512];
    float s = v0 + v1 + v2;
    float ss = v0 * v0 + v1 * v1 + v2 * v2;
    float2 r2 = blockReduceSum2(s, ss);
    float mean = r2.x * (1.0f / HH);
    float var = r2.y * (1.0f / HH) - mean * mean;
    float rs = rsqrtf(var + 1e-7f);
    float* o = out + (size_t)row * HH;
    o[t] = (v0 - mean) * rs;
    o[t + 256] = (v1 - mean) * rs;
    o[t + 512] = (v2 - mean) * rs;
}

// rel LN -> bf16, padded to 128 rows (rows 63..127 zero)
__global__ __launch_bounds__(256) void k_rel_ln_bf(const float* __restrict__ rel_emb,
                                                   const float* __restrict__ g,
                                                   const float* __restrict__ b,
                                                   unsigned short* __restrict__ out) {
    int row = blockIdx.x, t = threadIdx.x;
    unsigned short* o = out + (size_t)row * HH;
    if (row >= 63) {
        o[t] = 0; o[t + 256] = 0; o[t + 512] = 0;
        return;
    }
    const float* r = rel_emb + (size_t)row * HH;
    float v0 = r[t], v1 = r[t + 256], v2 = r[t + 512];
    float s = v0 + v1 + v2;
    float ss = v0 * v0 + v1 * v1 + v2 * v2;
    float2 r2 = blockReduceSum2(s, ss);
    float mean = r2.x * (1.0f / HH);
    float var = r2.y * (1.0f / HH) - mean * mean;
    float rs = rsqrtf(var + 1e-7f);
    o[t] = f2b((v0 - mean) * rs * g[t] + b[t]);
    o[t + 256] = f2b((v1 - mean) * rs * g[t + 256] + b[t + 256]);
    o[t + 512] = f2b((v2 - mean) * rs * g[t + 512] + b[t + 512]);
}

// ctx_bf = bf16(LN(ctxr * gelu_exact(g))), g = qkvg[..., 2304:3072] (bf16)
__global__ __launch_bounds__(256) void k_gated_ln(const float* __restrict__ ctxr,
                                                  const unsigned short* __restrict__ qkvg,
                                                  unsigned short* __restrict__ out) {
    int row = blockIdx.x, t = threadIdx.x;
    const float* cr = ctxr + (size_t)row * HH;
    const unsigned short* gr = qkvg + (size_t)row * 3072 + 2304;
    float v[3];
    float s = 0.f, ss = 0.f;
#pragma unroll
    for (int e = 0; e < 3; ++e) {
        int i = t + e * 256;
        float x = cr[i] * gelu_erf(b2f(gr[i]));
        v[e] = x;
        s += x; ss += x * x;
    }
    float2 r2 = blockReduceSum2(s, ss);
    float mean = r2.x * (1.0f / HH);
    float var = r2.y * (1.0f / HH) - mean * mean;
    float rs = rsqrtf(var + 1e-7f);
    unsigned short* o = out + (size_t)row * HH;
#pragma unroll
    for (int e = 0; e < 3; ++e) o[t + e * 256] = f2b((v[e] - mean) * rs);
}

// h2_bf = bf16(LN(ffh[:, :I] * gelu_tanh(ffh[:, I:])))  (ffh bf16 [row][4096])
__global__ __launch_bounds__(256) void k_ffn_ln(const unsigned short* __restrict__ ffh,
                                                unsigned short* __restrict__ out) {
    int row = blockIdx.x, t = threadIdx.x;
    const unsigned short* ar = ffh + (size_t)row * 4096 + t * 8;
    const unsigned short* gr = ar + II;
    ushort4 a0 = *(const ushort4*)ar;
    ushort4 a1 = *(const ushort4*)(ar + 4);
    ushort4 g0 = *(const ushort4*)gr;
    ushort4 g1 = *(const ushort4*)(gr + 4);
    float av[8] = {b2f(a0.x), b2f(a0.y), b2f(a0.z), b2f(a0.w),
                   b2f(a1.x), b2f(a1.y), b2f(a1.z), b2f(a1.w)};
    float gv[8] = {b2f(g0.x), b2f(g0.y), b2f(g0.z), b2f(g0.w),
                   b2f(g1.x), b2f(g1.y), b2f(g1.z), b2f(g1.w)};
    float v[8];
    float s = 0.f, ss = 0.f;
#pragma unroll
    for (int e = 0; e < 8; ++e) {
        float x = av[e] * gelu_tanh(gv[e]);
        v[e] = x;
        s += x; ss += x * x;
    }
    float2 r2 = blockReduceSum2(s, ss);
    float mean = r2.x * (1.0f / II);
    float var = r2.y * (1.0f / II) - mean * mean;
    float rs = rsqrtf(var + 1e-7f);
    ushort4 o0, o1;
    o0.x = f2b((v[0] - mean) * rs); o0.y = f2b((v[1] - mean) * rs);
    o0.z = f2b((v[2] - mean) * rs); o0.w = f2b((v[3] - mean) * rs);
    o1.x = f2b((v[4] - mean) * rs); o1.y = f2b((v[5] - mean) * rs);
    o1.z = f2b((v[6] - mean) * rs); o1.w = f2b((v[7] - mean) * rs);
    unsigned short* o = out + (size_t)row * II + t * 8;
    *(ushort4*)o = o0;
    *(ushort4*)(o + 4) = o1;
}

// ---------------------------------------------------------------------------
// bf16 MFMA GEMM (m97 structure + bijective XCD swizzle) — used for the
// smaller GEMMs (Wout, W2, posproj). Requires M%128==0, N%128==0, K%32==0.
// ---------------------------------------------------------------------------
template <int OBF>
__global__ __launch_bounds__(256) void k_gemm_bf16(const unsigned short* __restrict__ A, int lda,
                                                   const unsigned short* __restrict__ W, int ldw,
                                                   void* __restrict__ Cv, int ldc,
                                                   int M, int N, int K,
                                                   const float* __restrict__ bias,
                                                   const float* __restrict__ bias2,
                                                   const float* __restrict__ res) {
    __shared__ unsigned short As[128 * 32];
    __shared__ unsigned short Ws[128 * 32];
    int nwg = gridDim.x * gridDim.y;
    int orig = blockIdx.y * gridDim.x + blockIdx.x;
    int qq = nwg >> 3, rr = nwg & 7;
    int xcd = orig & 7, idx = orig >> 3;
    int wg = (xcd < rr ? xcd * (qq + 1) : rr * (qq + 1) + (xcd - rr) * qq) + idx;
    int bx = wg % gridDim.x, by = wg / gridDim.x;

    const int t = threadIdx.x;
    const int lane = t & 63, wid = t >> 6;
    const int row0 = by * 128, col0 = bx * 128;
    const int wr = (wid >> 1) * 64, wc = (wid & 1) * 64;
    const int rA = lane & 15, kA = (lane >> 4) * 8;

    f32x4 acc[4][4] = {};

    for (int k0 = 0; k0 < K; k0 += 32) {
#pragma unroll
        for (int j = 0; j < 2; ++j) {
            int c = t + j * 256;
            int r = c >> 2, ko = (c & 3) * 8;
            const unsigned short* srcA = A + (size_t)(row0 + r) * lda + k0 + ko;
            const unsigned short* srcB = W + (size_t)(col0 + r) * ldw + k0 + ko;
            unsigned short* dstA = As + (size_t)(j * 256 + wid * 64) * 8;
            unsigned short* dstB = Ws + (size_t)(j * 256 + wid * 64) * 8;
            __builtin_amdgcn_global_load_lds(
                (const __attribute__((address_space(1))) void*)srcA,
                (__attribute__((address_space(3))) void*)dstA, 16, 0, 0);
            __builtin_amdgcn_global_load_lds(
                (const __attribute__((address_space(1))) void*)srcB,
                (__attribute__((address_space(3))) void*)dstB, 16, 0, 0);
        }
        __syncthreads();
        bf16x8 af[4], bfr[4];
#pragma unroll
        for (int m = 0; m < 4; ++m)
            af[m] = *(const bf16x8*)&As[(wr + m * 16 + rA) * 32 + kA];
#pragma unroll
        for (int n = 0; n < 4; ++n)
            bfr[n] = *(const bf16x8*)&Ws[(wc + n * 16 + rA) * 32 + kA];
#pragma unroll
        for (int m = 0; m < 4; ++m)
#pragma unroll
            for (int n = 0; n < 4; ++n)
                acc[m][n] = __builtin_amdgcn_mfma_f32_16x16x32_bf16(af[m], bfr[n], acc[m][n], 0, 0, 0);
        __syncthreads();
    }

    float* Cf = (float*)Cv;
    unsigned short* Cb = (unsigned short*)Cv;
    const int cl = lane & 15, rg = (lane >> 4) * 4;
#pragma unroll
    for (int n = 0; n < 4; ++n) {
        int gc = col0 + wc + n * 16 + cl;
        float bv = 0.0f;
        if (bias) bv = (bias2 && gc >= 1536) ? bias2[gc - 1536] : bias[gc];
#pragma unroll
        for (int m = 0; m < 4; ++m) {
#pragma unroll
            for (int i = 0; i < 4; ++i) {
                int gr = row0 + wr + m * 16 + rg + i;
                float v = acc[m][n][i] + bv;
                if (OBF) {
                    Cb[(size_t)gr * ldc + gc] = f2b(v);
                } else {
                    if (res) v += res[(size_t)gr * ldc + gc];
                    Cf[(size_t)gr * ldc + gc] = v;
                }
            }
        }
    }
}

// ---------------------------------------------------------------------------
// Pipelined bf16 MFMA GEMM for the large GEMMs (qkvg, W1):
//   BM=128, BN=256, BK=64, 512 threads (8 waves 2x4, 64x64 out per wave).
//   3 LDS slots (48 KB each, 144 KB dynamic), stage tile t+2 while computing
//   tile t; counted s_waitcnt vmcnt(12) (T4, never 0 in main loop); raw
//   s_barrier pairs (no __syncthreads drain); T2 XOR swizzle (row&7)<<4 on
//   both staging source and LDS reads (rule #21); T5 setprio around MFMA.
// Requires M%128==0, N%256==0, K%64==0, K/64 >= 3.
// ---------------------------------------------------------------------------
#define GSLOT 49152  /* 48 KB: A 16KB @0, B 32KB @16384 */

__device__ __forceinline__ void g_stage(const unsigned short* __restrict__ Abase, int lda,
                                        const unsigned short* __restrict__ Wbase, int ldw,
                                        unsigned char* slot, int t, int wid) {
    int rit = t >> 3;             // row within 64-row call region
    int kb = (t & 7) << 4;        // byte offset of 16B chunk within 128B row
#pragma unroll
    for (int c = 0; c < 2; ++c) { // A: 128 rows
        int row = c * 64 + rit;
        int gkb = kb ^ ((row & 7) << 4);
        const unsigned short* src = Abase + (size_t)row * lda + (gkb >> 1);
        unsigned char* dst = slot + c * 8192 + wid * 1024;
        __builtin_amdgcn_global_load_lds(
            (const __attribute__((address_space(1))) void*)src,
            (__attribute__((address_space(3))) void*)dst, 16, 0, 0);
    }
#pragma unroll
    for (int c = 0; c < 4; ++c) { // B: 256 rows
        int row = c * 64 + rit;
        int gkb = kb ^ ((row & 7) << 4);
        const unsigned short* src = Wbase + (size_t)row * ldw + (gkb >> 1);
        unsigned char* dst = slot + 16384 + c * 8192 + wid * 1024;
        __builtin_amdgcn_global_load_lds(
            (const __attribute__((address_space(1))) void*)src,
            (__attribute__((address_space(3))) void*)dst, 16, 0, 0);
    }
}

__device__ __forceinline__ void g_compute(const unsigned char* slot, int wm, int wn,
                                          int rA, int g16, f32x4 acc[4][4]) {
    const unsigned char* Ab = slot;
    const unsigned char* Bb = slot + 16384;
    bf16x8 a[4][2], b[4][2];
#pragma unroll
    for (int m = 0; m < 4; ++m) {
        int row = wm * 64 + m * 16 + rA;
        int sw = (row & 7) << 4;
#pragma unroll
        for (int s = 0; s < 2; ++s)
            a[m][s] = *(const bf16x8*)(Ab + row * 128 + ((s * 64 + g16 * 16) ^ sw));
    }
#pragma unroll
    for (int n = 0; n < 4; ++n) {
        int row = wn * 64 + n * 16 + rA;
        int sw = (row & 7) << 4;
#pragma unroll
        for (int s = 0; s < 2; ++s)
            b[n][s] = *(const bf16x8*)(Bb + row * 128 + ((s * 64 + g16 * 16) ^ sw));
    }
    __builtin_amdgcn_s_setprio(1);
#pragma unroll
    for (int m = 0; m < 4; ++m)
#pragma unroll
        for (int n = 0; n < 4; ++n) {
            acc[m][n] = __builtin_amdgcn_mfma_f32_16x16x32_bf16(a[m][0], b[n][0], acc[m][n], 0, 0, 0);
            acc[m][n] = __builtin_amdgcn_mfma_f32_16x16x32_bf16(a[m][1], b[n][1], acc[m][n], 0, 0, 0);
        }
    __builtin_amdgcn_s_setprio(0);
}

template <int OBF>
__global__ __launch_bounds__(512, 1) void k_gemm_big(const unsigned short* __restrict__ A, int lda,
                                                     const unsigned short* __restrict__ W, int ldw,
                                                     void* __restrict__ Cv, int ldc,
                                                     int M, int N, int K,
                                                     const float* __restrict__ bias,
                                                     const float* __restrict__ bias2,
                                                     const float* __restrict__ res) {
    extern __shared__ unsigned char smem[];
    int nwg = gridDim.x * gridDim.y;
    int orig = blockIdx.y * gridDim.x + blockIdx.x;
    int qq = nwg >> 3, rr = nwg & 7;
    int xcd = orig & 7, idx = orig >> 3;
    int wg = (xcd < rr ? xcd * (qq + 1) : rr * (qq + 1) + (xcd - rr) * qq) + idx;
    int bx = wg % gridDim.x, by = wg / gridDim.x;

    const int t = threadIdx.x;
    const int lane = t & 63, wid = t >> 6;
    const int wm = wid >> 2, wn = wid & 3;      // 2 x 4 wave grid
    const int rA = lane & 15, g16 = lane >> 4;
    const int row0 = by * 128, col0 = bx * 256;
    const unsigned short* Abase = A + (size_t)row0 * lda;
    const unsigned short* Wbase = W + (size_t)col0 * ldw;

    const int nt = K >> 6;
    f32x4 acc[4][4] = {};

    // prologue: stage tiles 0,1 into slots 0,1 (12 loads per wave)
    g_stage(Abase, lda, Wbase, ldw, smem, t, wid);
    g_stage(Abase + 64, lda, Wbase + 64, ldw, smem + GSLOT, t, wid);

#define GBAR() asm volatile("s_barrier" ::: "memory")
#define GITER(T, STG, VMSTR)                                                        \
    do {                                                                            \
        GBAR(); /* all waves done reading slot (T+2)%3 (tile T-1, last iter) */     \
        if (STG)                                                                    \
            g_stage(Abase + (size_t)(T + 2) * 64, lda, Wbase + (size_t)(T + 2) * 64,\
                    ldw, smem + (size_t)((T + 2) % 3) * GSLOT, t, wid);             \
        asm volatile(VMSTR ::: "memory"); /* tile T landed (per-wave) */            \
        GBAR(); /* tile T visible to all waves */                                   \
        g_compute(smem + (size_t)((T) % 3) * GSLOT, wm, wn, rA, g16, acc);          \
    } while (0)

    int tt = 0;
    for (; tt < nt - 2; ++tt) GITER(tt, true, "s_waitcnt vmcnt(12)");
    GITER(tt, false, "s_waitcnt vmcnt(6)");
    ++tt;
    GITER(tt, false, "s_waitcnt vmcnt(0)");
#undef GITER
#undef GBAR

    float* Cf = (float*)Cv;
    unsigned short* Cb = (unsigned short*)Cv;
    const int cl = lane & 15, rg = (lane >> 4) * 4;
#pragma unroll
    for (int n = 0; n < 4; ++n) {
        int gc = col0 + wn * 64 + n * 16 + cl;
        float bv = 0.0f;
        if (bias) bv = (bias2 && gc >= 1536) ? bias2[gc - 1536] : bias[gc];
#pragma unroll
        for (int m = 0; m < 4; ++m) {
#pragma unroll
            for (int i = 0; i < 4; ++i) {
                int gr = row0 + wm * 64 + m * 16 + rg + i;
                float v = acc[m][n][i] + bv;
                if (OBF) {
                    Cb[(size_t)gr * ldc + gc] = f2b(v);
                } else {
                    if (res) v += res[(size_t)gr * ldc + gc];
                    Cf[(size_t)gr * ldc + gc] = v;
                }
            }
        }
    }
}

// ---------------------------------------------------------------------------
// repack: qkvg bf16 [s*B, 3072] -> qT,kT bf16 [b,h,s,d]
// ---------------------------------------------------------------------------
__global__ __launch_bounds__(256) void k_repack_qk(const unsigned short* __restrict__ qkvg,
                                                   unsigned short* __restrict__ qT,
                                                   unsigned short* __restrict__ kT) {
    int bh = blockIdx.y;
    int b = bh / NHH, h = bh % NHH;
    int s0 = blockIdx.x * 64;
    int t = threadIdx.x;
#pragma unroll
    for (int j = 0; j < 2; ++j) {
        int idx = t + j * 256;
        int r = idx >> 3, dc = idx & 7;
        const unsigned short* src = qkvg + ((size_t)(s0 + r) * BB + b) * 3072 + h * DD + dc * 8;
        ushort4 a = *(const ushort4*)src;
        ushort4 c = *(const ushort4*)(src + 4);
        unsigned short* dq = qT + ((size_t)bh * SS + s0 + r) * DD + dc * 8;
        *(ushort4*)dq = a; *(ushort4*)(dq + 4) = c;
        const unsigned short* srck = src + HH;
        ushort4 a2 = *(const ushort4*)srck;
        ushort4 c2 = *(const ushort4*)(srck + 4);
        unsigned short* dk = kT + ((size_t)bh * SS + s0 + r) * DD + dc * 8;
        *(ushort4*)dk = a2; *(ushort4*)(dk + 4) = c2;
    }
}

// ---------------------------------------------------------------------------
// repack: qkvg bf16 (v at cols 1536..2303) -> vT bf16 [b,h,d,s]
// ---------------------------------------------------------------------------
__global__ __launch_bounds__(256) void k_repack_vT(const unsigned short* __restrict__ qkvg,
                                                   unsigned short* __restrict__ vT) {
    __shared__ unsigned short tile[64][72];
    int bh = blockIdx.y;
    int b = bh / NHH, h = bh % NHH;
    int s0 = blockIdx.x * 64;
    int t = threadIdx.x;
#pragma unroll
    for (int j = 0; j < 4; ++j) {
        int idx = t + j * 256;
        int r = idx >> 4, c4 = idx & 15;
        ushort4 u = *(const ushort4*)(qkvg + ((size_t)(s0 + r) * BB + b) * 3072 + 1536 + h * DD + c4 * 4);
        *(ushort4*)&tile[r][c4 * 4] = u;
    }
    __syncthreads();
#pragma unroll
    for (int j = 0; j < 2; ++j) {
        int idx = t + j * 256;
        int d = idx >> 3, s8 = idx & 7;
        ushort4 a, c;
        a.x = tile[s8 * 8 + 0][d]; a.y = tile[s8 * 8 + 1][d];
        a.z = tile[s8 * 8 + 2][d]; a.w = tile[s8 * 8 + 3][d];
        c.x = tile[s8 * 8 + 4][d]; c.y = tile[s8 * 8 + 5][d];
        c.z = tile[s8 * 8 + 6][d]; c.w = tile[s8 * 8 + 7][d];
        unsigned short* dst = vT + ((size_t)bh * DD + d) * SS + s0 + s8 * 8;
        *(ushort4*)dst = a; *(ushort4*)(dst + 4) = c;
    }
}

// ---------------------------------------------------------------------------
// cp[b,h,q,r] = qh . kposTab[r,h]  (z=0)   pc[b,h,k,r] = kh . qposTab[r,h]  (z=1)
// ---------------------------------------------------------------------------
__global__ __launch_bounds__(256) void k_cp_pc(const unsigned short* __restrict__ qkvg,
                                               const float* __restrict__ posproj,
                                               float* __restrict__ cp,
                                               float* __restrict__ pc) {
    __shared__ float Tb[63][65];
    __shared__ float Ar[64][68];
    int mt = blockIdx.x, h = blockIdx.y, z = blockIdx.z;
    int t = threadIdx.x;
    int aoff = z ? HH : 0;
    int toff = z ? 0 : HH;
    float* out = z ? pc : cp;
    for (int v = t; v < 1008; v += 256) {
        int r = v >> 4, c4 = v & 15;
        float4 d = *(const float4*)(posproj + (size_t)r * 1536 + toff + h * DD + c4 * 4);
        Tb[r][c4 * 4 + 0] = d.x; Tb[r][c4 * 4 + 1] = d.y;
        Tb[r][c4 * 4 + 2] = d.z; Tb[r][c4 * 4 + 3] = d.w;
    }
#pragma unroll
    for (int j = 0; j < 2; ++j) {
        int idx = t + j * 256;
        int m = idx >> 3, dc = idx & 7;
        const unsigned short* src = qkvg + (size_t)(mt * 64 + m) * 3072 + aoff + h * DD + dc * 8;
        ushort4 a = *(const ushort4*)src;
        ushort4 c = *(const ushort4*)(src + 4);
        float* dst = &Ar[m][dc * 8];
        dst[0] = b2f(a.x); dst[1] = b2f(a.y); dst[2] = b2f(a.z); dst[3] = b2f(a.w);
        dst[4] = b2f(c.x); dst[5] = b2f(c.y); dst[6] = b2f(c.z); dst[7] = b2f(c.w);
    }
    __syncthreads();
    for (int i = t; i < 64 * 63; i += 256) {
        int m = i / 63, r = i - m * 63;
        float s = 0.f;
#pragma unroll 16
        for (int d = 0; d < 64; ++d) s += Ar[m][d] * Tb[r][d];
        int row = mt * 64 + m;
        int sIdx = row >> 3, bIdx = row & 7;
        out[(((size_t)(bIdx * NHH + h)) * SS + sIdx) * 63 + r] = s;
    }
}

// ---------------------------------------------------------------------------
// fused disentangled flash attention (unchanged from round 4)
// ---------------------------------------------------------------------------
__global__ __launch_bounds__(256) void k_attn_fused(
    const unsigned short* __restrict__ qT, const unsigned short* __restrict__ kT,
    const unsigned short* __restrict__ vT, const float* __restrict__ cp,
    const float* __restrict__ pc, const int* __restrict__ bucket,
    const int* __restrict__ mask, float* __restrict__ ctxr) {
    __shared__ unsigned short pb_all[4][32 * 72];
    __shared__ int btab[1023];
    int t = threadIdx.x;
    for (int i = t; i < 1023; i += 256) btab[i] = bucket[i];
    __syncthreads();
    int lane = t & 63, wid = t >> 6;
    int bh = blockIdx.y;
    int b = bh / NHH, h = bh % NHH;
    int q0 = blockIdx.x * 128 + wid * 32;
    int rA = lane & 15, g = lane >> 4, kA = g * 8;
    unsigned short* pb = pb_all[wid];
    const unsigned short* qTb = qT + (size_t)bh * SS * DD;
    const unsigned short* kTb = kT + (size_t)bh * SS * DD;
    const unsigned short* vTb = vT + (size_t)bh * DD * SS;
    const float* cpb = cp + (size_t)bh * SS * 63;
    const float* pcb = pc + (size_t)bh * SS * 63;
    const int* mkb = mask + b * SS;

    bf16x8 aq[2][2];
#pragma unroll
    for (int m = 0; m < 2; ++m)
#pragma unroll
        for (int dc = 0; dc < 2; ++dc)
            aq[m][dc] = *(const bf16x8*)&qTb[(size_t)(q0 + m * 16 + rA) * DD + dc * 32 + kA];

    f32x4 o[2][4] = {};
    float mrow[2][4], lrow[2][4];
#pragma unroll
    for (int m = 0; m < 2; ++m)
#pragma unroll
        for (int i = 0; i < 4; ++i) { mrow[m][i] = -INFINITY; lrow[m][i] = 0.f; }

    for (int kt = 0; kt < 8; ++kt) {
        int k0 = kt * 64;
        f32x4 sa[2][4] = {};
#pragma unroll
        for (int n = 0; n < 4; ++n) {
            bf16x8 bk0 = *(const bf16x8*)&kTb[(size_t)(k0 + n * 16 + rA) * DD + kA];
            bf16x8 bk1 = *(const bf16x8*)&kTb[(size_t)(k0 + n * 16 + rA) * DD + 32 + kA];
#pragma unroll
            for (int m = 0; m < 2; ++m) {
                sa[m][n] = __builtin_amdgcn_mfma_f32_16x16x32_bf16(aq[m][0], bk0, sa[m][n], 0, 0, 0);
                sa[m][n] = __builtin_amdgcn_mfma_f32_16x16x32_bf16(aq[m][1], bk1, sa[m][n], 0, 0, 0);
            }
        }
        int mk[4];
#pragma unroll
        for (int n = 0; n < 4; ++n) mk[n] = mkb[k0 + n * 16 + rA];

        float pv[2][4][4];
#pragma unroll
        for (int m = 0; m < 2; ++m) {
#pragma unroll
            for (int i = 0; i < 4; ++i) {
                int q = q0 + m * 16 + g * 4 + i;
                float sv[4];
                float tmax = -INFINITY;
#pragma unroll
                for (int n = 0; n < 4; ++n) {
                    int k = k0 + n * 16 + rA;
                    int id = btab[q - k + 511];
                    float v = (sa[m][n][i] + cpb[q * 63 + id] + pcb[k * 63 + id]) * SCALE_F;
                    v = mk[n] ? -1e9f : v;
                    sv[n] = v;
                    tmax = fmaxf(tmax, v);
                }
                tmax = fmaxf(tmax, __shfl_xor(tmax, 1, 16));
                tmax = fmaxf(tmax, __shfl_xor(tmax, 2, 16));
                tmax = fmaxf(tmax, __shfl_xor(tmax, 4, 16));
                tmax = fmaxf(tmax, __shfl_xor(tmax, 8, 16));
                float mold = mrow[m][i];
                float mnew = fmaxf(mold, tmax);
                float alpha = __expf(mold - mnew);
                float ls = 0.f;
#pragma unroll
                for (int n = 0; n < 4; ++n) {
                    float p = __expf(sv[n] - mnew);
                    pv[m][n][i] = p;
                    ls += p;
                }
                ls += __shfl_xor(ls, 1, 16);
                ls += __shfl_xor(ls, 2, 16);
                ls += __shfl_xor(ls, 4, 16);
                ls += __shfl_xor(ls, 8, 16);
                lrow[m][i] = lrow[m][i] * alpha + ls;
                mrow[m][i] = mnew;
#pragma unroll
                for (int n = 0; n < 4; ++n) o[m][n][i] *= alpha;
            }
        }
#pragma unroll
        for (int m = 0; m < 2; ++m)
#pragma unroll
            for (int n = 0; n < 4; ++n)
#pragma unroll
                for (int i = 0; i < 4; ++i)
                    pb[(m * 16 + g * 4 + i) * 72 + n * 16 + rA] = f2b(pv[m][n][i]);
        bf16x8 ap[2][2];
#pragma unroll
        for (int m = 0; m < 2; ++m)
#pragma unroll
            for (int kc = 0; kc < 2; ++kc)
                ap[m][kc] = *(const bf16x8*)&pb[(m * 16 + rA) * 72 + kc * 32 + kA];
#pragma unroll
        for (int n = 0; n < 4; ++n) {
            bf16x8 bv0 = *(const bf16x8*)&vTb[(size_t)(n * 16 + rA) * SS + k0 + kA];
            bf16x8 bv1 = *(const bf16x8*)&vTb[(size_t)(n * 16 + rA) * SS + k0 + 32 + kA];
#pragma unroll
            for (int m = 0; m < 2; ++m) {
                o[m][n] = __builtin_amdgcn_mfma_f32_16x16x32_bf16(ap[m][0], bv0, o[m][n], 0, 0, 0);
                o[m][n] = __builtin_amdgcn_mfma_f32_16x16x32_bf16(ap[m][1], bv1, o[m][n], 0, 0, 0);
            }
        }
    }
#pragma unroll
    for (int m = 0; m < 2; ++m)
#pragma unroll
        for (int i = 0; i < 4; ++i) {
            int q = q0 + m * 16 + g * 4 + i;
            float inv = 1.0f / lrow[m][i];
#pragma unroll
            for (int n = 0; n < 4; ++n)
                ctxr[((size_t)q * BB + b) * HH + h * DD + n * 16 + rA] = o[m][n][i] * inv;
        }
}

// ---------------------------------------------------------------------------
// host launcher
// ---------------------------------------------------------------------------
static inline void gemm_bf(const unsigned short* A, int lda, const unsigned short* W, int ldw,
                           void* C, int ldc, int M, int N, int K,
                           const float* bias, const float* bias2, const float* res,
                           int obf, hipStream_t st) {
    dim3 g(N / 128, M / 128);
    if (obf)
        k_gemm_bf16<1><<<g, 256, 0, st>>>(A, lda, W, ldw, C, ldc, M, N, K, bias, bias2, res);
    else
        k_gemm_bf16<0><<<g, 256, 0, st>>>(A, lda, W, ldw, C, ldc, M, N, K, bias, bias2, res);
}

static inline void gemm_big(const unsigned short* A, int lda, const unsigned short* W, int ldw,
                            void* C, int ldc, int M, int N, int K,
                            const float* bias, const float* bias2, const float* res,
                            int obf, hipStream_t st) {
    dim3 g(N / 256, M / 128);
    if (obf)
        k_gemm_big<1><<<g, 512, 3 * GSLOT, st>>>(A, lda, W, ldw, C, ldc, M, N, K, bias, bias2, res);
    else
        k_gemm_big<0><<<g, 512, 3 * GSLOT, st>>>(A, lda, W, ldw, C, ldc, M, N, K, bias, bias2, res);
}

extern "C" void kernel_launch(void* const* d_in, const int* in_sizes, int n_in,
                              void* d_out, int out_size, void* d_ws, size_t ws_size,
                              hipStream_t stream) {
    // allow >64KB dynamic LDS for the pipelined GEMM (idempotent, host-side)
    static int attr_done = 0;
    if (!attr_done) {
        hipFuncSetAttribute((const void*)&k_gemm_big<1>,
                            hipFuncAttributeMaxDynamicSharedMemorySize, 3 * GSLOT);
        hipFuncSetAttribute((const void*)&k_gemm_big<0>,
                            hipFuncAttributeMaxDynamicSharedMemorySize, 3 * GSLOT);
        attr_done = 1;
    }

    const int* ids = (const int*)d_in[0];
    const unsigned char* maskraw = (const unsigned char*)d_in[1];
    const float* word_emb = (const float*)d_in[2];
    const float* rel_emb = (const float*)d_in[3];
    const float* rel_g = (const float*)d_in[4];
    const float* rel_b = (const float*)d_in[5];
    const float* Wqk = (const float*)d_in[6];
    const float* bqk = (const float*)d_in[7];
    const float* Wvg = (const float*)d_in[8];
    const float* bvg = (const float*)d_in[9];
    const float* Wout = (const float*)d_in[10];
    const float* bout = (const float*)d_in[11];
    const float* W1 = (const float*)d_in[12];
    const float* W2 = (const float*)d_in[13];

    const size_t N_X = (size_t)SS * BB * HH;
    const size_t N_CP = (size_t)SS * BB * NHH * 63;
    const size_t N_H2 = (size_t)SS * BB * II;
    const size_t N_WQK = (size_t)2 * HH * HH;
    const size_t N_WOUT = (size_t)HH * HH;
    const size_t N_W1 = (size_t)2 * II * HH;
    const size_t N_W2 = (size_t)HH * II;
    const size_t N_HD = (size_t)BB * NHH * SS * DD;
    const size_t N_QKVG = (size_t)SS * BB * 3072;
    const size_t N_FFH = (size_t)SS * BB * 4096;

    float* ws = (float*)d_ws;
    float* x = ws;
    float* ctxr = x + N_X;
    float* cp = ctxr + N_X;
    float* pc = cp + N_CP;
    float* posproj = pc + N_CP;                       // 128*1536
    unsigned short* us = (unsigned short*)(posproj + 128 * 1536);
    unsigned short* qkvg = us;
    unsigned short* hs_bf = qkvg + N_QKVG;
    unsigned short* ctx_bf = hs_bf + N_X;
    unsigned short* h2_bf = ctx_bf + N_X;
    unsigned short* ffh = h2_bf + N_H2;
    unsigned short* wqkvg_bf = ffh + N_FFH;           // packed [Wqk; Wvg; Wout; W1; W2]
    unsigned short* wout_bf = wqkvg_bf + 2 * N_WQK;
    unsigned short* w1_bf = wout_bf + N_WOUT;
    unsigned short* w2_bf = w1_bf + N_W1;
    unsigned short* rel_bf = w2_bf + N_W2;            // 128*768 (padded)
    unsigned short* qT = rel_bf + 128 * HH;
    unsigned short* kT = qT + N_HD;
    unsigned short* vT = kT + N_HD;
    int* bucket = (int*)(vT + N_HD);
    int* maski = bucket + 1024;

    size_t need_bytes = ((size_t)(maski + BB * SS) - (size_t)d_ws);
    if (ws_size < need_bytes) return;  // ~175 MB required

    // ---- setup ----
    k_decode_mask<<<1, 256, 0, stream>>>(maskraw, maski, BB * SS);
    k_bucket<<<4, 256, 0, stream>>>(bucket);
    k_embed_ln<<<SS * BB, 256, 0, stream>>>(ids, word_emb, x);
    k_rel_ln_bf<<<128, 256, 0, stream>>>(rel_emb, rel_g, rel_b, rel_bf);

    for (int l = 0; l < LL; ++l) {
        const float* Wqk_l = Wqk + (size_t)l * N_WQK;
        const float* bqk_l = bqk + (size_t)l * 2 * HH;
        const float* Wvg_l = Wvg + (size_t)l * N_WQK;
        const float* bvg_l = bvg + (size_t)l * 2 * HH;
        const float* Wout_l = Wout + (size_t)l * N_WOUT;
        const float* bout_l = bout + (size_t)l * HH;
        const float* W1_l = W1 + (size_t)l * N_W1;
        const float* W2_l = W2 + (size_t)l * N_W2;

        // one fused weight conversion per layer (into the contiguous bf16 area)
        k_f2b_all<<<3745, 256, 0, stream>>>(Wqk_l, Wvg_l, Wout_l, W1_l, W2_l, wqkvg_bf);

        // ---- attention ----
        k_ln_bf<<<SS * BB, 256, 0, stream>>>(x, hs_bf);
        gemm_big(hs_bf, HH, wqkvg_bf, HH, qkvg, 3072, SS * BB, 3072, HH,
                 bqk_l, bvg_l, nullptr, 1, stream);
        gemm_bf(rel_bf, HH, wqkvg_bf, HH, posproj, 1536, 128, 1536, HH,
                bqk_l, nullptr, nullptr, 0, stream);
        k_repack_qk<<<dim3(SS / 64, BB * NHH), 256, 0, stream>>>(qkvg, qT, kT);
        k_repack_vT<<<dim3(SS / 64, BB * NHH), 256, 0, stream>>>(qkvg, vT);
        k_cp_pc<<<dim3(SS * BB / 64, NHH, 2), 256, 0, stream>>>(qkvg, posproj, cp, pc);
        k_attn_fused<<<dim3(SS / 128, BB * NHH), 256, 0, stream>>>(qT, kT, vT, cp, pc,
                                                                   bucket, maski, ctxr);
        k_gated_ln<<<SS * BB, 256, 0, stream>>>(ctxr, qkvg, ctx_bf);
        gemm_bf(ctx_bf, HH, wout_bf, HH, x, HH, SS * BB, HH, HH,
                bout_l, nullptr, x, 0, stream);

        // ---- GeGLU FFN ----
        k_ln_bf<<<SS * BB, 256, 0, stream>>>(x, hs_bf);
        gemm_big(hs_bf, HH, w1_bf, HH, ffh, 4096, SS * BB, 4096, HH,
                 nullptr, nullptr, nullptr, 1, stream);
        k_ffn_ln<<<SS * BB, 256, 0, stream>>>(ffh, h2_bf);
        gemm_bf(h2_bf, II, w2_bf, II, x, HH, SS * BB, HH, II,
                nullptr, nullptr, x, 0, stream);
    }

    hipMemcpyAsync(d_out, x, N_X * sizeof(float), hipMemcpyDeviceToDevice, stream);
}

// Round 6
// 3629.391 us; speedup vs baseline: 4.1120x; 1.1241x over previous
//
#include <hip/hip_runtime.h>
#include <math.h>

#define SS 512
#define BB 8
#define NHH 12
#define DD 64
#define HH 768
#define II 2048
#define LL 12
#define SCALE_F 0.07216878364870323f  /* 1/sqrt(3*64) */

typedef __attribute__((ext_vector_type(8))) short bf16x8;
typedef __attribute__((ext_vector_type(4))) float f32x4;

// f32 -> bf16 (RNE, finite values)
__device__ __forceinline__ unsigned short f2b(float f) {
    union { float f; unsigned int u; } x; x.f = f;
    unsigned int r = x.u + 0x7fffu + ((x.u >> 16) & 1u);
    return (unsigned short)(r >> 16);
}
__device__ __forceinline__ float b2f(unsigned short u) {
    union { unsigned int u; float f; } x; x.u = ((unsigned int)u) << 16;
    return x.f;
}

// ---------------------------------------------------------------------------
// block reduction helpers (blockDim.x == 256)
// ---------------------------------------------------------------------------
__device__ __forceinline__ float2 blockReduceSum2(float a, float b) {
    __shared__ float2 sm[4];
    __shared__ float2 bc;
#pragma unroll
    for (int o = 32; o > 0; o >>= 1) {
        a += __shfl_down(a, o);
        b += __shfl_down(b, o);
    }
    int t = threadIdx.x;
    if ((t & 63) == 0) sm[t >> 6] = make_float2(a, b);
    __syncthreads();
    if (t == 0) {
        float xa = sm[0].x + sm[1].x + sm[2].x + sm[3].x;
        float xb = sm[0].y + sm[1].y + sm[2].y + sm[3].y;
        bc = make_float2(xa, xb);
    }
    __syncthreads();
    return bc;
}

__device__ __forceinline__ float gelu_erf(float v) {
    return 0.5f * v * (1.0f + erff(v * 0.70710678118654752f));
}
__device__ __forceinline__ float gelu_tanh(float v) {
    const float c = 0.7978845608028654f;
    return 0.5f * v * (1.0f + tanhf(c * (v + 0.044715f * v * v * v)));
}

// ---------------------------------------------------------------------------
// mask decode: handle bool-as-u8 or bool-as-int32 layouts
// ---------------------------------------------------------------------------
__global__ __launch_bounds__(256) void k_decode_mask(const unsigned char* __restrict__ raw,
                                                     int* __restrict__ mask, int n) {
    __shared__ int s_any;
    if (threadIdx.x == 0) s_any = 0;
    __syncthreads();
    int local = 0;
    for (int i = threadIdx.x; i < n; i += blockDim.x)
        if ((i & 3) && raw[i]) local = 1;
    if (local) atomicOr(&s_any, 1);
    __syncthreads();
    bool isU8 = (s_any != 0);
    const int* as_int = (const int*)raw;
    for (int i = threadIdx.x; i < n; i += blockDim.x)
        mask[i] = isU8 ? (raw[i] != 0) : (as_int[i] != 0);
}

// ---------------------------------------------------------------------------
// DeBERTa log-bucket table: rel in [-511,511] -> idx in [0,62]
// ---------------------------------------------------------------------------
__global__ __launch_bounds__(256) void k_bucket(int* __restrict__ tab) {
    int i = blockIdx.x * 256 + threadIdx.x;
    if (i >= 1023) return;
    int rel = i - 511;
    int a = rel < 0 ? -rel : rel;
    int abs_pos = (a < 16) ? 15 : (a < 511 ? a : 511);
    int bucket;
    if (abs_pos <= 16) {
        bucket = rel;
    } else {
        double lp = ceil(log((double)abs_pos / 16.0) / log(511.0 / 16.0) * 15.0);
        int l = (int)lp + 16;
        bucket = (rel > 0) ? l : -l;
    }
    int idx = bucket + 31;
    if (idx < 0) idx = 0;
    if (idx > 62) idx = 62;
    tab[i] = idx;
}

// ---------------------------------------------------------------------------
// generic f32 -> bf16 bulk conversion (8 elems/thread)
// ---------------------------------------------------------------------------
__global__ __launch_bounds__(256) void k_f2b(const float* __restrict__ in,
                                             unsigned short* __restrict__ out, int n8) {
    int i = blockIdx.x * 256 + threadIdx.x;
    if (i >= n8) return;
    float4 a = ((const float4*)in)[2 * (size_t)i];
    float4 b = ((const float4*)in)[2 * (size_t)i + 1];
    ushort4 lo, hi;
    lo.x = f2b(a.x); lo.y = f2b(a.y); lo.z = f2b(a.z); lo.w = f2b(a.w);
    hi.x = f2b(b.x); hi.y = f2b(b.y); hi.z = f2b(b.z); hi.w = f2b(b.w);
    ((ushort4*)out)[2 * (size_t)i] = lo;
    ((ushort4*)out)[2 * (size_t)i + 1] = hi;
}

// per-layer: Wvg, Wout, W1, W2 -> contiguous bf16 (chunk units of 8 elems)
__global__ __launch_bounds__(256) void k_f2b_rest(const float* __restrict__ wvg,
                                                  const float* __restrict__ wout,
                                                  const float* __restrict__ w1,
                                                  const float* __restrict__ w2,
                                                  unsigned short* __restrict__ out) {
    int i = blockIdx.x * 256 + threadIdx.x;
    if (i >= 811008) return;
    const float* src;
    int off;
    if (i < 221184) {
        if (i < 147456) { src = wvg;  off = i; }
        else            { src = wout; off = i - 147456; }
    } else if (i < 614400) { src = w1; off = i - 221184; }
    else                   { src = w2; off = i - 614400; }
    float4 a = ((const float4*)src)[2 * (size_t)off];
    float4 b = ((const float4*)src)[2 * (size_t)off + 1];
    ushort4 lo, hi;
    lo.x = f2b(a.x); lo.y = f2b(a.y); lo.z = f2b(a.z); lo.w = f2b(a.w);
    hi.x = f2b(b.x); hi.y = f2b(b.y); hi.z = f2b(b.z); hi.w = f2b(b.w);
    ((ushort4*)out)[2 * (size_t)i] = lo;
    ((ushort4*)out)[2 * (size_t)i + 1] = hi;
}

// ---------------------------------------------------------------------------
// LayerNorm family; EPS = 1e-7, biased variance
// ---------------------------------------------------------------------------
__global__ __launch_bounds__(256) void k_ln_bf(const float* __restrict__ in,
                                               unsigned short* __restrict__ out) {
    int row = blockIdx.x, t = threadIdx.x;
    const float* r = in + (size_t)row * HH;
    float v0 = r[t], v1 = r[t + 256], v2 = r[t + 512];
    float s = v0 + v1 + v2;
    float ss = v0 * v0 + v1 * v1 + v2 * v2;
    float2 r2 = blockReduceSum2(s, ss);
    float mean = r2.x * (1.0f / HH);
    float var = r2.y * (1.0f / HH) - mean * mean;
    float rs = rsqrtf(var + 1e-7f);
    unsigned short* o = out + (size_t)row * HH;
    o[t] = f2b((v0 - mean) * rs);
    o[t + 256] = f2b((v1 - mean) * rs);
    o[t + 512] = f2b((v2 - mean) * rs);
}

__global__ __launch_bounds__(256) void k_embed_ln(const int* __restrict__ ids,
                                                  const float* __restrict__ emb,
                                                  float* __restrict__ out) {
    int row = blockIdx.x, t = threadIdx.x;
    const float* r = emb + (size_t)ids[row] * HH;
    float v0 = r[t], v1 = r[t + 256], v2 = r[t + 512];
    float s = v0 + v1 + v2;
    float ss = v0 * v0 + v1 * v1 + v2 * v2;
    float2 r2 = blockReduceSum2(s, ss);
    float mean = r2.x * (1.0f / HH);
    float var = r2.y * (1.0f / HH) - mean * mean;
    float rs = rsqrtf(var + 1e-7f);
    float* o = out + (size_t)row * HH;
    o[t] = (v0 - mean) * rs;
    o[t + 256] = (v1 - mean) * rs;
    o[t + 512] = (v2 - mean) * rs;
}

// rel LN -> bf16, padded to 128 rows (rows 63..127 zero)
__global__ __launch_bounds__(256) void k_rel_ln_bf(const float* __restrict__ rel_emb,
                                                   const float* __restrict__ g,
                                                   const float* __restrict__ b,
                                                   unsigned short* __restrict__ out) {
    int row = blockIdx.x, t = threadIdx.x;
    unsigned short* o = out + (size_t)row * HH;
    if (row >= 63) {
        o[t] = 0; o[t + 256] = 0; o[t + 512] = 0;
        return;
    }
    const float* r = rel_emb + (size_t)row * HH;
    float v0 = r[t], v1 = r[t + 256], v2 = r[t + 512];
    float s = v0 + v1 + v2;
    float ss = v0 * v0 + v1 * v1 + v2 * v2;
    float2 r2 = blockReduceSum2(s, ss);
    float mean = r2.x * (1.0f / HH);
    float var = r2.y * (1.0f / HH) - mean * mean;
    float rs = rsqrtf(var + 1e-7f);
    o[t] = f2b((v0 - mean) * rs * g[t] + b[t]);
    o[t + 256] = f2b((v1 - mean) * rs * g[t + 256] + b[t + 256]);
    o[t + 512] = f2b((v2 - mean) * rs * g[t + 512] + b[t + 512]);
}

// ctx_bf = bf16(LN(ctxr * gelu_exact(g))), g = qkvg[..., 2304:3072] (bf16)
__global__ __launch_bounds__(256) void k_gated_ln(const float* __restrict__ ctxr,
                                                  const unsigned short* __restrict__ qkvg,
                                                  unsigned short* __restrict__ out) {
    int row = blockIdx.x, t = threadIdx.x;
    const float* cr = ctxr + (size_t)row * HH;
    const unsigned short* gr = qkvg + (size_t)row * 3072 + 2304;
    float v[3];
    float s = 0.f, ss = 0.f;
#pragma unroll
    for (int e = 0; e < 3; ++e) {
        int i = t + e * 256;
        float x = cr[i] * gelu_erf(b2f(gr[i]));
        v[e] = x;
        s += x; ss += x * x;
    }
    float2 r2 = blockReduceSum2(s, ss);
    float mean = r2.x * (1.0f / HH);
    float var = r2.y * (1.0f / HH) - mean * mean;
    float rs = rsqrtf(var + 1e-7f);
    unsigned short* o = out + (size_t)row * HH;
#pragma unroll
    for (int e = 0; e < 3; ++e) o[t + e * 256] = f2b((v[e] - mean) * rs);
}

// h2_bf = bf16(LN(ffh[:, :I] * gelu_tanh(ffh[:, I:])))  (ffh bf16 [row][4096])
__global__ __launch_bounds__(256) void k_ffn_ln(const unsigned short* __restrict__ ffh,
                                                unsigned short* __restrict__ out) {
    int row = blockIdx.x, t = threadIdx.x;
    const unsigned short* ar = ffh + (size_t)row * 4096 + t * 8;
    const unsigned short* gr = ar + II;
    ushort4 a0 = *(const ushort4*)ar;
    ushort4 a1 = *(const ushort4*)(ar + 4);
    ushort4 g0 = *(const ushort4*)gr;
    ushort4 g1 = *(const ushort4*)(gr + 4);
    float av[8] = {b2f(a0.x), b2f(a0.y), b2f(a0.z), b2f(a0.w),
                   b2f(a1.x), b2f(a1.y), b2f(a1.z), b2f(a1.w)};
    float gv[8] = {b2f(g0.x), b2f(g0.y), b2f(g0.z), b2f(g0.w),
                   b2f(g1.x), b2f(g1.y), b2f(g1.z), b2f(g1.w)};
    float v[8];
    float s = 0.f, ss = 0.f;
#pragma unroll
    for (int e = 0; e < 8; ++e) {
        float x = av[e] * gelu_tanh(gv[e]);
        v[e] = x;
        s += x; ss += x * x;
    }
    float2 r2 = blockReduceSum2(s, ss);
    float mean = r2.x * (1.0f / II);
    float var = r2.y * (1.0f / II) - mean * mean;
    float rs = rsqrtf(var + 1e-7f);
    ushort4 o0, o1;
    o0.x = f2b((v[0] - mean) * rs); o0.y = f2b((v[1] - mean) * rs);
    o0.z = f2b((v[2] - mean) * rs); o0.w = f2b((v[3] - mean) * rs);
    o1.x = f2b((v[4] - mean) * rs); o1.y = f2b((v[5] - mean) * rs);
    o1.z = f2b((v[6] - mean) * rs); o1.w = f2b((v[7] - mean) * rs);
    unsigned short* o = out + (size_t)row * II + t * 8;
    *(ushort4*)o = o0;
    *(ushort4*)(o + 4) = o1;
}

// ---------------------------------------------------------------------------
// bf16 MFMA GEMM (m97 structure + bijective XCD swizzle + optional z-batch):
//   C[M,N] = A[M,K] * W[N,K]^T (+bias[/bias2 at col>=1536]) (+res)
//   z-batch: W += z*wz, C += z*cz (elements), bias += z*bz
// Requires M%128==0, N%128==0, K%32==0.
// ---------------------------------------------------------------------------
template <int OBF>
__global__ __launch_bounds__(256) void k_gemm_bf16(const unsigned short* __restrict__ A, int lda,
                                                   const unsigned short* __restrict__ W, int ldw,
                                                   void* __restrict__ Cv, int ldc,
                                                   int M, int N, int K,
                                                   const float* __restrict__ bias,
                                                   const float* __restrict__ bias2,
                                                   const float* __restrict__ res,
                                                   size_t wz, size_t cz, size_t bz) {
    __shared__ unsigned short As[128 * 32];
    __shared__ unsigned short Ws[128 * 32];
    int zz = blockIdx.z;
    W += (size_t)zz * wz;
    if (bias) bias += (size_t)zz * bz;
    int nwg = gridDim.x * gridDim.y;
    int orig = blockIdx.y * gridDim.x + blockIdx.x;
    int qq = nwg >> 3, rr = nwg & 7;
    int xcd = orig & 7, idx = orig >> 3;
    int wg = (xcd < rr ? xcd * (qq + 1) : rr * (qq + 1) + (xcd - rr) * qq) + idx;
    int bx = wg % gridDim.x, by = wg / gridDim.x;

    const int t = threadIdx.x;
    const int lane = t & 63, wid = t >> 6;
    const int row0 = by * 128, col0 = bx * 128;
    const int wr = (wid >> 1) * 64, wc = (wid & 1) * 64;
    const int rA = lane & 15, kA = (lane >> 4) * 8;

    f32x4 acc[4][4] = {};

    for (int k0 = 0; k0 < K; k0 += 32) {
#pragma unroll
        for (int j = 0; j < 2; ++j) {
            int c = t + j * 256;
            int r = c >> 2, ko = (c & 3) * 8;
            const unsigned short* srcA = A + (size_t)(row0 + r) * lda + k0 + ko;
            const unsigned short* srcB = W + (size_t)(col0 + r) * ldw + k0 + ko;
            unsigned short* dstA = As + (size_t)(j * 256 + wid * 64) * 8;
            unsigned short* dstB = Ws + (size_t)(j * 256 + wid * 64) * 8;
            __builtin_amdgcn_global_load_lds(
                (const __attribute__((address_space(1))) void*)srcA,
                (__attribute__((address_space(3))) void*)dstA, 16, 0, 0);
            __builtin_amdgcn_global_load_lds(
                (const __attribute__((address_space(1))) void*)srcB,
                (__attribute__((address_space(3))) void*)dstB, 16, 0, 0);
        }
        __syncthreads();
        bf16x8 af[4], bfr[4];
#pragma unroll
        for (int m = 0; m < 4; ++m)
            af[m] = *(const bf16x8*)&As[(wr + m * 16 + rA) * 32 + kA];
#pragma unroll
        for (int n = 0; n < 4; ++n)
            bfr[n] = *(const bf16x8*)&Ws[(wc + n * 16 + rA) * 32 + kA];
#pragma unroll
        for (int m = 0; m < 4; ++m)
#pragma unroll
            for (int n = 0; n < 4; ++n)
                acc[m][n] = __builtin_amdgcn_mfma_f32_16x16x32_bf16(af[m], bfr[n], acc[m][n], 0, 0, 0);
        __syncthreads();
    }

    float* Cf = (float*)Cv + (size_t)zz * cz;
    unsigned short* Cb = (unsigned short*)Cv + (size_t)zz * cz;
    const int cl = lane & 15, rg = (lane >> 4) * 4;
#pragma unroll
    for (int n = 0; n < 4; ++n) {
        int gc = col0 + wc + n * 16 + cl;
        float bv = 0.0f;
        if (bias) bv = (bias2 && gc >= 1536) ? bias2[gc - 1536] : bias[gc];
#pragma unroll
        for (int m = 0; m < 4; ++m) {
#pragma unroll
            for (int i = 0; i < 4; ++i) {
                int gr = row0 + wr + m * 16 + rg + i;
                float v = acc[m][n][i] + bv;
                if (OBF) {
                    Cb[(size_t)gr * ldc + gc] = f2b(v);
                } else {
                    if (res) v += res[(size_t)gr * ldc + gc];
                    Cf[(size_t)gr * ldc + gc] = v;
                }
            }
        }
    }
}

// ---------------------------------------------------------------------------
// Pipelined bf16 MFMA GEMM for the large GEMMs (qkvg, W1):
//   BM=128, BN=256, BK=64, 512 threads (8 waves 2x4, 64x64 out per wave).
//   3 LDS slots, counted vmcnt(12), raw s_barrier pairs, T2 XOR swizzle
//   both-sides, T5 setprio. W operand optionally split at row 1536 (Wb2).
// Requires M%128==0, N%256==0, K%64==0, K/64 >= 3.
// ---------------------------------------------------------------------------
#define GSLOT 49152  /* 48 KB: A 16KB @0, B 32KB @16384 */

__device__ __forceinline__ void g_stage(const unsigned short* __restrict__ Abase, int lda,
                                        const unsigned short* __restrict__ Wbase, int ldw,
                                        unsigned char* slot, int t, int wid) {
    int rit = t >> 3;
    int kb = (t & 7) << 4;
#pragma unroll
    for (int c = 0; c < 2; ++c) {
        int row = c * 64 + rit;
        int gkb = kb ^ ((row & 7) << 4);
        const unsigned short* src = Abase + (size_t)row * lda + (gkb >> 1);
        unsigned char* dst = slot + c * 8192 + wid * 1024;
        __builtin_amdgcn_global_load_lds(
            (const __attribute__((address_space(1))) void*)src,
            (__attribute__((address_space(3))) void*)dst, 16, 0, 0);
    }
#pragma unroll
    for (int c = 0; c < 4; ++c) {
        int row = c * 64 + rit;
        int gkb = kb ^ ((row & 7) << 4);
        const unsigned short* src = Wbase + (size_t)row * ldw + (gkb >> 1);
        unsigned char* dst = slot + 16384 + c * 8192 + wid * 1024;
        __builtin_amdgcn_global_load_lds(
            (const __attribute__((address_space(1))) void*)src,
            (__attribute__((address_space(3))) void*)dst, 16, 0, 0);
    }
}

__device__ __forceinline__ void g_compute(const unsigned char* slot, int wm, int wn,
                                          int rA, int g16, f32x4 acc[4][4]) {
    const unsigned char* Ab = slot;
    const unsigned char* Bb = slot + 16384;
    bf16x8 a[4][2], b[4][2];
#pragma unroll
    for (int m = 0; m < 4; ++m) {
        int row = wm * 64 + m * 16 + rA;
        int sw = (row & 7) << 4;
#pragma unroll
        for (int s = 0; s < 2; ++s)
            a[m][s] = *(const bf16x8*)(Ab + row * 128 + ((s * 64 + g16 * 16) ^ sw));
    }
#pragma unroll
    for (int n = 0; n < 4; ++n) {
        int row = wn * 64 + n * 16 + rA;
        int sw = (row & 7) << 4;
#pragma unroll
        for (int s = 0; s < 2; ++s)
            b[n][s] = *(const bf16x8*)(Bb + row * 128 + ((s * 64 + g16 * 16) ^ sw));
    }
    __builtin_amdgcn_s_setprio(1);
#pragma unroll
    for (int m = 0; m < 4; ++m)
#pragma unroll
        for (int n = 0; n < 4; ++n) {
            acc[m][n] = __builtin_amdgcn_mfma_f32_16x16x32_bf16(a[m][0], b[n][0], acc[m][n], 0, 0, 0);
            acc[m][n] = __builtin_amdgcn_mfma_f32_16x16x32_bf16(a[m][1], b[n][1], acc[m][n], 0, 0, 0);
        }
    __builtin_amdgcn_s_setprio(0);
}

template <int OBF>
__global__ __launch_bounds__(512, 1) void k_gemm_big(const unsigned short* __restrict__ A, int lda,
                                                     const unsigned short* __restrict__ W,
                                                     const unsigned short* __restrict__ Wb2, int ldw,
                                                     void* __restrict__ Cv, int ldc,
                                                     int M, int N, int K,
                                                     const float* __restrict__ bias,
                                                     const float* __restrict__ bias2,
                                                     const float* __restrict__ res) {
    extern __shared__ unsigned char smem[];
    int nwg = gridDim.x * gridDim.y;
    int orig = blockIdx.y * gridDim.x + blockIdx.x;
    int qq = nwg >> 3, rr = nwg & 7;
    int xcd = orig & 7, idx = orig >> 3;
    int wg = (xcd < rr ? xcd * (qq + 1) : rr * (qq + 1) + (xcd - rr) * qq) + idx;
    int bx = wg % gridDim.x, by = wg / gridDim.x;

    const int t = threadIdx.x;
    const int lane = t & 63, wid = t >> 6;
    const int wm = wid >> 2, wn = wid & 3;
    const int rA = lane & 15, g16 = lane >> 4;
    const int row0 = by * 128, col0 = bx * 256;
    const unsigned short* Abase = A + (size_t)row0 * lda;
    const unsigned short* Wbase = (Wb2 && col0 >= 1536)
                                      ? Wb2 + (size_t)(col0 - 1536) * ldw
                                      : W + (size_t)col0 * ldw;

    const int nt = K >> 6;
    f32x4 acc[4][4] = {};

    g_stage(Abase, lda, Wbase, ldw, smem, t, wid);
    g_stage(Abase + 64, lda, Wbase + 64, ldw, smem + GSLOT, t, wid);

#define GBAR() asm volatile("s_barrier" ::: "memory")
#define GITER(T, STG, VMSTR)                                                        \
    do {                                                                            \
        GBAR();                                                                     \
        if (STG)                                                                    \
            g_stage(Abase + (size_t)(T + 2) * 64, lda, Wbase + (size_t)(T + 2) * 64,\
                    ldw, smem + (size_t)((T + 2) % 3) * GSLOT, t, wid);             \
        asm volatile(VMSTR ::: "memory");                                           \
        GBAR();                                                                     \
        g_compute(smem + (size_t)((T) % 3) * GSLOT, wm, wn, rA, g16, acc);          \
    } while (0)

    int tt = 0;
    for (; tt < nt - 2; ++tt) GITER(tt, true, "s_waitcnt vmcnt(12)");
    GITER(tt, false, "s_waitcnt vmcnt(6)");
    ++tt;
    GITER(tt, false, "s_waitcnt vmcnt(0)");
#undef GITER
#undef GBAR

    float* Cf = (float*)Cv;
    unsigned short* Cb = (unsigned short*)Cv;
    const int cl = lane & 15, rg = (lane >> 4) * 4;
#pragma unroll
    for (int n = 0; n < 4; ++n) {
        int gc = col0 + wn * 64 + n * 16 + cl;
        float bv = 0.0f;
        if (bias) bv = (bias2 && gc >= 1536) ? bias2[gc - 1536] : bias[gc];
#pragma unroll
        for (int m = 0; m < 4; ++m) {
#pragma unroll
            for (int i = 0; i < 4; ++i) {
                int gr = row0 + wm * 64 + m * 16 + rg + i;
                float v = acc[m][n][i] + bv;
                if (OBF) {
                    Cb[(size_t)gr * ldc + gc] = f2b(v);
                } else {
                    if (res) v += res[(size_t)gr * ldc + gc];
                    Cf[(size_t)gr * ldc + gc] = v;
                }
            }
        }
    }
}

// ---------------------------------------------------------------------------
// merged repack: qkvg bf16 [s*B, 3072] -> qT,kT bf16 [b,h,s,d]; v -> vT [b,h,d,s]
// ---------------------------------------------------------------------------
__global__ __launch_bounds__(256) void k_repack(const unsigned short* __restrict__ qkvg,
                                                unsigned short* __restrict__ qT,
                                                unsigned short* __restrict__ kT,
                                                unsigned short* __restrict__ vT) {
    __shared__ unsigned short tile[64][72];
    int bh = blockIdx.y;
    int b = bh / NHH, h = bh % NHH;
    int s0 = blockIdx.x * 64;
    int t = threadIdx.x;
    // q,k: direct copy (layout already [s,d] per (b,h))
#pragma unroll
    for (int j = 0; j < 2; ++j) {
        int idx = t + j * 256;
        int r = idx >> 3, dc = idx & 7;
        const unsigned short* src = qkvg + ((size_t)(s0 + r) * BB + b) * 3072 + h * DD + dc * 8;
        ushort4 a = *(const ushort4*)src;
        ushort4 c = *(const ushort4*)(src + 4);
        unsigned short* dq = qT + ((size_t)bh * SS + s0 + r) * DD + dc * 8;
        *(ushort4*)dq = a; *(ushort4*)(dq + 4) = c;
        const unsigned short* srck = src + HH;
        ushort4 a2 = *(const ushort4*)srck;
        ushort4 c2 = *(const ushort4*)(srck + 4);
        unsigned short* dk = kT + ((size_t)bh * SS + s0 + r) * DD + dc * 8;
        *(ushort4*)dk = a2; *(ushort4*)(dk + 4) = c2;
    }
    // v: LDS transpose
#pragma unroll
    for (int j = 0; j < 4; ++j) {
        int idx = t + j * 256;
        int r = idx >> 4, c4 = idx & 15;
        ushort4 u = *(const ushort4*)(qkvg + ((size_t)(s0 + r) * BB + b) * 3072 + 1536 + h * DD + c4 * 4);
        *(ushort4*)&tile[r][c4 * 4] = u;
    }
    __syncthreads();
#pragma unroll
    for (int j = 0; j < 2; ++j) {
        int idx = t + j * 256;
        int d = idx >> 3, s8 = idx & 7;
        ushort4 a, c;
        a.x = tile[s8 * 8 + 0][d]; a.y = tile[s8 * 8 + 1][d];
        a.z = tile[s8 * 8 + 2][d]; a.w = tile[s8 * 8 + 3][d];
        c.x = tile[s8 * 8 + 4][d]; c.y = tile[s8 * 8 + 5][d];
        c.z = tile[s8 * 8 + 6][d]; c.w = tile[s8 * 8 + 7][d];
        unsigned short* dst = vT + ((size_t)bh * DD + d) * SS + s0 + s8 * 8;
        *(ushort4*)dst = a; *(ushort4*)(dst + 4) = c;
    }
}

// ---------------------------------------------------------------------------
// MFMA cp/pc: cp[b,h,q,r] = q . kposTab[r] (z=0), pc[b,h,k,r] = k . qposTab[r] (z=1)
//   A = qkvg (bf16) rows mt*128..+128, cols (z?768:0)+h*64..+64 -> M=128, K=64
//   B = posproj_all[l] (bf16) rows 0..63 (row 63 masked), cols (z?0:768)+h*64
//   grid (32, 12, 2), 256 threads (4 waves x 32 rows)
// ---------------------------------------------------------------------------
__global__ __launch_bounds__(256) void k_cp_pc_mfma(const unsigned short* __restrict__ qkvg,
                                                    const unsigned short* __restrict__ pp,
                                                    float* __restrict__ cp,
                                                    float* __restrict__ pc) {
    __shared__ unsigned short As[128 * 32];
    __shared__ unsigned short Bs[64 * 32];
    int mt = blockIdx.x, h = blockIdx.y, z = blockIdx.z;
    int aoff = z ? HH : 0;
    int toff = z ? 0 : HH;
    float* out = z ? pc : cp;
    const int t = threadIdx.x;
    const int lane = t & 63, wid = t >> 6;
    const int rA = lane & 15, kA = (lane >> 4) * 8;

    f32x4 acc[2][4] = {};

    for (int k0 = 0; k0 < 64; k0 += 32) {
#pragma unroll
        for (int j = 0; j < 2; ++j) {
            int c = t + j * 256;
            int r = c >> 2, ko = (c & 3) * 8;
            const unsigned short* srcA = qkvg + (size_t)(mt * 128 + r) * 3072 + aoff + h * DD + k0 + ko;
            unsigned short* dstA = As + (size_t)(j * 256 + wid * 64) * 8;
            __builtin_amdgcn_global_load_lds(
                (const __attribute__((address_space(1))) void*)srcA,
                (__attribute__((address_space(3))) void*)dstA, 16, 0, 0);
        }
        {
            int r = t >> 2, ko = (t & 3) * 8;
            const unsigned short* srcB = pp + (size_t)r * 1536 + toff + h * DD + k0 + ko;
            unsigned short* dstB = Bs + (size_t)(wid * 64) * 8;
            __builtin_amdgcn_global_load_lds(
                (const __attribute__((address_space(1))) void*)srcB,
                (__attribute__((address_space(3))) void*)dstB, 16, 0, 0);
        }
        __syncthreads();
        bf16x8 af[2], bfr[4];
#pragma unroll
        for (int m = 0; m < 2; ++m)
            af[m] = *(const bf16x8*)&As[(wid * 32 + m * 16 + rA) * 32 + kA];
#pragma unroll
        for (int n = 0; n < 4; ++n)
            bfr[n] = *(const bf16x8*)&Bs[(n * 16 + rA) * 32 + kA];
#pragma unroll
        for (int m = 0; m < 2; ++m)
#pragma unroll
            for (int n = 0; n < 4; ++n)
                acc[m][n] = __builtin_amdgcn_mfma_f32_16x16x32_bf16(af[m], bfr[n], acc[m][n], 0, 0, 0);
        __syncthreads();
    }

    const int cl = lane & 15, rg = (lane >> 4) * 4;
#pragma unroll
    for (int m = 0; m < 2; ++m)
#pragma unroll
        for (int n = 0; n < 4; ++n) {
            int gc = n * 16 + cl;
            if (gc < 63) {
#pragma unroll
                for (int i = 0; i < 4; ++i) {
                    int gr = mt * 128 + wid * 32 + m * 16 + rg + i;
                    int sIdx = gr >> 3, bIdx = gr & 7;
                    out[(((size_t)(bIdx * NHH + h)) * SS + sIdx) * 63 + gc] = acc[m][n][i];
                }
            }
        }
}

// ---------------------------------------------------------------------------
// fused disentangled flash attention (+ defer-max guard)
// ---------------------------------------------------------------------------
__global__ __launch_bounds__(256) void k_attn_fused(
    const unsigned short* __restrict__ qT, const unsigned short* __restrict__ kT,
    const unsigned short* __restrict__ vT, const float* __restrict__ cp,
    const float* __restrict__ pc, const int* __restrict__ bucket,
    const int* __restrict__ mask, float* __restrict__ ctxr) {
    __shared__ unsigned short pb_all[4][32 * 72];
    __shared__ int btab[1023];
    int t = threadIdx.x;
    for (int i = t; i < 1023; i += 256) btab[i] = bucket[i];
    __syncthreads();
    int lane = t & 63, wid = t >> 6;
    int bh = blockIdx.y;
    int b = bh / NHH, h = bh % NHH;
    int q0 = blockIdx.x * 128 + wid * 32;
    int rA = lane & 15, g = lane >> 4, kA = g * 8;
    unsigned short* pb = pb_all[wid];
    const unsigned short* qTb = qT + (size_t)bh * SS * DD;
    const unsigned short* kTb = kT + (size_t)bh * SS * DD;
    const unsigned short* vTb = vT + (size_t)bh * DD * SS;
    const float* cpb = cp + (size_t)bh * SS * 63;
    const float* pcb = pc + (size_t)bh * SS * 63;
    const int* mkb = mask + b * SS;

    bf16x8 aq[2][2];
#pragma unroll
    for (int m = 0; m < 2; ++m)
#pragma unroll
        for (int dc = 0; dc < 2; ++dc)
            aq[m][dc] = *(const bf16x8*)&qTb[(size_t)(q0 + m * 16 + rA) * DD + dc * 32 + kA];

    f32x4 o[2][4] = {};
    float mrow[2][4], lrow[2][4];
#pragma unroll
    for (int m = 0; m < 2; ++m)
#pragma unroll
        for (int i = 0; i < 4; ++i) { mrow[m][i] = -INFINITY; lrow[m][i] = 0.f; }

    for (int kt = 0; kt < 8; ++kt) {
        int k0 = kt * 64;
        f32x4 sa[2][4] = {};
#pragma unroll
        for (int n = 0; n < 4; ++n) {
            bf16x8 bk0 = *(const bf16x8*)&kTb[(size_t)(k0 + n * 16 + rA) * DD + kA];
            bf16x8 bk1 = *(const bf16x8*)&kTb[(size_t)(k0 + n * 16 + rA) * DD + 32 + kA];
#pragma unroll
            for (int m = 0; m < 2; ++m) {
                sa[m][n] = __builtin_amdgcn_mfma_f32_16x16x32_bf16(aq[m][0], bk0, sa[m][n], 0, 0, 0);
                sa[m][n] = __builtin_amdgcn_mfma_f32_16x16x32_bf16(aq[m][1], bk1, sa[m][n], 0, 0, 0);
            }
        }
        int mk[4];
#pragma unroll
        for (int n = 0; n < 4; ++n) mk[n] = mkb[k0 + n * 16 + rA];

        float pv[2][4][4];
#pragma unroll
        for (int m = 0; m < 2; ++m) {
#pragma unroll
            for (int i = 0; i < 4; ++i) {
                int q = q0 + m * 16 + g * 4 + i;
                float sv[4];
                float tmax = -INFINITY;
#pragma unroll
                for (int n = 0; n < 4; ++n) {
                    int k = k0 + n * 16 + rA;
                    int id = btab[q - k + 511];
                    float v = (sa[m][n][i] + cpb[q * 63 + id] + pcb[k * 63 + id]) * SCALE_F;
                    v = mk[n] ? -1e9f : v;
                    sv[n] = v;
                    tmax = fmaxf(tmax, v);
                }
                tmax = fmaxf(tmax, __shfl_xor(tmax, 1, 16));
                tmax = fmaxf(tmax, __shfl_xor(tmax, 2, 16));
                tmax = fmaxf(tmax, __shfl_xor(tmax, 4, 16));
                tmax = fmaxf(tmax, __shfl_xor(tmax, 8, 16));
                float mold = mrow[m][i];
                float mnew = fmaxf(mold, tmax);
                float ls = 0.f;
#pragma unroll
                for (int n = 0; n < 4; ++n) {
                    float p = __expf(sv[n] - mnew);
                    pv[m][n][i] = p;
                    ls += p;
                }
                ls += __shfl_xor(ls, 1, 16);
                ls += __shfl_xor(ls, 2, 16);
                ls += __shfl_xor(ls, 4, 16);
                ls += __shfl_xor(ls, 8, 16);
                if (mnew > mold) {
                    float alpha = __expf(mold - mnew);
                    lrow[m][i] = lrow[m][i] * alpha + ls;
                    mrow[m][i] = mnew;
#pragma unroll
                    for (int n = 0; n < 4; ++n) o[m][n][i] *= alpha;
                } else {
                    lrow[m][i] += ls;
                }
            }
        }
#pragma unroll
        for (int m = 0; m < 2; ++m)
#pragma unroll
            for (int n = 0; n < 4; ++n)
#pragma unroll
                for (int i = 0; i < 4; ++i)
                    pb[(m * 16 + g * 4 + i) * 72 + n * 16 + rA] = f2b(pv[m][n][i]);
        bf16x8 ap[2][2];
#pragma unroll
        for (int m = 0; m < 2; ++m)
#pragma unroll
            for (int kc = 0; kc < 2; ++kc)
                ap[m][kc] = *(const bf16x8*)&pb[(m * 16 + rA) * 72 + kc * 32 + kA];
#pragma unroll
        for (int n = 0; n < 4; ++n) {
            bf16x8 bv0 = *(const bf16x8*)&vTb[(size_t)(n * 16 + rA) * SS + k0 + kA];
            bf16x8 bv1 = *(const bf16x8*)&vTb[(size_t)(n * 16 + rA) * SS + k0 + 32 + kA];
#pragma unroll
            for (int m = 0; m < 2; ++m) {
                o[m][n] = __builtin_amdgcn_mfma_f32_16x16x32_bf16(ap[m][0], bv0, o[m][n], 0, 0, 0);
                o[m][n] = __builtin_amdgcn_mfma_f32_16x16x32_bf16(ap[m][1], bv1, o[m][n], 0, 0, 0);
            }
        }
    }
#pragma unroll
    for (int m = 0; m < 2; ++m)
#pragma unroll
        for (int i = 0; i < 4; ++i) {
            int q = q0 + m * 16 + g * 4 + i;
            float inv = 1.0f / lrow[m][i];
#pragma unroll
            for (int n = 0; n < 4; ++n)
                ctxr[((size_t)q * BB + b) * HH + h * DD + n * 16 + rA] = o[m][n][i] * inv;
        }
}

// ---------------------------------------------------------------------------
// host launcher
// ---------------------------------------------------------------------------
static inline void gemm_bf(const unsigned short* A, int lda, const unsigned short* W, int ldw,
                           void* C, int ldc, int M, int N, int K,
                           const float* bias, const float* bias2, const float* res,
                           int obf, hipStream_t st) {
    dim3 g(N / 128, M / 128);
    if (obf)
        k_gemm_bf16<1><<<g, 256, 0, st>>>(A, lda, W, ldw, C, ldc, M, N, K, bias, bias2, res, 0, 0, 0);
    else
        k_gemm_bf16<0><<<g, 256, 0, st>>>(A, lda, W, ldw, C, ldc, M, N, K, bias, bias2, res, 0, 0, 0);
}

static inline void gemm_big(const unsigned short* A, int lda,
                            const unsigned short* W, const unsigned short* Wb2, int ldw,
                            void* C, int ldc, int M, int N, int K,
                            const float* bias, const float* bias2, const float* res,
                            int obf, hipStream_t st) {
    dim3 g(N / 256, M / 128);
    if (obf)
        k_gemm_big<1><<<g, 512, 3 * GSLOT, st>>>(A, lda, W, Wb2, ldw, C, ldc, M, N, K, bias, bias2, res);
    else
        k_gemm_big<0><<<g, 512, 3 * GSLOT, st>>>(A, lda, W, Wb2, ldw, C, ldc, M, N, K, bias, bias2, res);
}

extern "C" void kernel_launch(void* const* d_in, const int* in_sizes, int n_in,
                              void* d_out, int out_size, void* d_ws, size_t ws_size,
                              hipStream_t stream) {
    static int attr_done = 0;
    if (!attr_done) {
        hipFuncSetAttribute((const void*)&k_gemm_big<1>,
                            hipFuncAttributeMaxDynamicSharedMemorySize, 3 * GSLOT);
        hipFuncSetAttribute((const void*)&k_gemm_big<0>,
                            hipFuncAttributeMaxDynamicSharedMemorySize, 3 * GSLOT);
        attr_done = 1;
    }

    const int* ids = (const int*)d_in[0];
    const unsigned char* maskraw = (const unsigned char*)d_in[1];
    const float* word_emb = (const float*)d_in[2];
    const float* rel_emb = (const float*)d_in[3];
    const float* rel_g = (const float*)d_in[4];
    const float* rel_b = (const float*)d_in[5];
    const float* Wqk = (const float*)d_in[6];
    const float* bqk = (const float*)d_in[7];
    const float* Wvg = (const float*)d_in[8];
    const float* bvg = (const float*)d_in[9];
    const float* Wout = (const float*)d_in[10];
    const float* bout = (const float*)d_in[11];
    const float* W1 = (const float*)d_in[12];
    const float* W2 = (const float*)d_in[13];

    const size_t N_X = (size_t)SS * BB * HH;
    const size_t N_CP = (size_t)SS * BB * NHH * 63;
    const size_t N_H2 = (size_t)SS * BB * II;
    const size_t N_WQK = (size_t)2 * HH * HH;         // 1,179,648
    const size_t N_WOUT = (size_t)HH * HH;
    const size_t N_W1 = (size_t)2 * II * HH;
    const size_t N_W2 = (size_t)HH * II;
    const size_t N_HD = (size_t)BB * NHH * SS * DD;
    const size_t N_QKVG = (size_t)SS * BB * 3072;
    const size_t N_FFH = (size_t)SS * BB * 4096;
    const size_t N_PP = (size_t)128 * 1536;           // 196,608

    float* ws = (float*)d_ws;
    float* x = ws;
    float* ctxr = x + N_X;
    float* cp = ctxr + N_X;
    float* pc = cp + N_CP;
    unsigned short* us = (unsigned short*)(pc + N_CP);
    unsigned short* qkvg = us;
    unsigned short* hs_bf = qkvg + N_QKVG;
    unsigned short* ctx_bf = hs_bf + N_X;
    unsigned short* h2_bf = ctx_bf + N_X;
    unsigned short* ffh = h2_bf + N_H2;
    unsigned short* wqk_all = ffh + N_FFH;            // 12 x [Wqk] bf16
    unsigned short* wvg_bf = wqk_all + 12 * N_WQK;    // per-layer: Wvg,Wout,W1,W2
    unsigned short* wout_bf = wvg_bf + N_WQK;
    unsigned short* w1_bf = wout_bf + N_WOUT;
    unsigned short* w2_bf = w1_bf + N_W1;
    unsigned short* ppall = w2_bf + N_W2;             // 12 x posproj bf16 [128,1536]
    unsigned short* rel_bf = ppall + 12 * N_PP;       // 128*768 (padded)
    unsigned short* qT = rel_bf + 128 * HH;
    unsigned short* kT = qT + N_HD;
    unsigned short* vT = kT + N_HD;
    int* bucket = (int*)(vT + N_HD);
    int* maski = bucket + 1024;

    size_t need_bytes = ((size_t)(maski + BB * SS) - (size_t)d_ws);
    if (ws_size < need_bytes) return;  // ~205 MB required

    // ---- setup ----
    k_decode_mask<<<1, 256, 0, stream>>>(maskraw, maski, BB * SS);
    k_bucket<<<4, 256, 0, stream>>>(bucket);
    k_embed_ln<<<SS * BB, 256, 0, stream>>>(ids, word_emb, x);
    k_rel_ln_bf<<<128, 256, 0, stream>>>(rel_emb, rel_g, rel_b, rel_bf);
    // all 12 layers' Wqk -> bf16 (contiguous input)
    k_f2b<<<(int)((12 * N_WQK / 8 + 255) / 256), 256, 0, stream>>>(Wqk, wqk_all,
                                                                   (int)(12 * N_WQK / 8));
    // batched posproj for all layers: posproj[l] = rel * Wqk[l]^T + bqk[l] (bf16 out)
    {
        dim3 gpp(1536 / 128, 1, 12);
        k_gemm_bf16<1><<<gpp, 256, 0, stream>>>(rel_bf, HH, wqk_all, HH, ppall, 1536,
                                                128, 1536, HH, bqk, nullptr, nullptr,
                                                N_WQK, N_PP, 2 * HH);
    }

    for (int l = 0; l < LL; ++l) {
        const unsigned short* wqk_l = wqk_all + (size_t)l * N_WQK;
        const float* bqk_l = bqk + (size_t)l * 2 * HH;
        const float* Wvg_l = Wvg + (size_t)l * N_WQK;
        const float* bvg_l = bvg + (size_t)l * 2 * HH;
        const float* Wout_l = Wout + (size_t)l * N_WOUT;
        const float* bout_l = bout + (size_t)l * HH;
        const float* W1_l = W1 + (size_t)l * N_W1;
        const float* W2_l = W2 + (size_t)l * N_W2;

        k_f2b_rest<<<3169, 256, 0, stream>>>(Wvg_l, Wout_l, W1_l, W2_l, wvg_bf);

        // ---- attention ----
        k_ln_bf<<<SS * BB, 256, 0, stream>>>(x, hs_bf);
        gemm_big(hs_bf, HH, wqk_l, wvg_bf, HH, qkvg, 3072, SS * BB, 3072, HH,
                 bqk_l, bvg_l, nullptr, 1, stream);
        k_repack<<<dim3(SS / 64, BB * NHH), 256, 0, stream>>>(qkvg, qT, kT, vT);
        k_cp_pc_mfma<<<dim3(SS * BB / 128, NHH, 2), 256, 0, stream>>>(
            qkvg, ppall + (size_t)l * N_PP, cp, pc);
        k_attn_fused<<<dim3(SS / 128, BB * NHH), 256, 0, stream>>>(qT, kT, vT, cp, pc,
                                                                   bucket, maski, ctxr);
        k_gated_ln<<<SS * BB, 256, 0, stream>>>(ctxr, qkvg, ctx_bf);
        gemm_bf(ctx_bf, HH, wout_bf, HH, x, HH, SS * BB, HH, HH,
                bout_l, nullptr, x, 0, stream);

        // ---- GeGLU FFN ----
        k_ln_bf<<<SS * BB, 256, 0, stream>>>(x, hs_bf);
        gemm_big(hs_bf, HH, w1_bf, nullptr, HH, ffh, 4096, SS * BB, 4096, HH,
                 nullptr, nullptr, nullptr, 1, stream);
        k_ffn_ln<<<SS * BB, 256, 0, stream>>>(ffh, h2_bf);
        gemm_bf(h2_bf, II, w2_bf, II, x, HH, SS * BB, HH, II,
                nullptr, nullptr, x, 0, stream);
    }

    hipMemcpyAsync(d_out, x, N_X * sizeof(float), hipMemcpyDeviceToDevice, stream);
}

// Round 7
// 3409.814 us; speedup vs baseline: 4.3768x; 1.0644x over previous
//
#include <hip/hip_runtime.h>
#include <math.h>

#define SS 512
#define BB 8
#define NHH 12
#define DD 64
#define HH 768
#define II 2048
#define LL 12
#define SCALE_F 0.07216878364870323f  /* 1/sqrt(3*64) */

typedef __attribute__((ext_vector_type(8))) short bf16x8;
typedef __attribute__((ext_vector_type(4))) float f32x4;

// f32 -> bf16 (RNE, finite values)
__device__ __forceinline__ unsigned short f2b(float f) {
    union { float f; unsigned int u; } x; x.f = f;
    unsigned int r = x.u + 0x7fffu + ((x.u >> 16) & 1u);
    return (unsigned short)(r >> 16);
}
__device__ __forceinline__ float b2f(unsigned short u) {
    union { unsigned int u; float f; } x; x.u = ((unsigned int)u) << 16;
    return x.f;
}

// ---------------------------------------------------------------------------
// block reduction helpers (blockDim.x == 256)
// ---------------------------------------------------------------------------
__device__ __forceinline__ float2 blockReduceSum2(float a, float b) {
    __shared__ float2 sm[4];
    __shared__ float2 bc;
#pragma unroll
    for (int o = 32; o > 0; o >>= 1) {
        a += __shfl_down(a, o);
        b += __shfl_down(b, o);
    }
    int t = threadIdx.x;
    if ((t & 63) == 0) sm[t >> 6] = make_float2(a, b);
    __syncthreads();
    if (t == 0) {
        float xa = sm[0].x + sm[1].x + sm[2].x + sm[3].x;
        float xb = sm[0].y + sm[1].y + sm[2].y + sm[3].y;
        bc = make_float2(xa, xb);
    }
    __syncthreads();
    return bc;
}

__device__ __forceinline__ float gelu_erf(float v) {
    return 0.5f * v * (1.0f + erff(v * 0.70710678118654752f));
}
__device__ __forceinline__ float gelu_tanh(float v) {
    const float c = 0.7978845608028654f;
    return 0.5f * v * (1.0f + tanhf(c * (v + 0.044715f * v * v * v)));
}

// ---------------------------------------------------------------------------
// mask decode: handle bool-as-u8 or bool-as-int32 layouts
// ---------------------------------------------------------------------------
__global__ __launch_bounds__(256) void k_decode_mask(const unsigned char* __restrict__ raw,
                                                     int* __restrict__ mask, int n) {
    __shared__ int s_any;
    if (threadIdx.x == 0) s_any = 0;
    __syncthreads();
    int local = 0;
    for (int i = threadIdx.x; i < n; i += blockDim.x)
        if ((i & 3) && raw[i]) local = 1;
    if (local) atomicOr(&s_any, 1);
    __syncthreads();
    bool isU8 = (s_any != 0);
    const int* as_int = (const int*)raw;
    for (int i = threadIdx.x; i < n; i += blockDim.x)
        mask[i] = isU8 ? (raw[i] != 0) : (as_int[i] != 0);
}

// ---------------------------------------------------------------------------
// DeBERTa log-bucket table: rel in [-511,511] -> idx in [0,62]
// ---------------------------------------------------------------------------
__global__ __launch_bounds__(256) void k_bucket(int* __restrict__ tab) {
    int i = blockIdx.x * 256 + threadIdx.x;
    if (i >= 1023) return;
    int rel = i - 511;
    int a = rel < 0 ? -rel : rel;
    int abs_pos = (a < 16) ? 15 : (a < 511 ? a : 511);
    int bucket;
    if (abs_pos <= 16) {
        bucket = rel;
    } else {
        double lp = ceil(log((double)abs_pos / 16.0) / log(511.0 / 16.0) * 15.0);
        int l = (int)lp + 16;
        bucket = (rel > 0) ? l : -l;
    }
    int idx = bucket + 31;
    if (idx < 0) idx = 0;
    if (idx > 62) idx = 62;
    tab[i] = idx;
}

// ---------------------------------------------------------------------------
// generic f32 -> bf16 bulk conversion (8 elems/thread)
// ---------------------------------------------------------------------------
__global__ __launch_bounds__(256) void k_f2b(const float* __restrict__ in,
                                             unsigned short* __restrict__ out, int n8) {
    int i = blockIdx.x * 256 + threadIdx.x;
    if (i >= n8) return;
    float4 a = ((const float4*)in)[2 * (size_t)i];
    float4 b = ((const float4*)in)[2 * (size_t)i + 1];
    ushort4 lo, hi;
    lo.x = f2b(a.x); lo.y = f2b(a.y); lo.z = f2b(a.z); lo.w = f2b(a.w);
    hi.x = f2b(b.x); hi.y = f2b(b.y); hi.z = f2b(b.z); hi.w = f2b(b.w);
    ((ushort4*)out)[2 * (size_t)i] = lo;
    ((ushort4*)out)[2 * (size_t)i + 1] = hi;
}

// per-layer: Wvg, Wout, W1, W2 -> contiguous bf16 (chunk units of 8 elems)
__global__ __launch_bounds__(256) void k_f2b_rest(const float* __restrict__ wvg,
                                                  const float* __restrict__ wout,
                                                  const float* __restrict__ w1,
                                                  const float* __restrict__ w2,
                                                  unsigned short* __restrict__ out) {
    int i = blockIdx.x * 256 + threadIdx.x;
    if (i >= 811008) return;
    const float* src;
    int off;
    if (i < 221184) {
        if (i < 147456) { src = wvg;  off = i; }
        else            { src = wout; off = i - 147456; }
    } else if (i < 614400) { src = w1; off = i - 221184; }
    else                   { src = w2; off = i - 614400; }
    float4 a = ((const float4*)src)[2 * (size_t)off];
    float4 b = ((const float4*)src)[2 * (size_t)off + 1];
    ushort4 lo, hi;
    lo.x = f2b(a.x); lo.y = f2b(a.y); lo.z = f2b(a.z); lo.w = f2b(a.w);
    hi.x = f2b(b.x); hi.y = f2b(b.y); hi.z = f2b(b.z); hi.w = f2b(b.w);
    ((ushort4*)out)[2 * (size_t)i] = lo;
    ((ushort4*)out)[2 * (size_t)i + 1] = hi;
}

// ---------------------------------------------------------------------------
// LayerNorm family; EPS = 1e-7, biased variance
// ---------------------------------------------------------------------------
__global__ __launch_bounds__(256) void k_ln_bf(const float* __restrict__ in,
                                               unsigned short* __restrict__ out) {
    int row = blockIdx.x, t = threadIdx.x;
    const float* r = in + (size_t)row * HH;
    float v0 = r[t], v1 = r[t + 256], v2 = r[t + 512];
    float s = v0 + v1 + v2;
    float ss = v0 * v0 + v1 * v1 + v2 * v2;
    float2 r2 = blockReduceSum2(s, ss);
    float mean = r2.x * (1.0f / HH);
    float var = r2.y * (1.0f / HH) - mean * mean;
    float rs = rsqrtf(var + 1e-7f);
    unsigned short* o = out + (size_t)row * HH;
    o[t] = f2b((v0 - mean) * rs);
    o[t + 256] = f2b((v1 - mean) * rs);
    o[t + 512] = f2b((v2 - mean) * rs);
}

__global__ __launch_bounds__(256) void k_embed_ln(const int* __restrict__ ids,
                                                  const float* __restrict__ emb,
                                                  float* __restrict__ out) {
    int row = blockIdx.x, t = threadIdx.x;
    const float* r = emb + (size_t)ids[row] * HH;
    float v0 = r[t], v1 = r[t + 256], v2 = r[t + 512];
    float s = v0 + v1 + v2;
    float ss = v0 * v0 + v1 * v1 + v2 * v2;
    float2 r2 = blockReduceSum2(s, ss);
    float mean = r2.x * (1.0f / HH);
    float var = r2.y * (1.0f / HH) - mean * mean;
    float rs = rsqrtf(var + 1e-7f);
    float* o = out + (size_t)row * HH;
    o[t] = (v0 - mean) * rs;
    o[t + 256] = (v1 - mean) * rs;
    o[t + 512] = (v2 - mean) * rs;
}

// rel LN -> bf16, padded to 128 rows (rows 63..127 zero)
__global__ __launch_bounds__(256) void k_rel_ln_bf(const float* __restrict__ rel_emb,
                                                   const float* __restrict__ g,
                                                   const float* __restrict__ b,
                                                   unsigned short* __restrict__ out) {
    int row = blockIdx.x, t = threadIdx.x;
    unsigned short* o = out + (size_t)row * HH;
    if (row >= 63) {
        o[t] = 0; o[t + 256] = 0; o[t + 512] = 0;
        return;
    }
    const float* r = rel_emb + (size_t)row * HH;
    float v0 = r[t], v1 = r[t + 256], v2 = r[t + 512];
    float s = v0 + v1 + v2;
    float ss = v0 * v0 + v1 * v1 + v2 * v2;
    float2 r2 = blockReduceSum2(s, ss);
    float mean = r2.x * (1.0f / HH);
    float var = r2.y * (1.0f / HH) - mean * mean;
    float rs = rsqrtf(var + 1e-7f);
    o[t] = f2b((v0 - mean) * rs * g[t] + b[t]);
    o[t + 256] = f2b((v1 - mean) * rs * g[t + 256] + b[t + 256]);
    o[t + 512] = f2b((v2 - mean) * rs * g[t + 512] + b[t + 512]);
}

// ctx_bf = bf16(LN(ctxr * gelu_exact(g))), g = qkvg[..., 2304:3072] (bf16)
__global__ __launch_bounds__(256) void k_gated_ln(const float* __restrict__ ctxr,
                                                  const unsigned short* __restrict__ qkvg,
                                                  unsigned short* __restrict__ out) {
    int row = blockIdx.x, t = threadIdx.x;
    const float* cr = ctxr + (size_t)row * HH;
    const unsigned short* gr = qkvg + (size_t)row * 3072 + 2304;
    float v[3];
    float s = 0.f, ss = 0.f;
#pragma unroll
    for (int e = 0; e < 3; ++e) {
        int i = t + e * 256;
        float x = cr[i] * gelu_erf(b2f(gr[i]));
        v[e] = x;
        s += x; ss += x * x;
    }
    float2 r2 = blockReduceSum2(s, ss);
    float mean = r2.x * (1.0f / HH);
    float var = r2.y * (1.0f / HH) - mean * mean;
    float rs = rsqrtf(var + 1e-7f);
    unsigned short* o = out + (size_t)row * HH;
#pragma unroll
    for (int e = 0; e < 3; ++e) o[t + e * 256] = f2b((v[e] - mean) * rs);
}

// h2_bf = bf16(LN(ffh[:, :I] * gelu_tanh(ffh[:, I:])))  (ffh bf16 [row][4096])
__global__ __launch_bounds__(256) void k_ffn_ln(const unsigned short* __restrict__ ffh,
                                                unsigned short* __restrict__ out) {
    int row = blockIdx.x, t = threadIdx.x;
    const unsigned short* ar = ffh + (size_t)row * 4096 + t * 8;
    const unsigned short* gr = ar + II;
    ushort4 a0 = *(const ushort4*)ar;
    ushort4 a1 = *(const ushort4*)(ar + 4);
    ushort4 g0 = *(const ushort4*)gr;
    ushort4 g1 = *(const ushort4*)(gr + 4);
    float av[8] = {b2f(a0.x), b2f(a0.y), b2f(a0.z), b2f(a0.w),
                   b2f(a1.x), b2f(a1.y), b2f(a1.z), b2f(a1.w)};
    float gv[8] = {b2f(g0.x), b2f(g0.y), b2f(g0.z), b2f(g0.w),
                   b2f(g1.x), b2f(g1.y), b2f(g1.z), b2f(g1.w)};
    float v[8];
    float s = 0.f, ss = 0.f;
#pragma unroll
    for (int e = 0; e < 8; ++e) {
        float x = av[e] * gelu_tanh(gv[e]);
        v[e] = x;
        s += x; ss += x * x;
    }
    float2 r2 = blockReduceSum2(s, ss);
    float mean = r2.x * (1.0f / II);
    float var = r2.y * (1.0f / II) - mean * mean;
    float rs = rsqrtf(var + 1e-7f);
    ushort4 o0, o1;
    o0.x = f2b((v[0] - mean) * rs); o0.y = f2b((v[1] - mean) * rs);
    o0.z = f2b((v[2] - mean) * rs); o0.w = f2b((v[3] - mean) * rs);
    o1.x = f2b((v[4] - mean) * rs); o1.y = f2b((v[5] - mean) * rs);
    o1.z = f2b((v[6] - mean) * rs); o1.w = f2b((v[7] - mean) * rs);
    unsigned short* o = out + (size_t)row * II + t * 8;
    *(ushort4*)o = o0;
    *(ushort4*)(o + 4) = o1;
}

// ---------------------------------------------------------------------------
// bf16 MFMA GEMM (m97 structure + bijective XCD swizzle + optional z-batch)
// ---------------------------------------------------------------------------
template <int OBF>
__global__ __launch_bounds__(256) void k_gemm_bf16(const unsigned short* __restrict__ A, int lda,
                                                   const unsigned short* __restrict__ W, int ldw,
                                                   void* __restrict__ Cv, int ldc,
                                                   int M, int N, int K,
                                                   const float* __restrict__ bias,
                                                   const float* __restrict__ bias2,
                                                   const float* __restrict__ res,
                                                   size_t wz, size_t cz, size_t bz) {
    __shared__ unsigned short As[128 * 32];
    __shared__ unsigned short Ws[128 * 32];
    int zz = blockIdx.z;
    W += (size_t)zz * wz;
    if (bias) bias += (size_t)zz * bz;
    int nwg = gridDim.x * gridDim.y;
    int orig = blockIdx.y * gridDim.x + blockIdx.x;
    int qq = nwg >> 3, rr = nwg & 7;
    int xcd = orig & 7, idx = orig >> 3;
    int wg = (xcd < rr ? xcd * (qq + 1) : rr * (qq + 1) + (xcd - rr) * qq) + idx;
    int bx = wg % gridDim.x, by = wg / gridDim.x;

    const int t = threadIdx.x;
    const int lane = t & 63, wid = t >> 6;
    const int row0 = by * 128, col0 = bx * 128;
    const int wr = (wid >> 1) * 64, wc = (wid & 1) * 64;
    const int rA = lane & 15, kA = (lane >> 4) * 8;

    f32x4 acc[4][4] = {};

    for (int k0 = 0; k0 < K; k0 += 32) {
#pragma unroll
        for (int j = 0; j < 2; ++j) {
            int c = t + j * 256;
            int r = c >> 2, ko = (c & 3) * 8;
            const unsigned short* srcA = A + (size_t)(row0 + r) * lda + k0 + ko;
            const unsigned short* srcB = W + (size_t)(col0 + r) * ldw + k0 + ko;
            unsigned short* dstA = As + (size_t)(j * 256 + wid * 64) * 8;
            unsigned short* dstB = Ws + (size_t)(j * 256 + wid * 64) * 8;
            __builtin_amdgcn_global_load_lds(
                (const __attribute__((address_space(1))) void*)srcA,
                (__attribute__((address_space(3))) void*)dstA, 16, 0, 0);
            __builtin_amdgcn_global_load_lds(
                (const __attribute__((address_space(1))) void*)srcB,
                (__attribute__((address_space(3))) void*)dstB, 16, 0, 0);
        }
        __syncthreads();
        bf16x8 af[4], bfr[4];
#pragma unroll
        for (int m = 0; m < 4; ++m)
            af[m] = *(const bf16x8*)&As[(wr + m * 16 + rA) * 32 + kA];
#pragma unroll
        for (int n = 0; n < 4; ++n)
            bfr[n] = *(const bf16x8*)&Ws[(wc + n * 16 + rA) * 32 + kA];
#pragma unroll
        for (int m = 0; m < 4; ++m)
#pragma unroll
            for (int n = 0; n < 4; ++n)
                acc[m][n] = __builtin_amdgcn_mfma_f32_16x16x32_bf16(af[m], bfr[n], acc[m][n], 0, 0, 0);
        __syncthreads();
    }

    float* Cf = (float*)Cv + (size_t)zz * cz;
    unsigned short* Cb = (unsigned short*)Cv + (size_t)zz * cz;
    const int cl = lane & 15, rg = (lane >> 4) * 4;
#pragma unroll
    for (int n = 0; n < 4; ++n) {
        int gc = col0 + wc + n * 16 + cl;
        float bv = 0.0f;
        if (bias) bv = (bias2 && gc >= 1536) ? bias2[gc - 1536] : bias[gc];
#pragma unroll
        for (int m = 0; m < 4; ++m) {
#pragma unroll
            for (int i = 0; i < 4; ++i) {
                int gr = row0 + wr + m * 16 + rg + i;
                float v = acc[m][n][i] + bv;
                if (OBF) {
                    Cb[(size_t)gr * ldc + gc] = f2b(v);
                } else {
                    if (res) v += res[(size_t)gr * ldc + gc];
                    Cf[(size_t)gr * ldc + gc] = v;
                }
            }
        }
    }
}

// ---------------------------------------------------------------------------
// Pipelined bf16 MFMA GEMM for the large GEMMs (qkvg, W1)
// ---------------------------------------------------------------------------
#define GSLOT 49152  /* 48 KB: A 16KB @0, B 32KB @16384 */

__device__ __forceinline__ void g_stage(const unsigned short* __restrict__ Abase, int lda,
                                        const unsigned short* __restrict__ Wbase, int ldw,
                                        unsigned char* slot, int t, int wid) {
    int rit = t >> 3;
    int kb = (t & 7) << 4;
#pragma unroll
    for (int c = 0; c < 2; ++c) {
        int row = c * 64 + rit;
        int gkb = kb ^ ((row & 7) << 4);
        const unsigned short* src = Abase + (size_t)row * lda + (gkb >> 1);
        unsigned char* dst = slot + c * 8192 + wid * 1024;
        __builtin_amdgcn_global_load_lds(
            (const __attribute__((address_space(1))) void*)src,
            (__attribute__((address_space(3))) void*)dst, 16, 0, 0);
    }
#pragma unroll
    for (int c = 0; c < 4; ++c) {
        int row = c * 64 + rit;
        int gkb = kb ^ ((row & 7) << 4);
        const unsigned short* src = Wbase + (size_t)row * ldw + (gkb >> 1);
        unsigned char* dst = slot + 16384 + c * 8192 + wid * 1024;
        __builtin_amdgcn_global_load_lds(
            (const __attribute__((address_space(1))) void*)src,
            (__attribute__((address_space(3))) void*)dst, 16, 0, 0);
    }
}

__device__ __forceinline__ void g_compute(const unsigned char* slot, int wm, int wn,
                                          int rA, int g16, f32x4 acc[4][4]) {
    const unsigned char* Ab = slot;
    const unsigned char* Bb = slot + 16384;
    bf16x8 a[4][2], b[4][2];
#pragma unroll
    for (int m = 0; m < 4; ++m) {
        int row = wm * 64 + m * 16 + rA;
        int sw = (row & 7) << 4;
#pragma unroll
        for (int s = 0; s < 2; ++s)
            a[m][s] = *(const bf16x8*)(Ab + row * 128 + ((s * 64 + g16 * 16) ^ sw));
    }
#pragma unroll
    for (int n = 0; n < 4; ++n) {
        int row = wn * 64 + n * 16 + rA;
        int sw = (row & 7) << 4;
#pragma unroll
        for (int s = 0; s < 2; ++s)
            b[n][s] = *(const bf16x8*)(Bb + row * 128 + ((s * 64 + g16 * 16) ^ sw));
    }
    __builtin_amdgcn_s_setprio(1);
#pragma unroll
    for (int m = 0; m < 4; ++m)
#pragma unroll
        for (int n = 0; n < 4; ++n) {
            acc[m][n] = __builtin_amdgcn_mfma_f32_16x16x32_bf16(a[m][0], b[n][0], acc[m][n], 0, 0, 0);
            acc[m][n] = __builtin_amdgcn_mfma_f32_16x16x32_bf16(a[m][1], b[n][1], acc[m][n], 0, 0, 0);
        }
    __builtin_amdgcn_s_setprio(0);
}

template <int OBF>
__global__ __launch_bounds__(512, 1) void k_gemm_big(const unsigned short* __restrict__ A, int lda,
                                                     const unsigned short* __restrict__ W,
                                                     const unsigned short* __restrict__ Wb2, int ldw,
                                                     void* __restrict__ Cv, int ldc,
                                                     int M, int N, int K,
                                                     const float* __restrict__ bias,
                                                     const float* __restrict__ bias2,
                                                     const float* __restrict__ res) {
    extern __shared__ unsigned char smem[];
    int nwg = gridDim.x * gridDim.y;
    int orig = blockIdx.y * gridDim.x + blockIdx.x;
    int qq = nwg >> 3, rr = nwg & 7;
    int xcd = orig & 7, idx = orig >> 3;
    int wg = (xcd < rr ? xcd * (qq + 1) : rr * (qq + 1) + (xcd - rr) * qq) + idx;
    int bx = wg % gridDim.x, by = wg / gridDim.x;

    const int t = threadIdx.x;
    const int lane = t & 63, wid = t >> 6;
    const int wm = wid >> 2, wn = wid & 3;
    const int rA = lane & 15, g16 = lane >> 4;
    const int row0 = by * 128, col0 = bx * 256;
    const unsigned short* Abase = A + (size_t)row0 * lda;
    const unsigned short* Wbase = (Wb2 && col0 >= 1536)
                                      ? Wb2 + (size_t)(col0 - 1536) * ldw
                                      : W + (size_t)col0 * ldw;

    const int nt = K >> 6;
    f32x4 acc[4][4] = {};

    g_stage(Abase, lda, Wbase, ldw, smem, t, wid);
    g_stage(Abase + 64, lda, Wbase + 64, ldw, smem + GSLOT, t, wid);

#define GBAR() asm volatile("s_barrier" ::: "memory")
#define GITER(T, STG, VMSTR)                                                        \
    do {                                                                            \
        GBAR();                                                                     \
        if (STG)                                                                    \
            g_stage(Abase + (size_t)(T + 2) * 64, lda, Wbase + (size_t)(T + 2) * 64,\
                    ldw, smem + (size_t)((T + 2) % 3) * GSLOT, t, wid);             \
        asm volatile(VMSTR ::: "memory");                                           \
        GBAR();                                                                     \
        g_compute(smem + (size_t)((T) % 3) * GSLOT, wm, wn, rA, g16, acc);          \
    } while (0)

    int tt = 0;
    for (; tt < nt - 2; ++tt) GITER(tt, true, "s_waitcnt vmcnt(12)");
    GITER(tt, false, "s_waitcnt vmcnt(6)");
    ++tt;
    GITER(tt, false, "s_waitcnt vmcnt(0)");
#undef GITER
#undef GBAR

    float* Cf = (float*)Cv;
    unsigned short* Cb = (unsigned short*)Cv;
    const int cl = lane & 15, rg = (lane >> 4) * 4;
#pragma unroll
    for (int n = 0; n < 4; ++n) {
        int gc = col0 + wn * 64 + n * 16 + cl;
        float bv = 0.0f;
        if (bias) bv = (bias2 && gc >= 1536) ? bias2[gc - 1536] : bias[gc];
#pragma unroll
        for (int m = 0; m < 4; ++m) {
#pragma unroll
            for (int i = 0; i < 4; ++i) {
                int gr = row0 + wm * 64 + m * 16 + rg + i;
                float v = acc[m][n][i] + bv;
                if (OBF) {
                    Cb[(size_t)gr * ldc + gc] = f2b(v);
                } else {
                    if (res) v += res[(size_t)gr * ldc + gc];
                    Cf[(size_t)gr * ldc + gc] = v;
                }
            }
        }
    }
}

// ---------------------------------------------------------------------------
// merged repack: qkvg bf16 [s*B, 3072] -> qT,kT bf16 [b,h,s,d]; v -> vT [b,h,d,s]
// ---------------------------------------------------------------------------
__global__ __launch_bounds__(256) void k_repack(const unsigned short* __restrict__ qkvg,
                                                unsigned short* __restrict__ qT,
                                                unsigned short* __restrict__ kT,
                                                unsigned short* __restrict__ vT) {
    __shared__ unsigned short tile[64][72];
    int bh = blockIdx.y;
    int b = bh / NHH, h = bh % NHH;
    int s0 = blockIdx.x * 64;
    int t = threadIdx.x;
#pragma unroll
    for (int j = 0; j < 2; ++j) {
        int idx = t + j * 256;
        int r = idx >> 3, dc = idx & 7;
        const unsigned short* src = qkvg + ((size_t)(s0 + r) * BB + b) * 3072 + h * DD + dc * 8;
        ushort4 a = *(const ushort4*)src;
        ushort4 c = *(const ushort4*)(src + 4);
        unsigned short* dq = qT + ((size_t)bh * SS + s0 + r) * DD + dc * 8;
        *(ushort4*)dq = a; *(ushort4*)(dq + 4) = c;
        const unsigned short* srck = src + HH;
        ushort4 a2 = *(const ushort4*)srck;
        ushort4 c2 = *(const ushort4*)(srck + 4);
        unsigned short* dk = kT + ((size_t)bh * SS + s0 + r) * DD + dc * 8;
        *(ushort4*)dk = a2; *(ushort4*)(dk + 4) = c2;
    }
#pragma unroll
    for (int j = 0; j < 4; ++j) {
        int idx = t + j * 256;
        int r = idx >> 4, c4 = idx & 15;
        ushort4 u = *(const ushort4*)(qkvg + ((size_t)(s0 + r) * BB + b) * 3072 + 1536 + h * DD + c4 * 4);
        *(ushort4*)&tile[r][c4 * 4] = u;
    }
    __syncthreads();
#pragma unroll
    for (int j = 0; j < 2; ++j) {
        int idx = t + j * 256;
        int d = idx >> 3, s8 = idx & 7;
        ushort4 a, c;
        a.x = tile[s8 * 8 + 0][d]; a.y = tile[s8 * 8 + 1][d];
        a.z = tile[s8 * 8 + 2][d]; a.w = tile[s8 * 8 + 3][d];
        c.x = tile[s8 * 8 + 4][d]; c.y = tile[s8 * 8 + 5][d];
        c.z = tile[s8 * 8 + 6][d]; c.w = tile[s8 * 8 + 7][d];
        unsigned short* dst = vT + ((size_t)bh * DD + d) * SS + s0 + s8 * 8;
        *(ushort4*)dst = a; *(ushort4*)(dst + 4) = c;
    }
}

// ---------------------------------------------------------------------------
// MFMA cp/pc (unchanged from round 6)
// ---------------------------------------------------------------------------
__global__ __launch_bounds__(256) void k_cp_pc_mfma(const unsigned short* __restrict__ qkvg,
                                                    const unsigned short* __restrict__ pp,
                                                    float* __restrict__ cp,
                                                    float* __restrict__ pc) {
    __shared__ unsigned short As[128 * 32];
    __shared__ unsigned short Bs[64 * 32];
    int mt = blockIdx.x, h = blockIdx.y, z = blockIdx.z;
    int aoff = z ? HH : 0;
    int toff = z ? 0 : HH;
    float* out = z ? pc : cp;
    const int t = threadIdx.x;
    const int lane = t & 63, wid = t >> 6;
    const int rA = lane & 15, kA = (lane >> 4) * 8;

    f32x4 acc[2][4] = {};

    for (int k0 = 0; k0 < 64; k0 += 32) {
#pragma unroll
        for (int j = 0; j < 2; ++j) {
            int c = t + j * 256;
            int r = c >> 2, ko = (c & 3) * 8;
            const unsigned short* srcA = qkvg + (size_t)(mt * 128 + r) * 3072 + aoff + h * DD + k0 + ko;
            unsigned short* dstA = As + (size_t)(j * 256 + wid * 64) * 8;
            __builtin_amdgcn_global_load_lds(
                (const __attribute__((address_space(1))) void*)srcA,
                (__attribute__((address_space(3))) void*)dstA, 16, 0, 0);
        }
        {
            int r = t >> 2, ko = (t & 3) * 8;
            const unsigned short* srcB = pp + (size_t)r * 1536 + toff + h * DD + k0 + ko;
            unsigned short* dstB = Bs + (size_t)(wid * 64) * 8;
            __builtin_amdgcn_global_load_lds(
                (const __attribute__((address_space(1))) void*)srcB,
                (__attribute__((address_space(3))) void*)dstB, 16, 0, 0);
        }
        __syncthreads();
        bf16x8 af[2], bfr[4];
#pragma unroll
        for (int m = 0; m < 2; ++m)
            af[m] = *(const bf16x8*)&As[(wid * 32 + m * 16 + rA) * 32 + kA];
#pragma unroll
        for (int n = 0; n < 4; ++n)
            bfr[n] = *(const bf16x8*)&Bs[(n * 16 + rA) * 32 + kA];
#pragma unroll
        for (int m = 0; m < 2; ++m)
#pragma unroll
            for (int n = 0; n < 4; ++n)
                acc[m][n] = __builtin_amdgcn_mfma_f32_16x16x32_bf16(af[m], bfr[n], acc[m][n], 0, 0, 0);
        __syncthreads();
    }

    const int cl = lane & 15, rg = (lane >> 4) * 4;
#pragma unroll
    for (int m = 0; m < 2; ++m)
#pragma unroll
        for (int n = 0; n < 4; ++n) {
            int gc = n * 16 + cl;
            if (gc < 63) {
#pragma unroll
                for (int i = 0; i < 4; ++i) {
                    int gr = mt * 128 + wid * 32 + m * 16 + rg + i;
                    int sIdx = gr >> 3, bIdx = gr & 7;
                    out[(((size_t)(bIdx * NHH + h)) * SS + sIdx) * 63 + gc] = acc[m][n][i];
                }
            }
        }
}

// ---------------------------------------------------------------------------
// fused disentangled flash attention, v2:
//   QBLK=64/block (4 waves x 16 q-rows) -> 768 blocks (2x occupancy)
//   cp rows staged once per block into LDS (coalesced); pc rows staged per
//   K-tile between barriers with QK^T MFMAs covering the latency; gathers
//   hit LDS instead of L2.
// ---------------------------------------------------------------------------
__global__ __launch_bounds__(256) void k_attn_fused(
    const unsigned short* __restrict__ qT, const unsigned short* __restrict__ kT,
    const unsigned short* __restrict__ vT, const float* __restrict__ cp,
    const float* __restrict__ pc, const int* __restrict__ bucket,
    const int* __restrict__ mask, float* __restrict__ ctxr) {
    __shared__ float cps[64 * 63];                 // 16128 B (block q-rows)
    __shared__ float pcs[64 * 63];                 // 16128 B (K-tile rows)
    __shared__ unsigned short pb_all[4][16 * 72];  // 9216 B
    __shared__ int btab[1023];                     // 4092 B
    int t = threadIdx.x;
    int lane = t & 63, wid = t >> 6;
    int bh = blockIdx.y;
    int b = bh / NHH, h = bh % NHH;
    int qb0 = blockIdx.x * 64;
    int q0 = qb0 + wid * 16;
    int rA = lane & 15, g = lane >> 4, kA = g * 8;
    unsigned short* pb = pb_all[wid];
    const unsigned short* qTb = qT + (size_t)bh * SS * DD;
    const unsigned short* kTb = kT + (size_t)bh * SS * DD;
    const unsigned short* vTb = vT + (size_t)bh * DD * SS;
    const float* cpb = cp + (size_t)bh * SS * 63 + (size_t)qb0 * 63;
    const float* pcb = pc + (size_t)bh * SS * 63;
    const int* mkb = mask + b * SS;

    for (int i = t; i < 1023; i += 256) btab[i] = bucket[i];
    for (int i = t; i < 1008; i += 256) ((float4*)cps)[i] = ((const float4*)cpb)[i];

    bf16x8 aq[2];
#pragma unroll
    for (int dc = 0; dc < 2; ++dc)
        aq[dc] = *(const bf16x8*)&qTb[(size_t)(q0 + rA) * DD + dc * 32 + kA];

    f32x4 o[4] = {};
    float mrow[4], lrow[4];
#pragma unroll
    for (int i = 0; i < 4; ++i) { mrow[i] = -INFINITY; lrow[i] = 0.f; }

    for (int kt = 0; kt < 8; ++kt) {
        int k0 = kt * 64;
        __syncthreads();  // all waves done reading pcs (prev iter) / covers cps+btab on kt=0
        {
            const float4* src = (const float4*)(pcb + (size_t)k0 * 63);
            for (int i = t; i < 1008; i += 256) ((float4*)pcs)[i] = src[i];
        }
        // ---- S = Q.K^T (independent of pcs; covers stage latency) ----
        f32x4 sa[4] = {};
#pragma unroll
        for (int n = 0; n < 4; ++n) {
            bf16x8 bk0 = *(const bf16x8*)&kTb[(size_t)(k0 + n * 16 + rA) * DD + kA];
            bf16x8 bk1 = *(const bf16x8*)&kTb[(size_t)(k0 + n * 16 + rA) * DD + 32 + kA];
            sa[n] = __builtin_amdgcn_mfma_f32_16x16x32_bf16(aq[0], bk0, sa[n], 0, 0, 0);
            sa[n] = __builtin_amdgcn_mfma_f32_16x16x32_bf16(aq[1], bk1, sa[n], 0, 0, 0);
        }
        int mk[4];
#pragma unroll
        for (int n = 0; n < 4; ++n) mk[n] = mkb[k0 + n * 16 + rA];
        __syncthreads();  // pcs visible

        // ---- bias + mask + online softmax (gathers in LDS) ----
        float pv[4][4];
#pragma unroll
        for (int i = 0; i < 4; ++i) {
            int qr = wid * 16 + g * 4 + i;          // row within block's 64
            int q = qb0 + qr;
            float sv[4];
            float tmax = -INFINITY;
#pragma unroll
            for (int n = 0; n < 4; ++n) {
                int kr = n * 16 + rA;               // row within K-tile's 64
                int id = btab[q - (k0 + kr) + 511];
                float v = (sa[n][i] + cps[qr * 63 + id] + pcs[kr * 63 + id]) * SCALE_F;
                v = mk[n] ? -1e9f : v;
                sv[n] = v;
                tmax = fmaxf(tmax, v);
            }
            tmax = fmaxf(tmax, __shfl_xor(tmax, 1, 16));
            tmax = fmaxf(tmax, __shfl_xor(tmax, 2, 16));
            tmax = fmaxf(tmax, __shfl_xor(tmax, 4, 16));
            tmax = fmaxf(tmax, __shfl_xor(tmax, 8, 16));
            float mold = mrow[i];
            float mnew = fmaxf(mold, tmax);
            float ls = 0.f;
#pragma unroll
            for (int n = 0; n < 4; ++n) {
                float p = __expf(sv[n] - mnew);
                pv[n][i] = p;
                ls += p;
            }
            ls += __shfl_xor(ls, 1, 16);
            ls += __shfl_xor(ls, 2, 16);
            ls += __shfl_xor(ls, 4, 16);
            ls += __shfl_xor(ls, 8, 16);
            if (mnew > mold) {
                float alpha = __expf(mold - mnew);
                lrow[i] = lrow[i] * alpha + ls;
                mrow[i] = mnew;
#pragma unroll
                for (int n = 0; n < 4; ++n) o[n][i] *= alpha;
            } else {
                lrow[i] += ls;
            }
        }
        // ---- P -> bf16 via wave-local LDS transpose ----
#pragma unroll
        for (int n = 0; n < 4; ++n)
#pragma unroll
            for (int i = 0; i < 4; ++i)
                pb[(g * 4 + i) * 72 + n * 16 + rA] = f2b(pv[n][i]);
        // ---- O += P.V ----
        bf16x8 ap[2];
#pragma unroll
        for (int kc = 0; kc < 2; ++kc)
            ap[kc] = *(const bf16x8*)&pb[rA * 72 + kc * 32 + kA];
#pragma unroll
        for (int n = 0; n < 4; ++n) {
            bf16x8 bv0 = *(const bf16x8*)&vTb[(size_t)(n * 16 + rA) * SS + k0 + kA];
            bf16x8 bv1 = *(const bf16x8*)&vTb[(size_t)(n * 16 + rA) * SS + k0 + 32 + kA];
            o[n] = __builtin_amdgcn_mfma_f32_16x16x32_bf16(ap[0], bv0, o[n], 0, 0, 0);
            o[n] = __builtin_amdgcn_mfma_f32_16x16x32_bf16(ap[1], bv1, o[n], 0, 0, 0);
        }
    }
    // ---- epilogue ----
#pragma unroll
    for (int i = 0; i < 4; ++i) {
        int q = q0 + g * 4 + i;
        float inv = 1.0f / lrow[i];
#pragma unroll
        for (int n = 0; n < 4; ++n)
            ctxr[((size_t)q * BB + b) * HH + h * DD + n * 16 + rA] = o[n][i] * inv;
    }
}

// ---------------------------------------------------------------------------
// host launcher
// ---------------------------------------------------------------------------
static inline void gemm_bf(const unsigned short* A, int lda, const unsigned short* W, int ldw,
                           void* C, int ldc, int M, int N, int K,
                           const float* bias, const float* bias2, const float* res,
                           int obf, hipStream_t st) {
    dim3 g(N / 128, M / 128);
    if (obf)
        k_gemm_bf16<1><<<g, 256, 0, st>>>(A, lda, W, ldw, C, ldc, M, N, K, bias, bias2, res, 0, 0, 0);
    else
        k_gemm_bf16<0><<<g, 256, 0, st>>>(A, lda, W, ldw, C, ldc, M, N, K, bias, bias2, res, 0, 0, 0);
}

static inline void gemm_big(const unsigned short* A, int lda,
                            const unsigned short* W, const unsigned short* Wb2, int ldw,
                            void* C, int ldc, int M, int N, int K,
                            const float* bias, const float* bias2, const float* res,
                            int obf, hipStream_t st) {
    dim3 g(N / 256, M / 128);
    if (obf)
        k_gemm_big<1><<<g, 512, 3 * GSLOT, st>>>(A, lda, W, Wb2, ldw, C, ldc, M, N, K, bias, bias2, res);
    else
        k_gemm_big<0><<<g, 512, 3 * GSLOT, st>>>(A, lda, W, Wb2, ldw, C, ldc, M, N, K, bias, bias2, res);
}

extern "C" void kernel_launch(void* const* d_in, const int* in_sizes, int n_in,
                              void* d_out, int out_size, void* d_ws, size_t ws_size,
                              hipStream_t stream) {
    static int attr_done = 0;
    if (!attr_done) {
        hipFuncSetAttribute((const void*)&k_gemm_big<1>,
                            hipFuncAttributeMaxDynamicSharedMemorySize, 3 * GSLOT);
        hipFuncSetAttribute((const void*)&k_gemm_big<0>,
                            hipFuncAttributeMaxDynamicSharedMemorySize, 3 * GSLOT);
        attr_done = 1;
    }

    const int* ids = (const int*)d_in[0];
    const unsigned char* maskraw = (const unsigned char*)d_in[1];
    const float* word_emb = (const float*)d_in[2];
    const float* rel_emb = (const float*)d_in[3];
    const float* rel_g = (const float*)d_in[4];
    const float* rel_b = (const float*)d_in[5];
    const float* Wqk = (const float*)d_in[6];
    const float* bqk = (const float*)d_in[7];
    const float* Wvg = (const float*)d_in[8];
    const float* bvg = (const float*)d_in[9];
    const float* Wout = (const float*)d_in[10];
    const float* bout = (const float*)d_in[11];
    const float* W1 = (const float*)d_in[12];
    const float* W2 = (const float*)d_in[13];

    const size_t N_X = (size_t)SS * BB * HH;
    const size_t N_CP = (size_t)SS * BB * NHH * 63;
    const size_t N_H2 = (size_t)SS * BB * II;
    const size_t N_WQK = (size_t)2 * HH * HH;
    const size_t N_WOUT = (size_t)HH * HH;
    const size_t N_W1 = (size_t)2 * II * HH;
    const size_t N_W2 = (size_t)HH * II;
    const size_t N_HD = (size_t)BB * NHH * SS * DD;
    const size_t N_QKVG = (size_t)SS * BB * 3072;
    const size_t N_FFH = (size_t)SS * BB * 4096;
    const size_t N_PP = (size_t)128 * 1536;

    float* ws = (float*)d_ws;
    float* x = ws;
    float* ctxr = x + N_X;
    float* cp = ctxr + N_X;
    float* pc = cp + N_CP;
    unsigned short* us = (unsigned short*)(pc + N_CP);
    unsigned short* qkvg = us;
    unsigned short* hs_bf = qkvg + N_QKVG;
    unsigned short* ctx_bf = hs_bf + N_X;
    unsigned short* h2_bf = ctx_bf + N_X;
    unsigned short* ffh = h2_bf + N_H2;
    unsigned short* wqk_all = ffh + N_FFH;
    unsigned short* wvg_bf = wqk_all + 12 * N_WQK;
    unsigned short* wout_bf = wvg_bf + N_WQK;
    unsigned short* w1_bf = wout_bf + N_WOUT;
    unsigned short* w2_bf = w1_bf + N_W1;
    unsigned short* ppall = w2_bf + N_W2;
    unsigned short* rel_bf = ppall + 12 * N_PP;
    unsigned short* qT = rel_bf + 128 * HH;
    unsigned short* kT = qT + N_HD;
    unsigned short* vT = kT + N_HD;
    int* bucket = (int*)(vT + N_HD);
    int* maski = bucket + 1024;

    size_t need_bytes = ((size_t)(maski + BB * SS) - (size_t)d_ws);
    if (ws_size < need_bytes) return;  // ~205 MB required

    // ---- setup ----
    k_decode_mask<<<1, 256, 0, stream>>>(maskraw, maski, BB * SS);
    k_bucket<<<4, 256, 0, stream>>>(bucket);
    k_embed_ln<<<SS * BB, 256, 0, stream>>>(ids, word_emb, x);
    k_rel_ln_bf<<<128, 256, 0, stream>>>(rel_emb, rel_g, rel_b, rel_bf);
    k_f2b<<<(int)((12 * N_WQK / 8 + 255) / 256), 256, 0, stream>>>(Wqk, wqk_all,
                                                                   (int)(12 * N_WQK / 8));
    {
        dim3 gpp(1536 / 128, 1, 12);
        k_gemm_bf16<1><<<gpp, 256, 0, stream>>>(rel_bf, HH, wqk_all, HH, ppall, 1536,
                                                128, 1536, HH, bqk, nullptr, nullptr,
                                                N_WQK, N_PP, 2 * HH);
    }

    for (int l = 0; l < LL; ++l) {
        const unsigned short* wqk_l = wqk_all + (size_t)l * N_WQK;
        const float* bqk_l = bqk + (size_t)l * 2 * HH;
        const float* Wvg_l = Wvg + (size_t)l * N_WQK;
        const float* bvg_l = bvg + (size_t)l * 2 * HH;
        const float* Wout_l = Wout + (size_t)l * N_WOUT;
        const float* bout_l = bout + (size_t)l * HH;
        const float* W1_l = W1 + (size_t)l * N_W1;
        const float* W2_l = W2 + (size_t)l * N_W2;

        k_f2b_rest<<<3169, 256, 0, stream>>>(Wvg_l, Wout_l, W1_l, W2_l, wvg_bf);

        // ---- attention ----
        k_ln_bf<<<SS * BB, 256, 0, stream>>>(x, hs_bf);
        gemm_big(hs_bf, HH, wqk_l, wvg_bf, HH, qkvg, 3072, SS * BB, 3072, HH,
                 bqk_l, bvg_l, nullptr, 1, stream);
        k_repack<<<dim3(SS / 64, BB * NHH), 256, 0, stream>>>(qkvg, qT, kT, vT);
        k_cp_pc_mfma<<<dim3(SS * BB / 128, NHH, 2), 256, 0, stream>>>(
            qkvg, ppall + (size_t)l * N_PP, cp, pc);
        k_attn_fused<<<dim3(SS / 64, BB * NHH), 256, 0, stream>>>(qT, kT, vT, cp, pc,
                                                                  bucket, maski, ctxr);
        k_gated_ln<<<SS * BB, 256, 0, stream>>>(ctxr, qkvg, ctx_bf);
        gemm_bf(ctx_bf, HH, wout_bf, HH, x, HH, SS * BB, HH, HH,
                bout_l, nullptr, x, 0, stream);

        // ---- GeGLU FFN ----
        k_ln_bf<<<SS * BB, 256, 0, stream>>>(x, hs_bf);
        gemm_big(hs_bf, HH, w1_bf, nullptr, HH, ffh, 4096, SS * BB, 4096, HH,
                 nullptr, nullptr, nullptr, 1, stream);
        k_ffn_ln<<<SS * BB, 256, 0, stream>>>(ffh, h2_bf);
        gemm_bf(h2_bf, II, w2_bf, II, x, HH, SS * BB, HH, II,
                nullptr, nullptr, x, 0, stream);
    }

    hipMemcpyAsync(d_out, x, N_X * sizeof(float), hipMemcpyDeviceToDevice, stream);
}

// Round 9
// 2758.682 us; speedup vs baseline: 5.4098x; 1.2360x over previous
//
#include <hip/hip_runtime.h>
#include <math.h>

#define SS 512
#define BB 8
#define NHH 12
#define DD 64
#define HH 768
#define II 2048
#define LL 12
#define SCALE_F 0.07216878364870323f  /* 1/sqrt(3*64) */

typedef __attribute__((ext_vector_type(8))) short bf16x8;
typedef __attribute__((ext_vector_type(4))) float f32x4;

// f32 -> bf16 (RNE, finite values)
__device__ __forceinline__ unsigned short f2b(float f) {
    union { float f; unsigned int u; } x; x.f = f;
    unsigned int r = x.u + 0x7fffu + ((x.u >> 16) & 1u);
    return (unsigned short)(r >> 16);
}
__device__ __forceinline__ float b2f(unsigned short u) {
    union { unsigned int u; float f; } x; x.u = ((unsigned int)u) << 16;
    return x.f;
}

// ---------------------------------------------------------------------------
// block reduction helpers (blockDim.x == 256)
// ---------------------------------------------------------------------------
__device__ __forceinline__ float2 blockReduceSum2(float a, float b) {
    __shared__ float2 sm[4];
    __shared__ float2 bc;
#pragma unroll
    for (int o = 32; o > 0; o >>= 1) {
        a += __shfl_down(a, o);
        b += __shfl_down(b, o);
    }
    int t = threadIdx.x;
    if ((t & 63) == 0) sm[t >> 6] = make_float2(a, b);
    __syncthreads();
    if (t == 0) {
        float xa = sm[0].x + sm[1].x + sm[2].x + sm[3].x;
        float xb = sm[0].y + sm[1].y + sm[2].y + sm[3].y;
        bc = make_float2(xa, xb);
    }
    __syncthreads();
    return bc;
}

__device__ __forceinline__ float gelu_erf(float v) {
    return 0.5f * v * (1.0f + erff(v * 0.70710678118654752f));
}
__device__ __forceinline__ float gelu_tanh(float v) {
    const float c = 0.7978845608028654f;
    return 0.5f * v * (1.0f + tanhf(c * (v + 0.044715f * v * v * v)));
}

// ---------------------------------------------------------------------------
// mask decode: handle bool-as-u8 or bool-as-int32 layouts
// ---------------------------------------------------------------------------
__global__ __launch_bounds__(256) void k_decode_mask(const unsigned char* __restrict__ raw,
                                                     int* __restrict__ mask, int n) {
    __shared__ int s_any;
    if (threadIdx.x == 0) s_any = 0;
    __syncthreads();
    int local = 0;
    for (int i = threadIdx.x; i < n; i += blockDim.x)
        if ((i & 3) && raw[i]) local = 1;
    if (local) atomicOr(&s_any, 1);
    __syncthreads();
    bool isU8 = (s_any != 0);
    const int* as_int = (const int*)raw;
    for (int i = threadIdx.x; i < n; i += blockDim.x)
        mask[i] = isU8 ? (raw[i] != 0) : (as_int[i] != 0);
}

// ---------------------------------------------------------------------------
// DeBERTa log-bucket table: rel in [-511,511] -> idx in [0,62]
// ---------------------------------------------------------------------------
__global__ __launch_bounds__(256) void k_bucket(int* __restrict__ tab) {
    int i = blockIdx.x * 256 + threadIdx.x;
    if (i >= 1023) return;
    int rel = i - 511;
    int a = rel < 0 ? -rel : rel;
    int abs_pos = (a < 16) ? 15 : (a < 511 ? a : 511);
    int bucket;
    if (abs_pos <= 16) {
        bucket = rel;
    } else {
        double lp = ceil(log((double)abs_pos / 16.0) / log(511.0 / 16.0) * 15.0);
        int l = (int)lp + 16;
        bucket = (rel > 0) ? l : -l;
    }
    int idx = bucket + 31;
    if (idx < 0) idx = 0;
    if (idx > 62) idx = 62;
    tab[i] = idx;
}

// ---------------------------------------------------------------------------
// generic f32 -> bf16 bulk conversion (8 elems/thread)
// ---------------------------------------------------------------------------
__global__ __launch_bounds__(256) void k_f2b(const float* __restrict__ in,
                                             unsigned short* __restrict__ out, int n8) {
    int i = blockIdx.x * 256 + threadIdx.x;
    if (i >= n8) return;
    float4 a = ((const float4*)in)[2 * (size_t)i];
    float4 b = ((const float4*)in)[2 * (size_t)i + 1];
    ushort4 lo, hi;
    lo.x = f2b(a.x); lo.y = f2b(a.y); lo.z = f2b(a.z); lo.w = f2b(a.w);
    hi.x = f2b(b.x); hi.y = f2b(b.y); hi.z = f2b(b.z); hi.w = f2b(b.w);
    ((ushort4*)out)[2 * (size_t)i] = lo;
    ((ushort4*)out)[2 * (size_t)i + 1] = hi;
}

// ---------------------------------------------------------------------------
// merged: per-layer weight conversion (blocks 0..3168) + LN of x (blocks 3169..7264)
// ---------------------------------------------------------------------------
__global__ __launch_bounds__(256) void k_f2b_ln(const float* __restrict__ wvg,
                                                const float* __restrict__ wout,
                                                const float* __restrict__ w1,
                                                const float* __restrict__ w2,
                                                unsigned short* __restrict__ wbf,
                                                const float* __restrict__ x,
                                                unsigned short* __restrict__ hs) {
    int bid = blockIdx.x;
    int t = threadIdx.x;
    if (bid < 3169) {
        int i = bid * 256 + t;
        if (i >= 811008) return;
        const float* src;
        int off;
        if (i < 221184) {
            if (i < 147456) { src = wvg;  off = i; }
            else            { src = wout; off = i - 147456; }
        } else if (i < 614400) { src = w1; off = i - 221184; }
        else                   { src = w2; off = i - 614400; }
        float4 a = ((const float4*)src)[2 * (size_t)off];
        float4 b = ((const float4*)src)[2 * (size_t)off + 1];
        ushort4 lo, hi;
        lo.x = f2b(a.x); lo.y = f2b(a.y); lo.z = f2b(a.z); lo.w = f2b(a.w);
        hi.x = f2b(b.x); hi.y = f2b(b.y); hi.z = f2b(b.z); hi.w = f2b(b.w);
        ((ushort4*)wbf)[2 * (size_t)i] = lo;
        ((ushort4*)wbf)[2 * (size_t)i + 1] = hi;
    } else {
        int row = bid - 3169;
        const float* r = x + (size_t)row * HH;
        float v0 = r[t], v1 = r[t + 256], v2 = r[t + 512];
        float s = v0 + v1 + v2;
        float ss = v0 * v0 + v1 * v1 + v2 * v2;
        float2 r2 = blockReduceSum2(s, ss);
        float mean = r2.x * (1.0f / HH);
        float var = r2.y * (1.0f / HH) - mean * mean;
        float rs = rsqrtf(var + 1e-7f);
        unsigned short* o = hs + (size_t)row * HH;
        o[t] = f2b((v0 - mean) * rs);
        o[t + 256] = f2b((v1 - mean) * rs);
        o[t + 512] = f2b((v2 - mean) * rs);
    }
}

// ---------------------------------------------------------------------------
// LayerNorm family; EPS = 1e-7, biased variance
// ---------------------------------------------------------------------------
__global__ __launch_bounds__(256) void k_ln_bf(const float* __restrict__ in,
                                               unsigned short* __restrict__ out) {
    int row = blockIdx.x, t = threadIdx.x;
    const float* r = in + (size_t)row * HH;
    float v0 = r[t], v1 = r[t + 256], v2 = r[t + 512];
    float s = v0 + v1 + v2;
    float ss = v0 * v0 + v1 * v1 + v2 * v2;
    float2 r2 = blockReduceSum2(s, ss);
    float mean = r2.x * (1.0f / HH);
    float var = r2.y * (1.0f / HH) - mean * mean;
    float rs = rsqrtf(var + 1e-7f);
    unsigned short* o = out + (size_t)row * HH;
    o[t] = f2b((v0 - mean) * rs);
    o[t + 256] = f2b((v1 - mean) * rs);
    o[t + 512] = f2b((v2 - mean) * rs);
}

__global__ __launch_bounds__(256) void k_embed_ln(const int* __restrict__ ids,
                                                  const float* __restrict__ emb,
                                                  float* __restrict__ out) {
    int row = blockIdx.x, t = threadIdx.x;
    const float* r = emb + (size_t)ids[row] * HH;
    float v0 = r[t], v1 = r[t + 256], v2 = r[t + 512];
    float s = v0 + v1 + v2;
    float ss = v0 * v0 + v1 * v1 + v2 * v2;
    float2 r2 = blockReduceSum2(s, ss);
    float mean = r2.x * (1.0f / HH);
    float var = r2.y * (1.0f / HH) - mean * mean;
    float rs = rsqrtf(var + 1e-7f);
    float* o = out + (size_t)row * HH;
    o[t] = (v0 - mean) * rs;
    o[t + 256] = (v1 - mean) * rs;
    o[t + 512] = (v2 - mean) * rs;
}

// rel LN -> bf16, padded to 128 rows (rows 63..127 zero)
__global__ __launch_bounds__(256) void k_rel_ln_bf(const float* __restrict__ rel_emb,
                                                   const float* __restrict__ g,
                                                   const float* __restrict__ b,
                                                   unsigned short* __restrict__ out) {
    int row = blockIdx.x, t = threadIdx.x;
    unsigned short* o = out + (size_t)row * HH;
    if (row >= 63) {
        o[t] = 0; o[t + 256] = 0; o[t + 512] = 0;
        return;
    }
    const float* r = rel_emb + (size_t)row * HH;
    float v0 = r[t], v1 = r[t + 256], v2 = r[t + 512];
    float s = v0 + v1 + v2;
    float ss = v0 * v0 + v1 * v1 + v2 * v2;
    float2 r2 = blockReduceSum2(s, ss);
    float mean = r2.x * (1.0f / HH);
    float var = r2.y * (1.0f / HH) - mean * mean;
    float rs = rsqrtf(var + 1e-7f);
    o[t] = f2b((v0 - mean) * rs * g[t] + b[t]);
    o[t + 256] = f2b((v1 - mean) * rs * g[t + 256] + b[t + 256]);
    o[t + 512] = f2b((v2 - mean) * rs * g[t + 512] + b[t + 512]);
}

// ctx_bf = bf16(LN(ctxr * gelu_exact(g))), g = qkvg[..., 2304:3072] (bf16)
__global__ __launch_bounds__(256) void k_gated_ln(const float* __restrict__ ctxr,
                                                  const unsigned short* __restrict__ qkvg,
                                                  unsigned short* __restrict__ out) {
    int row = blockIdx.x, t = threadIdx.x;
    const float* cr = ctxr + (size_t)row * HH;
    const unsigned short* gr = qkvg + (size_t)row * 3072 + 2304;
    float v[3];
    float s = 0.f, ss = 0.f;
#pragma unroll
    for (int e = 0; e < 3; ++e) {
        int i = t + e * 256;
        float x = cr[i] * gelu_erf(b2f(gr[i]));
        v[e] = x;
        s += x; ss += x * x;
    }
    float2 r2 = blockReduceSum2(s, ss);
    float mean = r2.x * (1.0f / HH);
    float var = r2.y * (1.0f / HH) - mean * mean;
    float rs = rsqrtf(var + 1e-7f);
    unsigned short* o = out + (size_t)row * HH;
#pragma unroll
    for (int e = 0; e < 3; ++e) o[t + e * 256] = f2b((v[e] - mean) * rs);
}

// h2_bf = bf16(LN(ffh[:, :I] * gelu_tanh(ffh[:, I:])))  (ffh bf16 [row][4096])
__global__ __launch_bounds__(256) void k_ffn_ln(const unsigned short* __restrict__ ffh,
                                                unsigned short* __restrict__ out) {
    int row = blockIdx.x, t = threadIdx.x;
    const unsigned short* ar = ffh + (size_t)row * 4096 + t * 8;
    const unsigned short* gr = ar + II;
    ushort4 a0 = *(const ushort4*)ar;
    ushort4 a1 = *(const ushort4*)(ar + 4);
    ushort4 g0 = *(const ushort4*)gr;
    ushort4 g1 = *(const ushort4*)(gr + 4);
    float av[8] = {b2f(a0.x), b2f(a0.y), b2f(a0.z), b2f(a0.w),
                   b2f(a1.x), b2f(a1.y), b2f(a1.z), b2f(a1.w)};
    float gv[8] = {b2f(g0.x), b2f(g0.y), b2f(g0.z), b2f(g0.w),
                   b2f(g1.x), b2f(g1.y), b2f(g1.z), b2f(g1.w)};
    float v[8];
    float s = 0.f, ss = 0.f;
#pragma unroll
    for (int e = 0; e < 8; ++e) {
        float x = av[e] * gelu_tanh(gv[e]);
        v[e] = x;
        s += x; ss += x * x;
    }
    float2 r2 = blockReduceSum2(s, ss);
    float mean = r2.x * (1.0f / II);
    float var = r2.y * (1.0f / II) - mean * mean;
    float rs = rsqrtf(var + 1e-7f);
    ushort4 o0, o1;
    o0.x = f2b((v[0] - mean) * rs); o0.y = f2b((v[1] - mean) * rs);
    o0.z = f2b((v[2] - mean) * rs); o0.w = f2b((v[3] - mean) * rs);
    o1.x = f2b((v[4] - mean) * rs); o1.y = f2b((v[5] - mean) * rs);
    o1.z = f2b((v[6] - mean) * rs); o1.w = f2b((v[7] - mean) * rs);
    unsigned short* o = out + (size_t)row * II + t * 8;
    *(ushort4*)o = o0;
    *(ushort4*)(o + 4) = o1;
}

// ---------------------------------------------------------------------------
// bf16 MFMA GEMM (m97 structure + bijective XCD swizzle + z-batch) —
// used only for the batched posproj at setup.
// ---------------------------------------------------------------------------
template <int OBF>
__global__ __launch_bounds__(256) void k_gemm_bf16(const unsigned short* __restrict__ A, int lda,
                                                   const unsigned short* __restrict__ W, int ldw,
                                                   void* __restrict__ Cv, int ldc,
                                                   int M, int N, int K,
                                                   const float* __restrict__ bias,
                                                   const float* __restrict__ bias2,
                                                   const float* __restrict__ res,
                                                   size_t wz, size_t cz, size_t bz) {
    __shared__ unsigned short As[128 * 32];
    __shared__ unsigned short Ws[128 * 32];
    int zz = blockIdx.z;
    W += (size_t)zz * wz;
    if (bias) bias += (size_t)zz * bz;
    int nwg = gridDim.x * gridDim.y;
    int orig = blockIdx.y * gridDim.x + blockIdx.x;
    int qq = nwg >> 3, rr = nwg & 7;
    int xcd = orig & 7, idx = orig >> 3;
    int wg = (xcd < rr ? xcd * (qq + 1) : rr * (qq + 1) + (xcd - rr) * qq) + idx;
    int bx = wg % gridDim.x, by = wg / gridDim.x;

    const int t = threadIdx.x;
    const int lane = t & 63, wid = t >> 6;
    const int row0 = by * 128, col0 = bx * 128;
    const int wr = (wid >> 1) * 64, wc = (wid & 1) * 64;
    const int rA = lane & 15, kA = (lane >> 4) * 8;

    f32x4 acc[4][4] = {};

    for (int k0 = 0; k0 < K; k0 += 32) {
#pragma unroll
        for (int j = 0; j < 2; ++j) {
            int c = t + j * 256;
            int r = c >> 2, ko = (c & 3) * 8;
            const unsigned short* srcA = A + (size_t)(row0 + r) * lda + k0 + ko;
            const unsigned short* srcB = W + (size_t)(col0 + r) * ldw + k0 + ko;
            unsigned short* dstA = As + (size_t)(j * 256 + wid * 64) * 8;
            unsigned short* dstB = Ws + (size_t)(j * 256 + wid * 64) * 8;
            __builtin_amdgcn_global_load_lds(
                (const __attribute__((address_space(1))) void*)srcA,
                (__attribute__((address_space(3))) void*)dstA, 16, 0, 0);
            __builtin_amdgcn_global_load_lds(
                (const __attribute__((address_space(1))) void*)srcB,
                (__attribute__((address_space(3))) void*)dstB, 16, 0, 0);
        }
        __syncthreads();
        bf16x8 af[4], bfr[4];
#pragma unroll
        for (int m = 0; m < 4; ++m)
            af[m] = *(const bf16x8*)&As[(wr + m * 16 + rA) * 32 + kA];
#pragma unroll
        for (int n = 0; n < 4; ++n)
            bfr[n] = *(const bf16x8*)&Ws[(wc + n * 16 + rA) * 32 + kA];
#pragma unroll
        for (int m = 0; m < 4; ++m)
#pragma unroll
            for (int n = 0; n < 4; ++n)
                acc[m][n] = __builtin_amdgcn_mfma_f32_16x16x32_bf16(af[m], bfr[n], acc[m][n], 0, 0, 0);
        __syncthreads();
    }

    float* Cf = (float*)Cv + (size_t)zz * cz;
    unsigned short* Cb = (unsigned short*)Cv + (size_t)zz * cz;
    const int cl = lane & 15, rg = (lane >> 4) * 4;
#pragma unroll
    for (int n = 0; n < 4; ++n) {
        int gc = col0 + wc + n * 16 + cl;
        float bv = 0.0f;
        if (bias) bv = (bias2 && gc >= 1536) ? bias2[gc - 1536] : bias[gc];
#pragma unroll
        for (int m = 0; m < 4; ++m) {
#pragma unroll
            for (int i = 0; i < 4; ++i) {
                int gr = row0 + wr + m * 16 + rg + i;
                float v = acc[m][n][i] + bv;
                if (OBF) {
                    Cb[(size_t)gr * ldc + gc] = f2b(v);
                } else {
                    if (res) v += res[(size_t)gr * ldc + gc];
                    Cf[(size_t)gr * ldc + gc] = v;
                }
            }
        }
    }
}

// ---------------------------------------------------------------------------
// Skinny bf16 MFMA GEMM for N=768 (Wout, W2): 64x64 tile, BK=64, 256 threads
// (4 waves 2x2 of 32x32), T2 XOR-swizzle both-sides, f32 out +bias +res.
// grid (N/64, M/64) = 768 blocks -> 3 blocks/CU (vs 192 at 128x128).
// ---------------------------------------------------------------------------
__device__ __forceinline__ void sk_stage(const unsigned short* __restrict__ Ab, int lda,
                                         const unsigned short* __restrict__ Wb, int ldw,
                                         unsigned char* slot, int t, int wid) {
    int rit = t >> 3;             // 0..31
    int kb = (t & 7) << 4;        // byte offset within 128B row
#pragma unroll
    for (int c = 0; c < 2; ++c) {
        int row = c * 32 + rit;
        int gkb = kb ^ ((row & 7) << 4);
        const unsigned short* src = Ab + (size_t)row * lda + (gkb >> 1);
        unsigned char* dst = slot + c * 4096 + wid * 1024;
        __builtin_amdgcn_global_load_lds(
            (const __attribute__((address_space(1))) void*)src,
            (__attribute__((address_space(3))) void*)dst, 16, 0, 0);
    }
#pragma unroll
    for (int c = 0; c < 2; ++c) {
        int row = c * 32 + rit;
        int gkb = kb ^ ((row & 7) << 4);
        const unsigned short* src = Wb + (size_t)row * ldw + (gkb >> 1);
        unsigned char* dst = slot + 8192 + c * 4096 + wid * 1024;
        __builtin_amdgcn_global_load_lds(
            (const __attribute__((address_space(1))) void*)src,
            (__attribute__((address_space(3))) void*)dst, 16, 0, 0);
    }
}

__global__ __launch_bounds__(256) void k_gemm_skinny(const unsigned short* __restrict__ A, int lda,
                                                     const unsigned short* __restrict__ W, int ldw,
                                                     float* __restrict__ C, int ldc,
                                                     int M, int N, int K,
                                                     const float* __restrict__ bias,
                                                     const float* __restrict__ res) {
    __shared__ unsigned char smem[16384];  // A 8KB @0, B 8KB @8192
    int nwg = gridDim.x * gridDim.y;
    int orig = blockIdx.y * gridDim.x + blockIdx.x;
    int qq = nwg >> 3, rr = nwg & 7;
    int xcd = orig & 7, idx = orig >> 3;
    int wg = (xcd < rr ? xcd * (qq + 1) : rr * (qq + 1) + (xcd - rr) * qq) + idx;
    int bx = wg % gridDim.x, by = wg / gridDim.x;

    const int t = threadIdx.x;
    const int lane = t & 63, wid = t >> 6;
    const int row0 = by * 64, col0 = bx * 64;
    const int wr = (wid >> 1) * 32, wc = (wid & 1) * 32;
    const int rA = lane & 15, g16 = lane >> 4;
    const unsigned short* Abase = A + (size_t)row0 * lda;
    const unsigned short* Wbase = W + (size_t)col0 * ldw;

    f32x4 acc[2][2] = {};

    for (int k0 = 0; k0 < K; k0 += 64) {
        sk_stage(Abase + k0, lda, Wbase + k0, ldw, smem, t, wid);
        __syncthreads();
        const unsigned char* Ab = smem;
        const unsigned char* Bb = smem + 8192;
        bf16x8 a[2][2], b[2][2];
#pragma unroll
        for (int m = 0; m < 2; ++m) {
            int row = wr + m * 16 + rA;
            int sw = (row & 7) << 4;
#pragma unroll
            for (int s = 0; s < 2; ++s)
                a[m][s] = *(const bf16x8*)(Ab + row * 128 + ((s * 64 + g16 * 16) ^ sw));
        }
#pragma unroll
        for (int n = 0; n < 2; ++n) {
            int row = wc + n * 16 + rA;
            int sw = (row & 7) << 4;
#pragma unroll
            for (int s = 0; s < 2; ++s)
                b[n][s] = *(const bf16x8*)(Bb + row * 128 + ((s * 64 + g16 * 16) ^ sw));
        }
#pragma unroll
        for (int m = 0; m < 2; ++m)
#pragma unroll
            for (int n = 0; n < 2; ++n) {
                acc[m][n] = __builtin_amdgcn_mfma_f32_16x16x32_bf16(a[m][0], b[n][0], acc[m][n], 0, 0, 0);
                acc[m][n] = __builtin_amdgcn_mfma_f32_16x16x32_bf16(a[m][1], b[n][1], acc[m][n], 0, 0, 0);
            }
        __syncthreads();
    }

    const int cl = lane & 15, rg = (lane >> 4) * 4;
#pragma unroll
    for (int n = 0; n < 2; ++n) {
        int gc = col0 + wc + n * 16 + cl;
        float bv = bias ? bias[gc] : 0.0f;
#pragma unroll
        for (int m = 0; m < 2; ++m) {
#pragma unroll
            for (int i = 0; i < 4; ++i) {
                int gr = row0 + wr + m * 16 + rg + i;
                float v = acc[m][n][i] + bv;
                if (res) v += res[(size_t)gr * ldc + gc];
                C[(size_t)gr * ldc + gc] = v;
            }
        }
    }
}

// ---------------------------------------------------------------------------
// Pipelined bf16 MFMA GEMM for the large GEMMs (qkvg, W1)
// ---------------------------------------------------------------------------
#define GSLOT 49152  /* 48 KB: A 16KB @0, B 32KB @16384 */

__device__ __forceinline__ void g_stage(const unsigned short* __restrict__ Abase, int lda,
                                        const unsigned short* __restrict__ Wbase, int ldw,
                                        unsigned char* slot, int t, int wid) {
    int rit = t >> 3;
    int kb = (t & 7) << 4;
#pragma unroll
    for (int c = 0; c < 2; ++c) {
        int row = c * 64 + rit;
        int gkb = kb ^ ((row & 7) << 4);
        const unsigned short* src = Abase + (size_t)row * lda + (gkb >> 1);
        unsigned char* dst = slot + c * 8192 + wid * 1024;
        __builtin_amdgcn_global_load_lds(
            (const __attribute__((address_space(1))) void*)src,
            (__attribute__((address_space(3))) void*)dst, 16, 0, 0);
    }
#pragma unroll
    for (int c = 0; c < 4; ++c) {
        int row = c * 64 + rit;
        int gkb = kb ^ ((row & 7) << 4);
        const unsigned short* src = Wbase + (size_t)row * ldw + (gkb >> 1);
        unsigned char* dst = slot + 16384 + c * 8192 + wid * 1024;
        __builtin_amdgcn_global_load_lds(
            (const __attribute__((address_space(1))) void*)src,
            (__attribute__((address_space(3))) void*)dst, 16, 0, 0);
    }
}

__device__ __forceinline__ void g_compute(const unsigned char* slot, int wm, int wn,
                                          int rA, int g16, f32x4 acc[4][4]) {
    const unsigned char* Ab = slot;
    const unsigned char* Bb = slot + 16384;
    bf16x8 a[4][2], b[4][2];
#pragma unroll
    for (int m = 0; m < 4; ++m) {
        int row = wm * 64 + m * 16 + rA;
        int sw = (row & 7) << 4;
#pragma unroll
        for (int s = 0; s < 2; ++s)
            a[m][s] = *(const bf16x8*)(Ab + row * 128 + ((s * 64 + g16 * 16) ^ sw));
    }
#pragma unroll
    for (int n = 0; n < 4; ++n) {
        int row = wn * 64 + n * 16 + rA;
        int sw = (row & 7) << 4;
#pragma unroll
        for (int s = 0; s < 2; ++s)
            b[n][s] = *(const bf16x8*)(Bb + row * 128 + ((s * 64 + g16 * 16) ^ sw));
    }
    __builtin_amdgcn_s_setprio(1);
#pragma unroll
    for (int m = 0; m < 4; ++m)
#pragma unroll
        for (int n = 0; n < 4; ++n) {
            acc[m][n] = __builtin_amdgcn_mfma_f32_16x16x32_bf16(a[m][0], b[n][0], acc[m][n], 0, 0, 0);
            acc[m][n] = __builtin_amdgcn_mfma_f32_16x16x32_bf16(a[m][1], b[n][1], acc[m][n], 0, 0, 0);
        }
    __builtin_amdgcn_s_setprio(0);
}

template <int OBF>
__global__ __launch_bounds__(512, 1) void k_gemm_big(const unsigned short* __restrict__ A, int lda,
                                                     const unsigned short* __restrict__ W,
                                                     const unsigned short* __restrict__ Wb2, int ldw,
                                                     void* __restrict__ Cv, int ldc,
                                                     int M, int N, int K,
                                                     const float* __restrict__ bias,
                                                     const float* __restrict__ bias2,
                                                     const float* __restrict__ res) {
    extern __shared__ unsigned char smem[];
    int nwg = gridDim.x * gridDim.y;
    int orig = blockIdx.y * gridDim.x + blockIdx.x;
    int qq = nwg >> 3, rr = nwg & 7;
    int xcd = orig & 7, idx = orig >> 3;
    int wg = (xcd < rr ? xcd * (qq + 1) : rr * (qq + 1) + (xcd - rr) * qq) + idx;
    int bx = wg % gridDim.x, by = wg / gridDim.x;

    const int t = threadIdx.x;
    const int lane = t & 63, wid = t >> 6;
    const int wm = wid >> 2, wn = wid & 3;
    const int rA = lane & 15, g16 = lane >> 4;
    const int row0 = by * 128, col0 = bx * 256;
    const unsigned short* Abase = A + (size_t)row0 * lda;
    const unsigned short* Wbase = (Wb2 && col0 >= 1536)
                                      ? Wb2 + (size_t)(col0 - 1536) * ldw
                                      : W + (size_t)col0 * ldw;

    const int nt = K >> 6;
    f32x4 acc[4][4] = {};

    g_stage(Abase, lda, Wbase, ldw, smem, t, wid);
    g_stage(Abase + 64, lda, Wbase + 64, ldw, smem + GSLOT, t, wid);

#define GBAR() asm volatile("s_barrier" ::: "memory")
#define GITER(T, STG, VMSTR)                                                        \
    do {                                                                            \
        GBAR();                                                                     \
        if (STG)                                                                    \
            g_stage(Abase + (size_t)(T + 2) * 64, lda, Wbase + (size_t)(T + 2) * 64,\
                    ldw, smem + (size_t)((T + 2) % 3) * GSLOT, t, wid);             \
        asm volatile(VMSTR ::: "memory");                                           \
        GBAR();                                                                     \
        g_compute(smem + (size_t)((T) % 3) * GSLOT, wm, wn, rA, g16, acc);          \
    } while (0)

    int tt = 0;
    for (; tt < nt - 2; ++tt) GITER(tt, true, "s_waitcnt vmcnt(12)");
    GITER(tt, false, "s_waitcnt vmcnt(6)");
    ++tt;
    GITER(tt, false, "s_waitcnt vmcnt(0)");
#undef GITER
#undef GBAR

    float* Cf = (float*)Cv;
    unsigned short* Cb = (unsigned short*)Cv;
    const int cl = lane & 15, rg = (lane >> 4) * 4;
#pragma unroll
    for (int n = 0; n < 4; ++n) {
        int gc = col0 + wn * 64 + n * 16 + cl;
        float bv = 0.0f;
        if (bias) bv = (bias2 && gc >= 1536) ? bias2[gc - 1536] : bias[gc];
#pragma unroll
        for (int m = 0; m < 4; ++m) {
#pragma unroll
            for (int i = 0; i < 4; ++i) {
                int gr = row0 + wm * 64 + m * 16 + rg + i;
                float v = acc[m][n][i] + bv;
                if (OBF) {
                    Cb[(size_t)gr * ldc + gc] = f2b(v);
                } else {
                    if (res) v += res[(size_t)gr * ldc + gc];
                    Cf[(size_t)gr * ldc + gc] = v;
                }
            }
        }
    }
}

// ---------------------------------------------------------------------------
// merged: repack (blockIdx.x<8) + cp/pc MFMA (blockIdx.x>=8); grid (16, 96)
// ---------------------------------------------------------------------------
__global__ __launch_bounds__(256) void k_repack_cppc(const unsigned short* __restrict__ qkvg,
                                                     const unsigned short* __restrict__ pp,
                                                     unsigned short* __restrict__ qT,
                                                     unsigned short* __restrict__ kT,
                                                     unsigned short* __restrict__ vT,
                                                     float* __restrict__ cp,
                                                     float* __restrict__ pc) {
    __shared__ unsigned char shmem[12288];
    int t = threadIdx.x;
    if (blockIdx.x < 8) {
        // ---- repack: qT,kT direct copy; v -> vT via LDS transpose ----
        unsigned short (*tile)[72] = (unsigned short(*)[72])shmem;
        int bh = blockIdx.y;
        int b = bh / NHH, h = bh % NHH;
        int s0 = blockIdx.x * 64;
#pragma unroll
        for (int j = 0; j < 2; ++j) {
            int idx = t + j * 256;
            int r = idx >> 3, dc = idx & 7;
            const unsigned short* src = qkvg + ((size_t)(s0 + r) * BB + b) * 3072 + h * DD + dc * 8;
            ushort4 a = *(const ushort4*)src;
            ushort4 c = *(const ushort4*)(src + 4);
            unsigned short* dq = qT + ((size_t)bh * SS + s0 + r) * DD + dc * 8;
            *(ushort4*)dq = a; *(ushort4*)(dq + 4) = c;
            const unsigned short* srck = src + HH;
            ushort4 a2 = *(const ushort4*)srck;
            ushort4 c2 = *(const ushort4*)(srck + 4);
            unsigned short* dk = kT + ((size_t)bh * SS + s0 + r) * DD + dc * 8;
            *(ushort4*)dk = a2; *(ushort4*)(dk + 4) = c2;
        }
#pragma unroll
        for (int j = 0; j < 4; ++j) {
            int idx = t + j * 256;
            int r = idx >> 4, c4 = idx & 15;
            ushort4 u = *(const ushort4*)(qkvg + ((size_t)(s0 + r) * BB + b) * 3072 + 1536 + h * DD + c4 * 4);
            *(ushort4*)&tile[r][c4 * 4] = u;
        }
        __syncthreads();
#pragma unroll
        for (int j = 0; j < 2; ++j) {
            int idx = t + j * 256;
            int d = idx >> 3, s8 = idx & 7;
            ushort4 a, c;
            a.x = tile[s8 * 8 + 0][d]; a.y = tile[s8 * 8 + 1][d];
            a.z = tile[s8 * 8 + 2][d]; a.w = tile[s8 * 8 + 3][d];
            c.x = tile[s8 * 8 + 4][d]; c.y = tile[s8 * 8 + 5][d];
            c.z = tile[s8 * 8 + 6][d]; c.w = tile[s8 * 8 + 7][d];
            unsigned short* dst = vT + ((size_t)bh * DD + d) * SS + s0 + s8 * 8;
            *(ushort4*)dst = a; *(ushort4*)(dst + 4) = c;
        }
    } else {
        // ---- cp/pc MFMA: cid in [0,768) -> (z, h, mt) ----
        int cid = (blockIdx.x - 8) * 96 + blockIdx.y;
        int z = cid >= 384;
        int rem = cid - (z ? 384 : 0);   // FIX (round 8 bug: cid & 383 kept bit 8)
        int h = rem >> 5;
        int mt = rem & 31;
        int aoff = z ? HH : 0;
        int toff = z ? 0 : HH;
        float* out = z ? pc : cp;
        unsigned short* As = (unsigned short*)shmem;           // 128*32
        unsigned short* Bs = (unsigned short*)(shmem + 8192);  // 64*32
        const int lane = t & 63, wid = t >> 6;
        const int rA = lane & 15, kA = (lane >> 4) * 8;

        f32x4 acc[2][4] = {};

        for (int k0 = 0; k0 < 64; k0 += 32) {
#pragma unroll
            for (int j = 0; j < 2; ++j) {
                int c = t + j * 256;
                int r = c >> 2, ko = (c & 3) * 8;
                const unsigned short* srcA = qkvg + (size_t)(mt * 128 + r) * 3072 + aoff + h * DD + k0 + ko;
                unsigned short* dstA = As + (size_t)(j * 256 + wid * 64) * 8;
                __builtin_amdgcn_global_load_lds(
                    (const __attribute__((address_space(1))) void*)srcA,
                    (__attribute__((address_space(3))) void*)dstA, 16, 0, 0);
            }
            {
                int r = t >> 2, ko = (t & 3) * 8;
                const unsigned short* srcB = pp + (size_t)r * 1536 + toff + h * DD + k0 + ko;
                unsigned short* dstB = Bs + (size_t)(wid * 64) * 8;
                __builtin_amdgcn_global_load_lds(
                    (const __attribute__((address_space(1))) void*)srcB,
                    (__attribute__((address_space(3))) void*)dstB, 16, 0, 0);
            }
            __syncthreads();
            bf16x8 af[2], bfr[4];
#pragma unroll
            for (int m = 0; m < 2; ++m)
                af[m] = *(const bf16x8*)&As[(wid * 32 + m * 16 + rA) * 32 + kA];
#pragma unroll
            for (int n = 0; n < 4; ++n)
                bfr[n] = *(const bf16x8*)&Bs[(n * 16 + rA) * 32 + kA];
#pragma unroll
            for (int m = 0; m < 2; ++m)
#pragma unroll
                for (int n = 0; n < 4; ++n)
                    acc[m][n] = __builtin_amdgcn_mfma_f32_16x16x32_bf16(af[m], bfr[n], acc[m][n], 0, 0, 0);
            __syncthreads();
        }

        const int cl = lane & 15, rg = (lane >> 4) * 4;
#pragma unroll
        for (int m = 0; m < 2; ++m)
#pragma unroll
            for (int n = 0; n < 4; ++n) {
                int gc = n * 16 + cl;
                if (gc < 63) {
#pragma unroll
                    for (int i = 0; i < 4; ++i) {
                        int gr = mt * 128 + wid * 32 + m * 16 + rg + i;
                        int sIdx = gr >> 3, bIdx = gr & 7;
                        out[(((size_t)(bIdx * NHH + h)) * SS + sIdx) * 63 + gc] = acc[m][n][i];
                    }
                }
            }
    }
}

// ---------------------------------------------------------------------------
// fused disentangled flash attention v2 (unchanged from round 7)
// ---------------------------------------------------------------------------
__global__ __launch_bounds__(256) void k_attn_fused(
    const unsigned short* __restrict__ qT, const unsigned short* __restrict__ kT,
    const unsigned short* __restrict__ vT, const float* __restrict__ cp,
    const float* __restrict__ pc, const int* __restrict__ bucket,
    const int* __restrict__ mask, float* __restrict__ ctxr) {
    __shared__ float cps[64 * 63];
    __shared__ float pcs[64 * 63];
    __shared__ unsigned short pb_all[4][16 * 72];
    __shared__ int btab[1023];
    int t = threadIdx.x;
    int lane = t & 63, wid = t >> 6;
    int bh = blockIdx.y;
    int b = bh / NHH, h = bh % NHH;
    int qb0 = blockIdx.x * 64;
    int q0 = qb0 + wid * 16;
    int rA = lane & 15, g = lane >> 4, kA = g * 8;
    unsigned short* pb = pb_all[wid];
    const unsigned short* qTb = qT + (size_t)bh * SS * DD;
    const unsigned short* kTb = kT + (size_t)bh * SS * DD;
    const unsigned short* vTb = vT + (size_t)bh * DD * SS;
    const float* cpb = cp + (size_t)bh * SS * 63 + (size_t)qb0 * 63;
    const float* pcb = pc + (size_t)bh * SS * 63;
    const int* mkb = mask + b * SS;

    for (int i = t; i < 1023; i += 256) btab[i] = bucket[i];
    for (int i = t; i < 1008; i += 256) ((float4*)cps)[i] = ((const float4*)cpb)[i];

    bf16x8 aq[2];
#pragma unroll
    for (int dc = 0; dc < 2; ++dc)
        aq[dc] = *(const bf16x8*)&qTb[(size_t)(q0 + rA) * DD + dc * 32 + kA];

    f32x4 o[4] = {};
    float mrow[4], lrow[4];
#pragma unroll
    for (int i = 0; i < 4; ++i) { mrow[i] = -INFINITY; lrow[i] = 0.f; }

    for (int kt = 0; kt < 8; ++kt) {
        int k0 = kt * 64;
        __syncthreads();
        {
            const float4* src = (const float4*)(pcb + (size_t)k0 * 63);
            for (int i = t; i < 1008; i += 256) ((float4*)pcs)[i] = src[i];
        }
        f32x4 sa[4] = {};
#pragma unroll
        for (int n = 0; n < 4; ++n) {
            bf16x8 bk0 = *(const bf16x8*)&kTb[(size_t)(k0 + n * 16 + rA) * DD + kA];
            bf16x8 bk1 = *(const bf16x8*)&kTb[(size_t)(k0 + n * 16 + rA) * DD + 32 + kA];
            sa[n] = __builtin_amdgcn_mfma_f32_16x16x32_bf16(aq[0], bk0, sa[n], 0, 0, 0);
            sa[n] = __builtin_amdgcn_mfma_f32_16x16x32_bf16(aq[1], bk1, sa[n], 0, 0, 0);
        }
        int mk[4];
#pragma unroll
        for (int n = 0; n < 4; ++n) mk[n] = mkb[k0 + n * 16 + rA];
        __syncthreads();

        float pv[4][4];
#pragma unroll
        for (int i = 0; i < 4; ++i) {
            int qr = wid * 16 + g * 4 + i;
            int q = qb0 + qr;
            float sv[4];
            float tmax = -INFINITY;
#pragma unroll
            for (int n = 0; n < 4; ++n) {
                int kr = n * 16 + rA;
                int id = btab[q - (k0 + kr) + 511];
                float v = (sa[n][i] + cps[qr * 63 + id] + pcs[kr * 63 + id]) * SCALE_F;
                v = mk[n] ? -1e9f : v;
                sv[n] = v;
                tmax = fmaxf(tmax, v);
            }
            tmax = fmaxf(tmax, __shfl_xor(tmax, 1, 16));
            tmax = fmaxf(tmax, __shfl_xor(tmax, 2, 16));
            tmax = fmaxf(tmax, __shfl_xor(tmax, 4, 16));
            tmax = fmaxf(tmax, __shfl_xor(tmax, 8, 16));
            float mold = mrow[i];
            float mnew = fmaxf(mold, tmax);
            float ls = 0.f;
#pragma unroll
            for (int n = 0; n < 4; ++n) {
                float p = __expf(sv[n] - mnew);
                pv[n][i] = p;
                ls += p;
            }
            ls += __shfl_xor(ls, 1, 16);
            ls += __shfl_xor(ls, 2, 16);
            ls += __shfl_xor(ls, 4, 16);
            ls += __shfl_xor(ls, 8, 16);
            if (mnew > mold) {
                float alpha = __expf(mold - mnew);
                lrow[i] = lrow[i] * alpha + ls;
                mrow[i] = mnew;
#pragma unroll
                for (int n = 0; n < 4; ++n) o[n][i] *= alpha;
            } else {
                lrow[i] += ls;
            }
        }
#pragma unroll
        for (int n = 0; n < 4; ++n)
#pragma unroll
            for (int i = 0; i < 4; ++i)
                pb[(g * 4 + i) * 72 + n * 16 + rA] = f2b(pv[n][i]);
        bf16x8 ap[2];
#pragma unroll
        for (int kc = 0; kc < 2; ++kc)
            ap[kc] = *(const bf16x8*)&pb[rA * 72 + kc * 32 + kA];
#pragma unroll
        for (int n = 0; n < 4; ++n) {
            bf16x8 bv0 = *(const bf16x8*)&vTb[(size_t)(n * 16 + rA) * SS + k0 + kA];
            bf16x8 bv1 = *(const bf16x8*)&vTb[(size_t)(n * 16 + rA) * SS + k0 + 32 + kA];
            o[n] = __builtin_amdgcn_mfma_f32_16x16x32_bf16(ap[0], bv0, o[n], 0, 0, 0);
            o[n] = __builtin_amdgcn_mfma_f32_16x16x32_bf16(ap[1], bv1, o[n], 0, 0, 0);
        }
    }
#pragma unroll
    for (int i = 0; i < 4; ++i) {
        int q = q0 + g * 4 + i;
        float inv = 1.0f / lrow[i];
#pragma unroll
        for (int n = 0; n < 4; ++n)
            ctxr[((size_t)q * BB + b) * HH + h * DD + n * 16 + rA] = o[n][i] * inv;
    }
}

// ---------------------------------------------------------------------------
// host launcher
// ---------------------------------------------------------------------------
static inline void gemm_big(const unsigned short* A, int lda,
                            const unsigned short* W, const unsigned short* Wb2, int ldw,
                            void* C, int ldc, int M, int N, int K,
                            const float* bias, const float* bias2, const float* res,
                            int obf, hipStream_t st) {
    dim3 g(N / 256, M / 128);
    if (obf)
        k_gemm_big<1><<<g, 512, 3 * GSLOT, st>>>(A, lda, W, Wb2, ldw, C, ldc, M, N, K, bias, bias2, res);
    else
        k_gemm_big<0><<<g, 512, 3 * GSLOT, st>>>(A, lda, W, Wb2, ldw, C, ldc, M, N, K, bias, bias2, res);
}

extern "C" void kernel_launch(void* const* d_in, const int* in_sizes, int n_in,
                              void* d_out, int out_size, void* d_ws, size_t ws_size,
                              hipStream_t stream) {
    static int attr_done = 0;
    if (!attr_done) {
        hipFuncSetAttribute((const void*)&k_gemm_big<1>,
                            hipFuncAttributeMaxDynamicSharedMemorySize, 3 * GSLOT);
        hipFuncSetAttribute((const void*)&k_gemm_big<0>,
                            hipFuncAttributeMaxDynamicSharedMemorySize, 3 * GSLOT);
        attr_done = 1;
    }

    const int* ids = (const int*)d_in[0];
    const unsigned char* maskraw = (const unsigned char*)d_in[1];
    const float* word_emb = (const float*)d_in[2];
    const float* rel_emb = (const float*)d_in[3];
    const float* rel_g = (const float*)d_in[4];
    const float* rel_b = (const float*)d_in[5];
    const float* Wqk = (const float*)d_in[6];
    const float* bqk = (const float*)d_in[7];
    const float* Wvg = (const float*)d_in[8];
    const float* bvg = (const float*)d_in[9];
    const float* Wout = (const float*)d_in[10];
    const float* bout = (const float*)d_in[11];
    const float* W1 = (const float*)d_in[12];
    const float* W2 = (const float*)d_in[13];

    const size_t N_X = (size_t)SS * BB * HH;
    const size_t N_CP = (size_t)SS * BB * NHH * 63;
    const size_t N_H2 = (size_t)SS * BB * II;
    const size_t N_WQK = (size_t)2 * HH * HH;
    const size_t N_WOUT = (size_t)HH * HH;
    const size_t N_W1 = (size_t)2 * II * HH;
    const size_t N_W2 = (size_t)HH * II;
    const size_t N_HD = (size_t)BB * NHH * SS * DD;
    const size_t N_QKVG = (size_t)SS * BB * 3072;
    const size_t N_FFH = (size_t)SS * BB * 4096;
    const size_t N_PP = (size_t)128 * 1536;

    float* ws = (float*)d_ws;
    float* x = ws;
    float* ctxr = x + N_X;
    float* cp = ctxr + N_X;
    float* pc = cp + N_CP;
    unsigned short* us = (unsigned short*)(pc + N_CP);
    unsigned short* qkvg = us;
    unsigned short* hs_bf = qkvg + N_QKVG;
    unsigned short* ctx_bf = hs_bf + N_X;
    unsigned short* h2_bf = ctx_bf + N_X;
    unsigned short* ffh = h2_bf + N_H2;
    unsigned short* wqk_all = ffh + N_FFH;
    unsigned short* wvg_bf = wqk_all + 12 * N_WQK;
    unsigned short* wout_bf = wvg_bf + N_WQK;
    unsigned short* w1_bf = wout_bf + N_WOUT;
    unsigned short* w2_bf = w1_bf + N_W1;
    unsigned short* ppall = w2_bf + N_W2;
    unsigned short* rel_bf = ppall + 12 * N_PP;
    unsigned short* qT = rel_bf + 128 * HH;
    unsigned short* kT = qT + N_HD;
    unsigned short* vT = kT + N_HD;
    int* bucket = (int*)(vT + N_HD);
    int* maski = bucket + 1024;

    size_t need_bytes = ((size_t)(maski + BB * SS) - (size_t)d_ws);
    if (ws_size < need_bytes) return;  // ~205 MB required

    // ---- setup ----
    k_decode_mask<<<1, 256, 0, stream>>>(maskraw, maski, BB * SS);
    k_bucket<<<4, 256, 0, stream>>>(bucket);
    k_embed_ln<<<SS * BB, 256, 0, stream>>>(ids, word_emb, x);
    k_rel_ln_bf<<<128, 256, 0, stream>>>(rel_emb, rel_g, rel_b, rel_bf);
    k_f2b<<<(int)((12 * N_WQK / 8 + 255) / 256), 256, 0, stream>>>(Wqk, wqk_all,
                                                                   (int)(12 * N_WQK / 8));
    {
        dim3 gpp(1536 / 128, 1, 12);
        k_gemm_bf16<1><<<gpp, 256, 0, stream>>>(rel_bf, HH, wqk_all, HH, ppall, 1536,
                                                128, 1536, HH, bqk, nullptr, nullptr,
                                                N_WQK, N_PP, 2 * HH);
    }

    for (int l = 0; l < LL; ++l) {
        const unsigned short* wqk_l = wqk_all + (size_t)l * N_WQK;
        const float* bqk_l = bqk + (size_t)l * 2 * HH;
        const float* Wvg_l = Wvg + (size_t)l * N_WQK;
        const float* bvg_l = bvg + (size_t)l * 2 * HH;
        const float* Wout_l = Wout + (size_t)l * N_WOUT;
        const float* bout_l = bout + (size_t)l * HH;
        const float* W1_l = W1 + (size_t)l * N_W1;
        const float* W2_l = W2 + (size_t)l * N_W2;

        // ---- attention ----
        k_f2b_ln<<<3169 + SS * BB, 256, 0, stream>>>(Wvg_l, Wout_l, W1_l, W2_l, wvg_bf,
                                                     x, hs_bf);
        gemm_big(hs_bf, HH, wqk_l, wvg_bf, HH, qkvg, 3072, SS * BB, 3072, HH,
                 bqk_l, bvg_l, nullptr, 1, stream);
        k_repack_cppc<<<dim3(16, 96), 256, 0, stream>>>(qkvg, ppall + (size_t)l * N_PP,
                                                        qT, kT, vT, cp, pc);
        k_attn_fused<<<dim3(SS / 64, BB * NHH), 256, 0, stream>>>(qT, kT, vT, cp, pc,
                                                                  bucket, maski, ctxr);
        k_gated_ln<<<SS * BB, 256, 0, stream>>>(ctxr, qkvg, ctx_bf);
        k_gemm_skinny<<<dim3(HH / 64, SS * BB / 64), 256, 0, stream>>>(
            ctx_bf, HH, wout_bf, HH, x, HH, SS * BB, HH, HH, bout_l, x);

        // ---- GeGLU FFN ----
        k_ln_bf<<<SS * BB, 256, 0, stream>>>(x, hs_bf);
        gemm_big(hs_bf, HH, w1_bf, nullptr, HH, ffh, 4096, SS * BB, 4096, HH,
                 nullptr, nullptr, nullptr, 1, stream);
        k_ffn_ln<<<SS * BB, 256, 0, stream>>>(ffh, h2_bf);
        k_gemm_skinny<<<dim3(HH / 64, SS * BB / 64), 256, 0, stream>>>(
            h2_bf, II, w2_bf, II, x, HH, SS * BB, HH, II, nullptr, x);
    }

    hipMemcpyAsync(d_out, x, N_X * sizeof(float), hipMemcpyDeviceToDevice, stream);
}

// Round 10
// 2713.261 us; speedup vs baseline: 5.5004x; 1.0167x over previous
//
#include <hip/hip_runtime.h>
#include <math.h>

#define SS 512
#define BB 8
#define NHH 12
#define DD 64
#define HH 768
#define II 2048
#define LL 12
#define SCALE_F 0.07216878364870323f  /* 1/sqrt(3*64) */

typedef __attribute__((ext_vector_type(8))) short bf16x8;
typedef __attribute__((ext_vector_type(4))) float f32x4;

// f32 -> bf16 (RNE, finite values)
__device__ __forceinline__ unsigned short f2b(float f) {
    union { float f; unsigned int u; } x; x.f = f;
    unsigned int r = x.u + 0x7fffu + ((x.u >> 16) & 1u);
    return (unsigned short)(r >> 16);
}
__device__ __forceinline__ float b2f(unsigned short u) {
    union { unsigned int u; float f; } x; x.u = ((unsigned int)u) << 16;
    return x.f;
}

// ---------------------------------------------------------------------------
// block reduction helpers (blockDim.x == 256)
// ---------------------------------------------------------------------------
__device__ __forceinline__ float2 blockReduceSum2(float a, float b) {
    __shared__ float2 sm[4];
    __shared__ float2 bc;
#pragma unroll
    for (int o = 32; o > 0; o >>= 1) {
        a += __shfl_down(a, o);
        b += __shfl_down(b, o);
    }
    int t = threadIdx.x;
    if ((t & 63) == 0) sm[t >> 6] = make_float2(a, b);
    __syncthreads();
    if (t == 0) {
        float xa = sm[0].x + sm[1].x + sm[2].x + sm[3].x;
        float xb = sm[0].y + sm[1].y + sm[2].y + sm[3].y;
        bc = make_float2(xa, xb);
    }
    __syncthreads();
    return bc;
}

__device__ __forceinline__ float gelu_erf(float v) {
    return 0.5f * v * (1.0f + erff(v * 0.70710678118654752f));
}
__device__ __forceinline__ float gelu_tanh(float v) {
    const float c = 0.7978845608028654f;
    return 0.5f * v * (1.0f + tanhf(c * (v + 0.044715f * v * v * v)));
}

// ---------------------------------------------------------------------------
// mask decode: handle bool-as-u8 or bool-as-int32 layouts
// ---------------------------------------------------------------------------
__global__ __launch_bounds__(256) void k_decode_mask(const unsigned char* __restrict__ raw,
                                                     int* __restrict__ mask, int n) {
    __shared__ int s_any;
    if (threadIdx.x == 0) s_any = 0;
    __syncthreads();
    int local = 0;
    for (int i = threadIdx.x; i < n; i += blockDim.x)
        if ((i & 3) && raw[i]) local = 1;
    if (local) atomicOr(&s_any, 1);
    __syncthreads();
    bool isU8 = (s_any != 0);
    const int* as_int = (const int*)raw;
    for (int i = threadIdx.x; i < n; i += blockDim.x)
        mask[i] = isU8 ? (raw[i] != 0) : (as_int[i] != 0);
}

// ---------------------------------------------------------------------------
// DeBERTa log-bucket table: rel in [-511,511] -> idx in [0,62]
// ---------------------------------------------------------------------------
__global__ __launch_bounds__(256) void k_bucket(int* __restrict__ tab) {
    int i = blockIdx.x * 256 + threadIdx.x;
    if (i >= 1023) return;
    int rel = i - 511;
    int a = rel < 0 ? -rel : rel;
    int abs_pos = (a < 16) ? 15 : (a < 511 ? a : 511);
    int bucket;
    if (abs_pos <= 16) {
        bucket = rel;
    } else {
        double lp = ceil(log((double)abs_pos / 16.0) / log(511.0 / 16.0) * 15.0);
        int l = (int)lp + 16;
        bucket = (rel > 0) ? l : -l;
    }
    int idx = bucket + 31;
    if (idx < 0) idx = 0;
    if (idx > 62) idx = 62;
    tab[i] = idx;
}

// ---------------------------------------------------------------------------
// generic f32 -> bf16 bulk conversion (8 elems/thread)
// ---------------------------------------------------------------------------
__global__ __launch_bounds__(256) void k_f2b(const float* __restrict__ in,
                                             unsigned short* __restrict__ out, int n8) {
    int i = blockIdx.x * 256 + threadIdx.x;
    if (i >= n8) return;
    float4 a = ((const float4*)in)[2 * (size_t)i];
    float4 b = ((const float4*)in)[2 * (size_t)i + 1];
    ushort4 lo, hi;
    lo.x = f2b(a.x); lo.y = f2b(a.y); lo.z = f2b(a.z); lo.w = f2b(a.w);
    hi.x = f2b(b.x); hi.y = f2b(b.y); hi.z = f2b(b.z); hi.w = f2b(b.w);
    ((ushort4*)out)[2 * (size_t)i] = lo;
    ((ushort4*)out)[2 * (size_t)i + 1] = hi;
}

// ---------------------------------------------------------------------------
// merged: per-layer weight conversion (blocks 0..3168) + LN of x (blocks 3169..7264)
// ---------------------------------------------------------------------------
__global__ __launch_bounds__(256) void k_f2b_ln(const float* __restrict__ wvg,
                                                const float* __restrict__ wout,
                                                const float* __restrict__ w1,
                                                const float* __restrict__ w2,
                                                unsigned short* __restrict__ wbf,
                                                const float* __restrict__ x,
                                                unsigned short* __restrict__ hs) {
    int bid = blockIdx.x;
    int t = threadIdx.x;
    if (bid < 3169) {
        int i = bid * 256 + t;
        if (i >= 811008) return;
        const float* src;
        int off;
        if (i < 221184) {
            if (i < 147456) { src = wvg;  off = i; }
            else            { src = wout; off = i - 147456; }
        } else if (i < 614400) { src = w1; off = i - 221184; }
        else                   { src = w2; off = i - 614400; }
        float4 a = ((const float4*)src)[2 * (size_t)off];
        float4 b = ((const float4*)src)[2 * (size_t)off + 1];
        ushort4 lo, hi;
        lo.x = f2b(a.x); lo.y = f2b(a.y); lo.z = f2b(a.z); lo.w = f2b(a.w);
        hi.x = f2b(b.x); hi.y = f2b(b.y); hi.z = f2b(b.z); hi.w = f2b(b.w);
        ((ushort4*)wbf)[2 * (size_t)i] = lo;
        ((ushort4*)wbf)[2 * (size_t)i + 1] = hi;
    } else {
        int row = bid - 3169;
        const float* r = x + (size_t)row * HH;
        float v0 = r[t], v1 = r[t + 256], v2 = r[t + 512];
        float s = v0 + v1 + v2;
        float ss = v0 * v0 + v1 * v1 + v2 * v2;
        float2 r2 = blockReduceSum2(s, ss);
        float mean = r2.x * (1.0f / HH);
        float var = r2.y * (1.0f / HH) - mean * mean;
        float rs = rsqrtf(var + 1e-7f);
        unsigned short* o = hs + (size_t)row * HH;
        o[t] = f2b((v0 - mean) * rs);
        o[t + 256] = f2b((v1 - mean) * rs);
        o[t + 512] = f2b((v2 - mean) * rs);
    }
}

// ---------------------------------------------------------------------------
// LayerNorm family; EPS = 1e-7, biased variance
// ---------------------------------------------------------------------------
__global__ __launch_bounds__(256) void k_ln_bf(const float* __restrict__ in,
                                               unsigned short* __restrict__ out) {
    int row = blockIdx.x, t = threadIdx.x;
    const float* r = in + (size_t)row * HH;
    float v0 = r[t], v1 = r[t + 256], v2 = r[t + 512];
    float s = v0 + v1 + v2;
    float ss = v0 * v0 + v1 * v1 + v2 * v2;
    float2 r2 = blockReduceSum2(s, ss);
    float mean = r2.x * (1.0f / HH);
    float var = r2.y * (1.0f / HH) - mean * mean;
    float rs = rsqrtf(var + 1e-7f);
    unsigned short* o = out + (size_t)row * HH;
    o[t] = f2b((v0 - mean) * rs);
    o[t + 256] = f2b((v1 - mean) * rs);
    o[t + 512] = f2b((v2 - mean) * rs);
}

__global__ __launch_bounds__(256) void k_embed_ln(const int* __restrict__ ids,
                                                  const float* __restrict__ emb,
                                                  float* __restrict__ out) {
    int row = blockIdx.x, t = threadIdx.x;
    const float* r = emb + (size_t)ids[row] * HH;
    float v0 = r[t], v1 = r[t + 256], v2 = r[t + 512];
    float s = v0 + v1 + v2;
    float ss = v0 * v0 + v1 * v1 + v2 * v2;
    float2 r2 = blockReduceSum2(s, ss);
    float mean = r2.x * (1.0f / HH);
    float var = r2.y * (1.0f / HH) - mean * mean;
    float rs = rsqrtf(var + 1e-7f);
    float* o = out + (size_t)row * HH;
    o[t] = (v0 - mean) * rs;
    o[t + 256] = (v1 - mean) * rs;
    o[t + 512] = (v2 - mean) * rs;
}

// rel LN -> bf16, padded to 128 rows (rows 63..127 zero)
__global__ __launch_bounds__(256) void k_rel_ln_bf(const float* __restrict__ rel_emb,
                                                   const float* __restrict__ g,
                                                   const float* __restrict__ b,
                                                   unsigned short* __restrict__ out) {
    int row = blockIdx.x, t = threadIdx.x;
    unsigned short* o = out + (size_t)row * HH;
    if (row >= 63) {
        o[t] = 0; o[t + 256] = 0; o[t + 512] = 0;
        return;
    }
    const float* r = rel_emb + (size_t)row * HH;
    float v0 = r[t], v1 = r[t + 256], v2 = r[t + 512];
    float s = v0 + v1 + v2;
    float ss = v0 * v0 + v1 * v1 + v2 * v2;
    float2 r2 = blockReduceSum2(s, ss);
    float mean = r2.x * (1.0f / HH);
    float var = r2.y * (1.0f / HH) - mean * mean;
    float rs = rsqrtf(var + 1e-7f);
    o[t] = f2b((v0 - mean) * rs * g[t] + b[t]);
    o[t + 256] = f2b((v1 - mean) * rs * g[t + 256] + b[t + 256]);
    o[t + 512] = f2b((v2 - mean) * rs * g[t + 512] + b[t + 512]);
}

// ctx_bf = bf16(LN(ctxr * gelu_exact(g))), g = qkvg[..., 2304:3072] (bf16)
__global__ __launch_bounds__(256) void k_gated_ln(const float* __restrict__ ctxr,
                                                  const unsigned short* __restrict__ qkvg,
                                                  unsigned short* __restrict__ out) {
    int row = blockIdx.x, t = threadIdx.x;
    const float* cr = ctxr + (size_t)row * HH;
    const unsigned short* gr = qkvg + (size_t)row * 3072 + 2304;
    float v[3];
    float s = 0.f, ss = 0.f;
#pragma unroll
    for (int e = 0; e < 3; ++e) {
        int i = t + e * 256;
        float x = cr[i] * gelu_erf(b2f(gr[i]));
        v[e] = x;
        s += x; ss += x * x;
    }
    float2 r2 = blockReduceSum2(s, ss);
    float mean = r2.x * (1.0f / HH);
    float var = r2.y * (1.0f / HH) - mean * mean;
    float rs = rsqrtf(var + 1e-7f);
    unsigned short* o = out + (size_t)row * HH;
#pragma unroll
    for (int e = 0; e < 3; ++e) o[t + e * 256] = f2b((v[e] - mean) * rs);
}

// h2_bf = bf16(LN(ffh[:, :I] * gelu_tanh(ffh[:, I:])))  (ffh bf16 [row][4096])
__global__ __launch_bounds__(256) void k_ffn_ln(const unsigned short* __restrict__ ffh,
                                                unsigned short* __restrict__ out) {
    int row = blockIdx.x, t = threadIdx.x;
    const unsigned short* ar = ffh + (size_t)row * 4096 + t * 8;
    const unsigned short* gr = ar + II;
    ushort4 a0 = *(const ushort4*)ar;
    ushort4 a1 = *(const ushort4*)(ar + 4);
    ushort4 g0 = *(const ushort4*)gr;
    ushort4 g1 = *(const ushort4*)(gr + 4);
    float av[8] = {b2f(a0.x), b2f(a0.y), b2f(a0.z), b2f(a0.w),
                   b2f(a1.x), b2f(a1.y), b2f(a1.z), b2f(a1.w)};
    float gv[8] = {b2f(g0.x), b2f(g0.y), b2f(g0.z), b2f(g0.w),
                   b2f(g1.x), b2f(g1.y), b2f(g1.z), b2f(g1.w)};
    float v[8];
    float s = 0.f, ss = 0.f;
#pragma unroll
    for (int e = 0; e < 8; ++e) {
        float x = av[e] * gelu_tanh(gv[e]);
        v[e] = x;
        s += x; ss += x * x;
    }
    float2 r2 = blockReduceSum2(s, ss);
    float mean = r2.x * (1.0f / II);
    float var = r2.y * (1.0f / II) - mean * mean;
    float rs = rsqrtf(var + 1e-7f);
    ushort4 o0, o1;
    o0.x = f2b((v[0] - mean) * rs); o0.y = f2b((v[1] - mean) * rs);
    o0.z = f2b((v[2] - mean) * rs); o0.w = f2b((v[3] - mean) * rs);
    o1.x = f2b((v[4] - mean) * rs); o1.y = f2b((v[5] - mean) * rs);
    o1.z = f2b((v[6] - mean) * rs); o1.w = f2b((v[7] - mean) * rs);
    unsigned short* o = out + (size_t)row * II + t * 8;
    *(ushort4*)o = o0;
    *(ushort4*)(o + 4) = o1;
}

// ---------------------------------------------------------------------------
// bf16 MFMA GEMM (m97 structure + bijective XCD swizzle + z-batch) —
// used only for the batched posproj at setup.
// ---------------------------------------------------------------------------
template <int OBF>
__global__ __launch_bounds__(256) void k_gemm_bf16(const unsigned short* __restrict__ A, int lda,
                                                   const unsigned short* __restrict__ W, int ldw,
                                                   void* __restrict__ Cv, int ldc,
                                                   int M, int N, int K,
                                                   const float* __restrict__ bias,
                                                   const float* __restrict__ bias2,
                                                   const float* __restrict__ res,
                                                   size_t wz, size_t cz, size_t bz) {
    __shared__ unsigned short As[128 * 32];
    __shared__ unsigned short Ws[128 * 32];
    int zz = blockIdx.z;
    W += (size_t)zz * wz;
    if (bias) bias += (size_t)zz * bz;
    int nwg = gridDim.x * gridDim.y;
    int orig = blockIdx.y * gridDim.x + blockIdx.x;
    int qq = nwg >> 3, rr = nwg & 7;
    int xcd = orig & 7, idx = orig >> 3;
    int wg = (xcd < rr ? xcd * (qq + 1) : rr * (qq + 1) + (xcd - rr) * qq) + idx;
    int bx = wg % gridDim.x, by = wg / gridDim.x;

    const int t = threadIdx.x;
    const int lane = t & 63, wid = t >> 6;
    const int row0 = by * 128, col0 = bx * 128;
    const int wr = (wid >> 1) * 64, wc = (wid & 1) * 64;
    const int rA = lane & 15, kA = (lane >> 4) * 8;

    f32x4 acc[4][4] = {};

    for (int k0 = 0; k0 < K; k0 += 32) {
#pragma unroll
        for (int j = 0; j < 2; ++j) {
            int c = t + j * 256;
            int r = c >> 2, ko = (c & 3) * 8;
            const unsigned short* srcA = A + (size_t)(row0 + r) * lda + k0 + ko;
            const unsigned short* srcB = W + (size_t)(col0 + r) * ldw + k0 + ko;
            unsigned short* dstA = As + (size_t)(j * 256 + wid * 64) * 8;
            unsigned short* dstB = Ws + (size_t)(j * 256 + wid * 64) * 8;
            __builtin_amdgcn_global_load_lds(
                (const __attribute__((address_space(1))) void*)srcA,
                (__attribute__((address_space(3))) void*)dstA, 16, 0, 0);
            __builtin_amdgcn_global_load_lds(
                (const __attribute__((address_space(1))) void*)srcB,
                (__attribute__((address_space(3))) void*)dstB, 16, 0, 0);
        }
        __syncthreads();
        bf16x8 af[4], bfr[4];
#pragma unroll
        for (int m = 0; m < 4; ++m)
            af[m] = *(const bf16x8*)&As[(wr + m * 16 + rA) * 32 + kA];
#pragma unroll
        for (int n = 0; n < 4; ++n)
            bfr[n] = *(const bf16x8*)&Ws[(wc + n * 16 + rA) * 32 + kA];
#pragma unroll
        for (int m = 0; m < 4; ++m)
#pragma unroll
            for (int n = 0; n < 4; ++n)
                acc[m][n] = __builtin_amdgcn_mfma_f32_16x16x32_bf16(af[m], bfr[n], acc[m][n], 0, 0, 0);
        __syncthreads();
    }

    float* Cf = (float*)Cv + (size_t)zz * cz;
    unsigned short* Cb = (unsigned short*)Cv + (size_t)zz * cz;
    const int cl = lane & 15, rg = (lane >> 4) * 4;
#pragma unroll
    for (int n = 0; n < 4; ++n) {
        int gc = col0 + wc + n * 16 + cl;
        float bv = 0.0f;
        if (bias) bv = (bias2 && gc >= 1536) ? bias2[gc - 1536] : bias[gc];
#pragma unroll
        for (int m = 0; m < 4; ++m) {
#pragma unroll
            for (int i = 0; i < 4; ++i) {
                int gr = row0 + wr + m * 16 + rg + i;
                float v = acc[m][n][i] + bv;
                if (OBF) {
                    Cb[(size_t)gr * ldc + gc] = f2b(v);
                } else {
                    if (res) v += res[(size_t)gr * ldc + gc];
                    Cf[(size_t)gr * ldc + gc] = v;
                }
            }
        }
    }
}

// ---------------------------------------------------------------------------
// Skinny bf16 MFMA GEMM for N=768 (Wout, W2), now 2-slot PIPELINED:
// 64x64 tile, BK=64, 256 threads (4 waves 2x2 of 32x32), T2 XOR-swizzle
// both-sides, counted vmcnt(4) (never 0 in main loop), raw s_barrier pairs.
// grid (N/64, M/64) = 768 blocks -> 3 blocks/CU. Requires K%64==0, K/64>=2.
// ---------------------------------------------------------------------------
#define SKSLOT 16384  /* 16 KB per slot: A 8KB @0, B 8KB @8192 */

__device__ __forceinline__ void sk_stage(const unsigned short* __restrict__ Ab, int lda,
                                         const unsigned short* __restrict__ Wb, int ldw,
                                         unsigned char* slot, int t, int wid) {
    int rit = t >> 3;             // 0..31
    int kb = (t & 7) << 4;        // byte offset within 128B row
#pragma unroll
    for (int c = 0; c < 2; ++c) {
        int row = c * 32 + rit;
        int gkb = kb ^ ((row & 7) << 4);
        const unsigned short* src = Ab + (size_t)row * lda + (gkb >> 1);
        unsigned char* dst = slot + c * 4096 + wid * 1024;
        __builtin_amdgcn_global_load_lds(
            (const __attribute__((address_space(1))) void*)src,
            (__attribute__((address_space(3))) void*)dst, 16, 0, 0);
    }
#pragma unroll
    for (int c = 0; c < 2; ++c) {
        int row = c * 32 + rit;
        int gkb = kb ^ ((row & 7) << 4);
        const unsigned short* src = Wb + (size_t)row * ldw + (gkb >> 1);
        unsigned char* dst = slot + 8192 + c * 4096 + wid * 1024;
        __builtin_amdgcn_global_load_lds(
            (const __attribute__((address_space(1))) void*)src,
            (__attribute__((address_space(3))) void*)dst, 16, 0, 0);
    }
}

__device__ __forceinline__ void sk_compute(const unsigned char* slot, int wr, int wc,
                                           int rA, int g16, f32x4 acc[2][2]) {
    const unsigned char* Ab = slot;
    const unsigned char* Bb = slot + 8192;
    bf16x8 a[2][2], b[2][2];
#pragma unroll
    for (int m = 0; m < 2; ++m) {
        int row = wr + m * 16 + rA;
        int sw = (row & 7) << 4;
#pragma unroll
        for (int s = 0; s < 2; ++s)
            a[m][s] = *(const bf16x8*)(Ab + row * 128 + ((s * 64 + g16 * 16) ^ sw));
    }
#pragma unroll
    for (int n = 0; n < 2; ++n) {
        int row = wc + n * 16 + rA;
        int sw = (row & 7) << 4;
#pragma unroll
        for (int s = 0; s < 2; ++s)
            b[n][s] = *(const bf16x8*)(Bb + row * 128 + ((s * 64 + g16 * 16) ^ sw));
    }
    __builtin_amdgcn_s_setprio(1);
#pragma unroll
    for (int m = 0; m < 2; ++m)
#pragma unroll
        for (int n = 0; n < 2; ++n) {
            acc[m][n] = __builtin_amdgcn_mfma_f32_16x16x32_bf16(a[m][0], b[n][0], acc[m][n], 0, 0, 0);
            acc[m][n] = __builtin_amdgcn_mfma_f32_16x16x32_bf16(a[m][1], b[n][1], acc[m][n], 0, 0, 0);
        }
    __builtin_amdgcn_s_setprio(0);
}

__global__ __launch_bounds__(256) void k_gemm_skinny(const unsigned short* __restrict__ A, int lda,
                                                     const unsigned short* __restrict__ W, int ldw,
                                                     float* __restrict__ C, int ldc,
                                                     int M, int N, int K,
                                                     const float* __restrict__ bias,
                                                     const float* __restrict__ res) {
    __shared__ unsigned char smem[2 * SKSLOT];
    int nwg = gridDim.x * gridDim.y;
    int orig = blockIdx.y * gridDim.x + blockIdx.x;
    int qq = nwg >> 3, rr = nwg & 7;
    int xcd = orig & 7, idx = orig >> 3;
    int wg = (xcd < rr ? xcd * (qq + 1) : rr * (qq + 1) + (xcd - rr) * qq) + idx;
    int bx = wg % gridDim.x, by = wg / gridDim.x;

    const int t = threadIdx.x;
    const int lane = t & 63, wid = t >> 6;
    const int row0 = by * 64, col0 = bx * 64;
    const int wr = (wid >> 1) * 32, wc = (wid & 1) * 32;
    const int rA = lane & 15, g16 = lane >> 4;
    const unsigned short* Abase = A + (size_t)row0 * lda;
    const unsigned short* Wbase = W + (size_t)col0 * ldw;

    const int nt = K >> 6;
    f32x4 acc[2][2] = {};

    // prologue: stage tile 0 into slot 0 (4 loads per thread)
    sk_stage(Abase, lda, Wbase, ldw, smem, t, wid);

    for (int tt = 0; tt < nt; ++tt) {
        // all waves done reading slot (tt+1)&1 (iter tt-1's compute)
        asm volatile("s_barrier" ::: "memory");
        if (tt + 1 < nt) {
            sk_stage(Abase + (size_t)(tt + 1) * 64, lda, Wbase + (size_t)(tt + 1) * 64,
                     ldw, smem + (size_t)((tt + 1) & 1) * SKSLOT, t, wid);
            asm volatile("s_waitcnt vmcnt(4)" ::: "memory");  // tile tt landed (per-wave)
        } else {
            asm volatile("s_waitcnt vmcnt(0)" ::: "memory");
        }
        asm volatile("s_barrier" ::: "memory");               // tile tt visible to all waves
        sk_compute(smem + (size_t)(tt & 1) * SKSLOT, wr, wc, rA, g16, acc);
    }

    const int cl = lane & 15, rg = (lane >> 4) * 4;
#pragma unroll
    for (int n = 0; n < 2; ++n) {
        int gc = col0 + wc + n * 16 + cl;
        float bv = bias ? bias[gc] : 0.0f;
#pragma unroll
        for (int m = 0; m < 2; ++m) {
#pragma unroll
            for (int i = 0; i < 4; ++i) {
                int gr = row0 + wr + m * 16 + rg + i;
                float v = acc[m][n][i] + bv;
                if (res) v += res[(size_t)gr * ldc + gc];
                C[(size_t)gr * ldc + gc] = v;
            }
        }
    }
}

// ---------------------------------------------------------------------------
// Pipelined bf16 MFMA GEMM for the large GEMMs (qkvg, W1)
// ---------------------------------------------------------------------------
#define GSLOT 49152  /* 48 KB: A 16KB @0, B 32KB @16384 */

__device__ __forceinline__ void g_stage(const unsigned short* __restrict__ Abase, int lda,
                                        const unsigned short* __restrict__ Wbase, int ldw,
                                        unsigned char* slot, int t, int wid) {
    int rit = t >> 3;
    int kb = (t & 7) << 4;
#pragma unroll
    for (int c = 0; c < 2; ++c) {
        int row = c * 64 + rit;
        int gkb = kb ^ ((row & 7) << 4);
        const unsigned short* src = Abase + (size_t)row * lda + (gkb >> 1);
        unsigned char* dst = slot + c * 8192 + wid * 1024;
        __builtin_amdgcn_global_load_lds(
            (const __attribute__((address_space(1))) void*)src,
            (__attribute__((address_space(3))) void*)dst, 16, 0, 0);
    }
#pragma unroll
    for (int c = 0; c < 4; ++c) {
        int row = c * 64 + rit;
        int gkb = kb ^ ((row & 7) << 4);
        const unsigned short* src = Wbase + (size_t)row * ldw + (gkb >> 1);
        unsigned char* dst = slot + 16384 + c * 8192 + wid * 1024;
        __builtin_amdgcn_global_load_lds(
            (const __attribute__((address_space(1))) void*)src,
            (__attribute__((address_space(3))) void*)dst, 16, 0, 0);
    }
}

__device__ __forceinline__ void g_compute(const unsigned char* slot, int wm, int wn,
                                          int rA, int g16, f32x4 acc[4][4]) {
    const unsigned char* Ab = slot;
    const unsigned char* Bb = slot + 16384;
    bf16x8 a[4][2], b[4][2];
#pragma unroll
    for (int m = 0; m < 4; ++m) {
        int row = wm * 64 + m * 16 + rA;
        int sw = (row & 7) << 4;
#pragma unroll
        for (int s = 0; s < 2; ++s)
            a[m][s] = *(const bf16x8*)(Ab + row * 128 + ((s * 64 + g16 * 16) ^ sw));
    }
#pragma unroll
    for (int n = 0; n < 4; ++n) {
        int row = wn * 64 + n * 16 + rA;
        int sw = (row & 7) << 4;
#pragma unroll
        for (int s = 0; s < 2; ++s)
            b[n][s] = *(const bf16x8*)(Bb + row * 128 + ((s * 64 + g16 * 16) ^ sw));
    }
    __builtin_amdgcn_s_setprio(1);
#pragma unroll
    for (int m = 0; m < 4; ++m)
#pragma unroll
        for (int n = 0; n < 4; ++n) {
            acc[m][n] = __builtin_amdgcn_mfma_f32_16x16x32_bf16(a[m][0], b[n][0], acc[m][n], 0, 0, 0);
            acc[m][n] = __builtin_amdgcn_mfma_f32_16x16x32_bf16(a[m][1], b[n][1], acc[m][n], 0, 0, 0);
        }
    __builtin_amdgcn_s_setprio(0);
}

template <int OBF>
__global__ __launch_bounds__(512, 1) void k_gemm_big(const unsigned short* __restrict__ A, int lda,
                                                     const unsigned short* __restrict__ W,
                                                     const unsigned short* __restrict__ Wb2, int ldw,
                                                     void* __restrict__ Cv, int ldc,
                                                     int M, int N, int K,
                                                     const float* __restrict__ bias,
                                                     const float* __restrict__ bias2,
                                                     const float* __restrict__ res) {
    extern __shared__ unsigned char smem[];
    int nwg = gridDim.x * gridDim.y;
    int orig = blockIdx.y * gridDim.x + blockIdx.x;
    int qq = nwg >> 3, rr = nwg & 7;
    int xcd = orig & 7, idx = orig >> 3;
    int wg = (xcd < rr ? xcd * (qq + 1) : rr * (qq + 1) + (xcd - rr) * qq) + idx;
    int bx = wg % gridDim.x, by = wg / gridDim.x;

    const int t = threadIdx.x;
    const int lane = t & 63, wid = t >> 6;
    const int wm = wid >> 2, wn = wid & 3;
    const int rA = lane & 15, g16 = lane >> 4;
    const int row0 = by * 128, col0 = bx * 256;
    const unsigned short* Abase = A + (size_t)row0 * lda;
    const unsigned short* Wbase = (Wb2 && col0 >= 1536)
                                      ? Wb2 + (size_t)(col0 - 1536) * ldw
                                      : W + (size_t)col0 * ldw;

    const int nt = K >> 6;
    f32x4 acc[4][4] = {};

    g_stage(Abase, lda, Wbase, ldw, smem, t, wid);
    g_stage(Abase + 64, lda, Wbase + 64, ldw, smem + GSLOT, t, wid);

#define GBAR() asm volatile("s_barrier" ::: "memory")
#define GITER(T, STG, VMSTR)                                                        \
    do {                                                                            \
        GBAR();                                                                     \
        if (STG)                                                                    \
            g_stage(Abase + (size_t)(T + 2) * 64, lda, Wbase + (size_t)(T + 2) * 64,\
                    ldw, smem + (size_t)((T + 2) % 3) * GSLOT, t, wid);             \
        asm volatile(VMSTR ::: "memory");                                           \
        GBAR();                                                                     \
        g_compute(smem + (size_t)((T) % 3) * GSLOT, wm, wn, rA, g16, acc);          \
    } while (0)

    int tt = 0;
    for (; tt < nt - 2; ++tt) GITER(tt, true, "s_waitcnt vmcnt(12)");
    GITER(tt, false, "s_waitcnt vmcnt(6)");
    ++tt;
    GITER(tt, false, "s_waitcnt vmcnt(0)");
#undef GITER
#undef GBAR

    float* Cf = (float*)Cv;
    unsigned short* Cb = (unsigned short*)Cv;
    const int cl = lane & 15, rg = (lane >> 4) * 4;
#pragma unroll
    for (int n = 0; n < 4; ++n) {
        int gc = col0 + wn * 64 + n * 16 + cl;
        float bv = 0.0f;
        if (bias) bv = (bias2 && gc >= 1536) ? bias2[gc - 1536] : bias[gc];
#pragma unroll
        for (int m = 0; m < 4; ++m) {
#pragma unroll
            for (int i = 0; i < 4; ++i) {
                int gr = row0 + wm * 64 + m * 16 + rg + i;
                float v = acc[m][n][i] + bv;
                if (OBF) {
                    Cb[(size_t)gr * ldc + gc] = f2b(v);
                } else {
                    if (res) v += res[(size_t)gr * ldc + gc];
                    Cf[(size_t)gr * ldc + gc] = v;
                }
            }
        }
    }
}

// ---------------------------------------------------------------------------
// merged: repack (blockIdx.x<8) + cp/pc MFMA (blockIdx.x>=8); grid (16, 96)
// ---------------------------------------------------------------------------
__global__ __launch_bounds__(256) void k_repack_cppc(const unsigned short* __restrict__ qkvg,
                                                     const unsigned short* __restrict__ pp,
                                                     unsigned short* __restrict__ qT,
                                                     unsigned short* __restrict__ kT,
                                                     unsigned short* __restrict__ vT,
                                                     float* __restrict__ cp,
                                                     float* __restrict__ pc) {
    __shared__ unsigned char shmem[12288];
    int t = threadIdx.x;
    if (blockIdx.x < 8) {
        unsigned short (*tile)[72] = (unsigned short(*)[72])shmem;
        int bh = blockIdx.y;
        int b = bh / NHH, h = bh % NHH;
        int s0 = blockIdx.x * 64;
#pragma unroll
        for (int j = 0; j < 2; ++j) {
            int idx = t + j * 256;
            int r = idx >> 3, dc = idx & 7;
            const unsigned short* src = qkvg + ((size_t)(s0 + r) * BB + b) * 3072 + h * DD + dc * 8;
            ushort4 a = *(const ushort4*)src;
            ushort4 c = *(const ushort4*)(src + 4);
            unsigned short* dq = qT + ((size_t)bh * SS + s0 + r) * DD + dc * 8;
            *(ushort4*)dq = a; *(ushort4*)(dq + 4) = c;
            const unsigned short* srck = src + HH;
            ushort4 a2 = *(const ushort4*)srck;
            ushort4 c2 = *(const ushort4*)(srck + 4);
            unsigned short* dk = kT + ((size_t)bh * SS + s0 + r) * DD + dc * 8;
            *(ushort4*)dk = a2; *(ushort4*)(dk + 4) = c2;
        }
#pragma unroll
        for (int j = 0; j < 4; ++j) {
            int idx = t + j * 256;
            int r = idx >> 4, c4 = idx & 15;
            ushort4 u = *(const ushort4*)(qkvg + ((size_t)(s0 + r) * BB + b) * 3072 + 1536 + h * DD + c4 * 4);
            *(ushort4*)&tile[r][c4 * 4] = u;
        }
        __syncthreads();
#pragma unroll
        for (int j = 0; j < 2; ++j) {
            int idx = t + j * 256;
            int d = idx >> 3, s8 = idx & 7;
            ushort4 a, c;
            a.x = tile[s8 * 8 + 0][d]; a.y = tile[s8 * 8 + 1][d];
            a.z = tile[s8 * 8 + 2][d]; a.w = tile[s8 * 8 + 3][d];
            c.x = tile[s8 * 8 + 4][d]; c.y = tile[s8 * 8 + 5][d];
            c.z = tile[s8 * 8 + 6][d]; c.w = tile[s8 * 8 + 7][d];
            unsigned short* dst = vT + ((size_t)bh * DD + d) * SS + s0 + s8 * 8;
            *(ushort4*)dst = a; *(ushort4*)(dst + 4) = c;
        }
    } else {
        int cid = (blockIdx.x - 8) * 96 + blockIdx.y;
        int z = cid >= 384;
        int rem = cid - (z ? 384 : 0);
        int h = rem >> 5;
        int mt = rem & 31;
        int aoff = z ? HH : 0;
        int toff = z ? 0 : HH;
        float* out = z ? pc : cp;
        unsigned short* As = (unsigned short*)shmem;
        unsigned short* Bs = (unsigned short*)(shmem + 8192);
        const int lane = t & 63, wid = t >> 6;
        const int rA = lane & 15, kA = (lane >> 4) * 8;

        f32x4 acc[2][4] = {};

        for (int k0 = 0; k0 < 64; k0 += 32) {
#pragma unroll
            for (int j = 0; j < 2; ++j) {
                int c = t + j * 256;
                int r = c >> 2, ko = (c & 3) * 8;
                const unsigned short* srcA = qkvg + (size_t)(mt * 128 + r) * 3072 + aoff + h * DD + k0 + ko;
                unsigned short* dstA = As + (size_t)(j * 256 + wid * 64) * 8;
                __builtin_amdgcn_global_load_lds(
                    (const __attribute__((address_space(1))) void*)srcA,
                    (__attribute__((address_space(3))) void*)dstA, 16, 0, 0);
            }
            {
                int r = t >> 2, ko = (t & 3) * 8;
                const unsigned short* srcB = pp + (size_t)r * 1536 + toff + h * DD + k0 + ko;
                unsigned short* dstB = Bs + (size_t)(wid * 64) * 8;
                __builtin_amdgcn_global_load_lds(
                    (const __attribute__((address_space(1))) void*)srcB,
                    (__attribute__((address_space(3))) void*)dstB, 16, 0, 0);
            }
            __syncthreads();
            bf16x8 af[2], bfr[4];
#pragma unroll
            for (int m = 0; m < 2; ++m)
                af[m] = *(const bf16x8*)&As[(wid * 32 + m * 16 + rA) * 32 + kA];
#pragma unroll
            for (int n = 0; n < 4; ++n)
                bfr[n] = *(const bf16x8*)&Bs[(n * 16 + rA) * 32 + kA];
#pragma unroll
            for (int m = 0; m < 2; ++m)
#pragma unroll
                for (int n = 0; n < 4; ++n)
                    acc[m][n] = __builtin_amdgcn_mfma_f32_16x16x32_bf16(af[m], bfr[n], acc[m][n], 0, 0, 0);
            __syncthreads();
        }

        const int cl = lane & 15, rg = (lane >> 4) * 4;
#pragma unroll
        for (int m = 0; m < 2; ++m)
#pragma unroll
            for (int n = 0; n < 4; ++n) {
                int gc = n * 16 + cl;
                if (gc < 63) {
#pragma unroll
                    for (int i = 0; i < 4; ++i) {
                        int gr = mt * 128 + wid * 32 + m * 16 + rg + i;
                        int sIdx = gr >> 3, bIdx = gr & 7;
                        out[(((size_t)(bIdx * NHH + h)) * SS + sIdx) * 63 + gc] = acc[m][n][i];
                    }
                }
            }
    }
}

// ---------------------------------------------------------------------------
// fused disentangled flash attention v2 (unchanged from round 7)
// ---------------------------------------------------------------------------
__global__ __launch_bounds__(256) void k_attn_fused(
    const unsigned short* __restrict__ qT, const unsigned short* __restrict__ kT,
    const unsigned short* __restrict__ vT, const float* __restrict__ cp,
    const float* __restrict__ pc, const int* __restrict__ bucket,
    const int* __restrict__ mask, float* __restrict__ ctxr) {
    __shared__ float cps[64 * 63];
    __shared__ float pcs[64 * 63];
    __shared__ unsigned short pb_all[4][16 * 72];
    __shared__ int btab[1023];
    int t = threadIdx.x;
    int lane = t & 63, wid = t >> 6;
    int bh = blockIdx.y;
    int b = bh / NHH, h = bh % NHH;
    int qb0 = blockIdx.x * 64;
    int q0 = qb0 + wid * 16;
    int rA = lane & 15, g = lane >> 4, kA = g * 8;
    unsigned short* pb = pb_all[wid];
    const unsigned short* qTb = qT + (size_t)bh * SS * DD;
    const unsigned short* kTb = kT + (size_t)bh * SS * DD;
    const unsigned short* vTb = vT + (size_t)bh * DD * SS;
    const float* cpb = cp + (size_t)bh * SS * 63 + (size_t)qb0 * 63;
    const float* pcb = pc + (size_t)bh * SS * 63;
    const int* mkb = mask + b * SS;

    for (int i = t; i < 1023; i += 256) btab[i] = bucket[i];
    for (int i = t; i < 1008; i += 256) ((float4*)cps)[i] = ((const float4*)cpb)[i];

    bf16x8 aq[2];
#pragma unroll
    for (int dc = 0; dc < 2; ++dc)
        aq[dc] = *(const bf16x8*)&qTb[(size_t)(q0 + rA) * DD + dc * 32 + kA];

    f32x4 o[4] = {};
    float mrow[4], lrow[4];
#pragma unroll
    for (int i = 0; i < 4; ++i) { mrow[i] = -INFINITY; lrow[i] = 0.f; }

    for (int kt = 0; kt < 8; ++kt) {
        int k0 = kt * 64;
        __syncthreads();
        {
            const float4* src = (const float4*)(pcb + (size_t)k0 * 63);
            for (int i = t; i < 1008; i += 256) ((float4*)pcs)[i] = src[i];
        }
        f32x4 sa[4] = {};
#pragma unroll
        for (int n = 0; n < 4; ++n) {
            bf16x8 bk0 = *(const bf16x8*)&kTb[(size_t)(k0 + n * 16 + rA) * DD + kA];
            bf16x8 bk1 = *(const bf16x8*)&kTb[(size_t)(k0 + n * 16 + rA) * DD + 32 + kA];
            sa[n] = __builtin_amdgcn_mfma_f32_16x16x32_bf16(aq[0], bk0, sa[n], 0, 0, 0);
            sa[n] = __builtin_amdgcn_mfma_f32_16x16x32_bf16(aq[1], bk1, sa[n], 0, 0, 0);
        }
        int mk[4];
#pragma unroll
        for (int n = 0; n < 4; ++n) mk[n] = mkb[k0 + n * 16 + rA];
        __syncthreads();

        float pv[4][4];
#pragma unroll
        for (int i = 0; i < 4; ++i) {
            int qr = wid * 16 + g * 4 + i;
            int q = qb0 + qr;
            float sv[4];
            float tmax = -INFINITY;
#pragma unroll
            for (int n = 0; n < 4; ++n) {
                int kr = n * 16 + rA;
                int id = btab[q - (k0 + kr) + 511];
                float v = (sa[n][i] + cps[qr * 63 + id] + pcs[kr * 63 + id]) * SCALE_F;
                v = mk[n] ? -1e9f : v;
                sv[n] = v;
                tmax = fmaxf(tmax, v);
            }
            tmax = fmaxf(tmax, __shfl_xor(tmax, 1, 16));
            tmax = fmaxf(tmax, __shfl_xor(tmax, 2, 16));
            tmax = fmaxf(tmax, __shfl_xor(tmax, 4, 16));
            tmax = fmaxf(tmax, __shfl_xor(tmax, 8, 16));
            float mold = mrow[i];
            float mnew = fmaxf(mold, tmax);
            float ls = 0.f;
#pragma unroll
            for (int n = 0; n < 4; ++n) {
                float p = __expf(sv[n] - mnew);
                pv[n][i] = p;
                ls += p;
            }
            ls += __shfl_xor(ls, 1, 16);
            ls += __shfl_xor(ls, 2, 16);
            ls += __shfl_xor(ls, 4, 16);
            ls += __shfl_xor(ls, 8, 16);
            if (mnew > mold) {
                float alpha = __expf(mold - mnew);
                lrow[i] = lrow[i] * alpha + ls;
                mrow[i] = mnew;
#pragma unroll
                for (int n = 0; n < 4; ++n) o[n][i] *= alpha;
            } else {
                lrow[i] += ls;
            }
        }
#pragma unroll
        for (int n = 0; n < 4; ++n)
#pragma unroll
            for (int i = 0; i < 4; ++i)
                pb[(g * 4 + i) * 72 + n * 16 + rA] = f2b(pv[n][i]);
        bf16x8 ap[2];
#pragma unroll
        for (int kc = 0; kc < 2; ++kc)
            ap[kc] = *(const bf16x8*)&pb[rA * 72 + kc * 32 + kA];
#pragma unroll
        for (int n = 0; n < 4; ++n) {
            bf16x8 bv0 = *(const bf16x8*)&vTb[(size_t)(n * 16 + rA) * SS + k0 + kA];
            bf16x8 bv1 = *(const bf16x8*)&vTb[(size_t)(n * 16 + rA) * SS + k0 + 32 + kA];
            o[n] = __builtin_amdgcn_mfma_f32_16x16x32_bf16(ap[0], bv0, o[n], 0, 0, 0);
            o[n] = __builtin_amdgcn_mfma_f32_16x16x32_bf16(ap[1], bv1, o[n], 0, 0, 0);
        }
    }
#pragma unroll
    for (int i = 0; i < 4; ++i) {
        int q = q0 + g * 4 + i;
        float inv = 1.0f / lrow[i];
#pragma unroll
        for (int n = 0; n < 4; ++n)
            ctxr[((size_t)q * BB + b) * HH + h * DD + n * 16 + rA] = o[n][i] * inv;
    }
}

// ---------------------------------------------------------------------------
// host launcher
// ---------------------------------------------------------------------------
static inline void gemm_big(const unsigned short* A, int lda,
                            const unsigned short* W, const unsigned short* Wb2, int ldw,
                            void* C, int ldc, int M, int N, int K,
                            const float* bias, const float* bias2, const float* res,
                            int obf, hipStream_t st) {
    dim3 g(N / 256, M / 128);
    if (obf)
        k_gemm_big<1><<<g, 512, 3 * GSLOT, st>>>(A, lda, W, Wb2, ldw, C, ldc, M, N, K, bias, bias2, res);
    else
        k_gemm_big<0><<<g, 512, 3 * GSLOT, st>>>(A, lda, W, Wb2, ldw, C, ldc, M, N, K, bias, bias2, res);
}

extern "C" void kernel_launch(void* const* d_in, const int* in_sizes, int n_in,
                              void* d_out, int out_size, void* d_ws, size_t ws_size,
                              hipStream_t stream) {
    static int attr_done = 0;
    if (!attr_done) {
        hipFuncSetAttribute((const void*)&k_gemm_big<1>,
                            hipFuncAttributeMaxDynamicSharedMemorySize, 3 * GSLOT);
        hipFuncSetAttribute((const void*)&k_gemm_big<0>,
                            hipFuncAttributeMaxDynamicSharedMemorySize, 3 * GSLOT);
        attr_done = 1;
    }

    const int* ids = (const int*)d_in[0];
    const unsigned char* maskraw = (const unsigned char*)d_in[1];
    const float* word_emb = (const float*)d_in[2];
    const float* rel_emb = (const float*)d_in[3];
    const float* rel_g = (const float*)d_in[4];
    const float* rel_b = (const float*)d_in[5];
    const float* Wqk = (const float*)d_in[6];
    const float* bqk = (const float*)d_in[7];
    const float* Wvg = (const float*)d_in[8];
    const float* bvg = (const float*)d_in[9];
    const float* Wout = (const float*)d_in[10];
    const float* bout = (const float*)d_in[11];
    const float* W1 = (const float*)d_in[12];
    const float* W2 = (const float*)d_in[13];

    const size_t N_X = (size_t)SS * BB * HH;
    const size_t N_CP = (size_t)SS * BB * NHH * 63;
    const size_t N_H2 = (size_t)SS * BB * II;
    const size_t N_WQK = (size_t)2 * HH * HH;
    const size_t N_WOUT = (size_t)HH * HH;
    const size_t N_W1 = (size_t)2 * II * HH;
    const size_t N_W2 = (size_t)HH * II;
    const size_t N_HD = (size_t)BB * NHH * SS * DD;
    const size_t N_QKVG = (size_t)SS * BB * 3072;
    const size_t N_FFH = (size_t)SS * BB * 4096;
    const size_t N_PP = (size_t)128 * 1536;

    float* ws = (float*)d_ws;
    float* x = ws;
    float* ctxr = x + N_X;
    float* cp = ctxr + N_X;
    float* pc = cp + N_CP;
    unsigned short* us = (unsigned short*)(pc + N_CP);
    unsigned short* qkvg = us;
    unsigned short* hs_bf = qkvg + N_QKVG;
    unsigned short* ctx_bf = hs_bf + N_X;
    unsigned short* h2_bf = ctx_bf + N_X;
    unsigned short* ffh = h2_bf + N_H2;
    unsigned short* wqk_all = ffh + N_FFH;
    unsigned short* wvg_bf = wqk_all + 12 * N_WQK;
    unsigned short* wout_bf = wvg_bf + N_WQK;
    unsigned short* w1_bf = wout_bf + N_WOUT;
    unsigned short* w2_bf = w1_bf + N_W1;
    unsigned short* ppall = w2_bf + N_W2;
    unsigned short* rel_bf = ppall + 12 * N_PP;
    unsigned short* qT = rel_bf + 128 * HH;
    unsigned short* kT = qT + N_HD;
    unsigned short* vT = kT + N_HD;
    int* bucket = (int*)(vT + N_HD);
    int* maski = bucket + 1024;

    size_t need_bytes = ((size_t)(maski + BB * SS) - (size_t)d_ws);
    if (ws_size < need_bytes) return;  // ~205 MB required

    // ---- setup ----
    k_decode_mask<<<1, 256, 0, stream>>>(maskraw, maski, BB * SS);
    k_bucket<<<4, 256, 0, stream>>>(bucket);
    k_embed_ln<<<SS * BB, 256, 0, stream>>>(ids, word_emb, x);
    k_rel_ln_bf<<<128, 256, 0, stream>>>(rel_emb, rel_g, rel_b, rel_bf);
    k_f2b<<<(int)((12 * N_WQK / 8 + 255) / 256), 256, 0, stream>>>(Wqk, wqk_all,
                                                                   (int)(12 * N_WQK / 8));
    {
        dim3 gpp(1536 / 128, 1, 12);
        k_gemm_bf16<1><<<gpp, 256, 0, stream>>>(rel_bf, HH, wqk_all, HH, ppall, 1536,
                                                128, 1536, HH, bqk, nullptr, nullptr,
                                                N_WQK, N_PP, 2 * HH);
    }

    for (int l = 0; l < LL; ++l) {
        const unsigned short* wqk_l = wqk_all + (size_t)l * N_WQK;
        const float* bqk_l = bqk + (size_t)l * 2 * HH;
        const float* Wvg_l = Wvg + (size_t)l * N_WQK;
        const float* bvg_l = bvg + (size_t)l * 2 * HH;
        const float* Wout_l = Wout + (size_t)l * N_WOUT;
        const float* bout_l = bout + (size_t)l * HH;
        const float* W1_l = W1 + (size_t)l * N_W1;
        const float* W2_l = W2 + (size_t)l * N_W2;

        // ---- attention ----
        k_f2b_ln<<<3169 + SS * BB, 256, 0, stream>>>(Wvg_l, Wout_l, W1_l, W2_l, wvg_bf,
                                                     x, hs_bf);
        gemm_big(hs_bf, HH, wqk_l, wvg_bf, HH, qkvg, 3072, SS * BB, 3072, HH,
                 bqk_l, bvg_l, nullptr, 1, stream);
        k_repack_cppc<<<dim3(16, 96), 256, 0, stream>>>(qkvg, ppall + (size_t)l * N_PP,
                                                        qT, kT, vT, cp, pc);
        k_attn_fused<<<dim3(SS / 64, BB * NHH), 256, 0, stream>>>(qT, kT, vT, cp, pc,
                                                                  bucket, maski, ctxr);
        k_gated_ln<<<SS * BB, 256, 0, stream>>>(ctxr, qkvg, ctx_bf);
        k_gemm_skinny<<<dim3(HH / 64, SS * BB / 64), 256, 0, stream>>>(
            ctx_bf, HH, wout_bf, HH, x, HH, SS * BB, HH, HH, bout_l, x);

        // ---- GeGLU FFN ----
        k_ln_bf<<<SS * BB, 256, 0, stream>>>(x, hs_bf);
        gemm_big(hs_bf, HH, w1_bf, nullptr, HH, ffh, 4096, SS * BB, 4096, HH,
                 nullptr, nullptr, nullptr, 1, stream);
        k_ffn_ln<<<SS * BB, 256, 0, stream>>>(ffh, h2_bf);
        k_gemm_skinny<<<dim3(HH / 64, SS * BB / 64), 256, 0, stream>>>(
            h2_bf, II, w2_bf, II, x, HH, SS * BB, HH, II, nullptr, x);
    }

    hipMemcpyAsync(d_out, x, N_X * sizeof(float), hipMemcpyDeviceToDevice, stream);
}